// Round 2
// baseline (530.205 us; speedup 1.0000x reference)
//
#include <hip/hip_runtime.h>
#include <stdint.h>

typedef unsigned short u16;
typedef u16 u16x8 __attribute__((ext_vector_type(8)));
typedef short s16x8 __attribute__((ext_vector_type(8)));
typedef float f32x4 __attribute__((ext_vector_type(4)));

#define B_ 4
#define LQ_ 1024
#define LK_ 2048
#define D_ 1024
#define H_ 16
#define DH_ 64
#define K3_ 3072

__device__ __forceinline__ u16 f2bf(float x) {
  uint32_t u = __float_as_uint(x);
  u += 0x7FFFu + ((u >> 16) & 1u);   // round-to-nearest-even
  return (u16)(u >> 16);
}
__device__ __forceinline__ float bf2f(u16 h) {
  return __uint_as_float(((uint32_t)h) << 16);
}

// ---------- split (activation side): rows x 1024 fp32 -> rows x 3072 bf16 [hi | lo | hi]
__global__ __launch_bounds__(256) void split3a_k(const float* __restrict__ src,
                                                 u16* __restrict__ dst, int n) {
  int i = blockIdx.x * 256 + threadIdx.x;
  if (i >= n) return;
  int k = i & 1023;
  int r = i >> 10;
  float x = src[i];
  u16 hi = f2bf(x);
  u16 lo = f2bf(x - bf2f(hi));
  u16* d = dst + (size_t)r * 3072;
  d[k] = hi;
  d[1024 + k] = lo;
  d[2048 + k] = hi;
}

// ---------- split (weight side): rows x 1024 fp32 -> rows x 3072 bf16 [hi | hi | lo]
// Pairing with the activation layout gives hi*hi + lo*hi + hi*lo (Dekker 3-term).
__global__ __launch_bounds__(256) void split3w_k(const float* __restrict__ src,
                                                 u16* __restrict__ dst, int n) {
  int i = blockIdx.x * 256 + threadIdx.x;
  if (i >= n) return;
  int k = i & 1023;
  int r = i >> 10;
  float x = src[i];
  u16 hi = f2bf(x);
  u16 lo = f2bf(x - bf2f(hi));
  u16* d = dst + (size_t)r * 3072;
  d[k] = hi;
  d[1024 + k] = hi;
  d[2048 + k] = lo;
}

// ---------- C[M,N] = A[M,K] * B[N,K]^T (bf16 in, fp32 out), 128x128 tile ----------
__global__ __launch_bounds__(256) void gemm_bt(const u16* __restrict__ A,
                                               const u16* __restrict__ Bm,
                                               float* __restrict__ C,
                                               int N, int K) {
  __shared__ __align__(16) u16 As[128 * 32];
  __shared__ __align__(16) u16 Bs[128 * 32];
  const int tid = threadIdx.x;
  const int lane = tid & 63;
  const int wid = tid >> 6;
  const int m0 = blockIdx.x * 128;
  const int n0 = blockIdx.y * 128;
  const int wr = (wid >> 1) * 64;
  const int wc = (wid & 1) * 64;
  const int fr = lane & 15;
  const int fq = lane >> 4;
  const int srow = lane >> 2;   // 0..15
  const int schunk = lane & 3;  // 0..3

  f32x4 zero = {0.f, 0.f, 0.f, 0.f};
  f32x4 acc[4][4];
  for (int i = 0; i < 4; i++)
    for (int j = 0; j < 4; j++) acc[i][j] = zero;

  const int r0 = wid * 32;  // each wave stages 32 rows of A and B
  const u16* gA = A + (size_t)(m0 + r0 + srow) * K + schunk * 8;
  const u16* gB = Bm + (size_t)(n0 + r0 + srow) * K + schunk * 8;
  u16* lA = &As[r0 * 32];
  u16* lB = &Bs[r0 * 32];

  for (int k0 = 0; k0 < K; k0 += 32) {
    __syncthreads();
    __builtin_amdgcn_global_load_lds(
        (const __attribute__((address_space(1))) void*)(gA + k0),
        (__attribute__((address_space(3))) void*)(lA), 16, 0, 0);
    __builtin_amdgcn_global_load_lds(
        (const __attribute__((address_space(1))) void*)(gA + k0 + (size_t)16 * K),
        (__attribute__((address_space(3))) void*)(lA + 16 * 32), 16, 0, 0);
    __builtin_amdgcn_global_load_lds(
        (const __attribute__((address_space(1))) void*)(gB + k0),
        (__attribute__((address_space(3))) void*)(lB), 16, 0, 0);
    __builtin_amdgcn_global_load_lds(
        (const __attribute__((address_space(1))) void*)(gB + k0 + (size_t)16 * K),
        (__attribute__((address_space(3))) void*)(lB + 16 * 32), 16, 0, 0);
    asm volatile("s_waitcnt vmcnt(0)" ::: "memory");
    __syncthreads();

    s16x8 af[4], bf[4];
#pragma unroll
    for (int mi = 0; mi < 4; mi++)
      af[mi] = *(const s16x8*)&As[(wr + mi * 16 + fr) * 32 + fq * 8];
#pragma unroll
    for (int ni = 0; ni < 4; ni++)
      bf[ni] = *(const s16x8*)&Bs[(wc + ni * 16 + fr) * 32 + fq * 8];
#pragma unroll
    for (int mi = 0; mi < 4; mi++)
#pragma unroll
      for (int ni = 0; ni < 4; ni++)
        acc[mi][ni] = __builtin_amdgcn_mfma_f32_16x16x32_bf16(af[mi], bf[ni],
                                                              acc[mi][ni], 0, 0, 0);
  }
#pragma unroll
  for (int mi = 0; mi < 4; mi++) {
#pragma unroll
    for (int ni = 0; ni < 4; ni++) {
      int row = m0 + wr + mi * 16 + fq * 4;
      int col = n0 + wc + ni * 16 + fr;
#pragma unroll
      for (int r = 0; r < 4; r++) C[(size_t)(row + r) * N + col] = acc[mi][ni][r];
    }
  }
}

// ---------- per-head RMSNorm + RoPE, fp32 in -> bf16 [b][h][l][64] out ----------
__global__ __launch_bounds__(256) void norm_rope_k(const float* __restrict__ src,
                                                   int srcStride, int hs,
                                                   const float* __restrict__ w,
                                                   const int* __restrict__ pos,
                                                   u16* __restrict__ dst, int L) {
  int wid = threadIdx.x >> 6;
  int lane = threadIdx.x & 63;
  int g = blockIdx.x * 4 + wid;  // (b*L + l)*H + h
  int h = g & 15;
  int bl = g >> 4;
  int b = bl / L;
  int l = bl - b * L;
  float x = src[(size_t)bl * srcStride + h * hs + lane];
  float ss = x * x;
#pragma unroll
  for (int m = 1; m < 64; m <<= 1) ss += __shfl_xor(ss, m, 64);
  float xn = x * rsqrtf(ss * (1.0f / 64.0f) + 1e-6f) * w[lane];
  float p = __shfl_xor(xn, 32, 64);
  int j = lane & 31;
  float freq = powf(10000.0f, -(float)j * (1.0f / 32.0f));
  float ang = (float)pos[l] * freq;
  float c = cosf(ang), s = sinf(ang);
  float o = (lane < 32) ? (xn * c - p * s) : (p * s + xn * c);
  dst[((size_t)(b * 16 + h) * L + l) * 64 + lane] = f2bf(o);
}

// ---------- V transpose: kvp v-part -> vt[b][h][dh][lk] bf16 ----------
__global__ __launch_bounds__(256) void vtrans_k(const float* __restrict__ kvp,
                                                u16* __restrict__ vt) {
  __shared__ float tile[64][65];
  int kt = blockIdx.x & 31;  // LK/64
  int bh = blockIdx.x >> 5;
  int h = bh & 15;
  int b = bh >> 4;
  int c = threadIdx.x & 63;
  int r4 = threadIdx.x >> 6;
  const float* src = kvp + ((size_t)(b * LK_ + kt * 64)) * 2048 + h * 128 + 64;
#pragma unroll
  for (int p = 0; p < 16; p++) {
    int lk = p * 4 + r4;
    tile[lk][c] = src[(size_t)lk * 2048 + c];
  }
  __syncthreads();
  u16* dst = vt + (size_t)bh * 64 * LK_ + kt * 64;
#pragma unroll
  for (int p = 0; p < 16; p++) {
    int dh = p * 4 + r4;
    dst[(size_t)dh * LK_ + c] = f2bf(tile[c][dh]);
  }
}

// ---------- flash attention: q[b][h][lq][64], k[b][h][lk][64], vT[b][h][64][lk] ----------
__global__ __launch_bounds__(256) void flash_k(const u16* __restrict__ qb,
                                               const u16* __restrict__ kb,
                                               const u16* __restrict__ vb,
                                               float* __restrict__ y) {
  __shared__ __align__(16) u16 Ks[64][72];
  __shared__ __align__(16) u16 Vs[64][72];       // Vs[dh][kv]
  __shared__ __align__(16) u16 Ps[4][16][72];
  const int tid = threadIdx.x;
  const int lane = tid & 63;
  const int wid = tid >> 6;
  const int fr = lane & 15;
  const int fq = lane >> 4;
  int qt = blockIdx.x & 15;  // LQ/64
  int bh = blockIdx.x >> 4;  // b*16+h
  const u16* qbase = qb + ((size_t)bh * LQ_ + qt * 64 + wid * 16) * 64;
  const u16* kbase = kb + (size_t)bh * LK_ * 64;
  const u16* vbase = vb + (size_t)bh * 64 * LK_;
  s16x8 qf0 = *(const s16x8*)(qbase + (size_t)fr * 64 + fq * 8);
  s16x8 qf1 = *(const s16x8*)(qbase + (size_t)fr * 64 + 32 + fq * 8);
  float mrun[4], lrun[4];
  f32x4 zero = {0.f, 0.f, 0.f, 0.f};
  f32x4 yacc[4];
#pragma unroll
  for (int r = 0; r < 4; r++) { mrun[r] = -1e30f; lrun[r] = 0.f; }
#pragma unroll
  for (int ni = 0; ni < 4; ni++) yacc[ni] = zero;
  const int srow = tid >> 3;   // 0..31
  const int schunk = tid & 7;  // 0..7

  for (int kt = 0; kt < LK_; kt += 64) {
    __syncthreads();
#pragma unroll
    for (int ps = 0; ps < 2; ps++) {
      int row = srow + ps * 32;
      *(u16x8*)&Ks[row][schunk * 8] =
          *(const u16x8*)(kbase + (size_t)(kt + row) * 64 + schunk * 8);
      *(u16x8*)&Vs[row][schunk * 8] =
          *(const u16x8*)(vbase + (size_t)row * LK_ + kt + schunk * 8);
    }
    __syncthreads();
    f32x4 sacc[4];
#pragma unroll
    for (int ni = 0; ni < 4; ni++) sacc[ni] = zero;
#pragma unroll
    for (int ni = 0; ni < 4; ni++) {
      s16x8 kf0 = *(const s16x8*)&Ks[ni * 16 + fr][fq * 8];
      s16x8 kf1 = *(const s16x8*)&Ks[ni * 16 + fr][32 + fq * 8];
      sacc[ni] = __builtin_amdgcn_mfma_f32_16x16x32_bf16(qf0, kf0, sacc[ni], 0, 0, 0);
      sacc[ni] = __builtin_amdgcn_mfma_f32_16x16x32_bf16(qf1, kf1, sacc[ni], 0, 0, 0);
    }
    float alpha[4];
#pragma unroll
    for (int r = 0; r < 4; r++) {
      float mx = -1e30f;
#pragma unroll
      for (int ni = 0; ni < 4; ni++) {
        float sv = sacc[ni][r] * 0.125f;
        sacc[ni][r] = sv;
        mx = fmaxf(mx, sv);
      }
#pragma unroll
      for (int mm = 1; mm < 16; mm <<= 1) mx = fmaxf(mx, __shfl_xor(mx, mm, 64));
      float mn = fmaxf(mrun[r], mx);
      alpha[r] = __expf(mrun[r] - mn);
      mrun[r] = mn;
      float ts = 0.f;
#pragma unroll
      for (int ni = 0; ni < 4; ni++) {
        float pv = __expf(sacc[ni][r] - mn);
        sacc[ni][r] = pv;
        ts += pv;
      }
#pragma unroll
      for (int mm = 1; mm < 16; mm <<= 1) ts += __shfl_xor(ts, mm, 64);
      lrun[r] = lrun[r] * alpha[r] + ts;
    }
#pragma unroll
    for (int ni = 0; ni < 4; ni++)
#pragma unroll
      for (int r = 0; r < 4; r++) yacc[ni][r] *= alpha[r];
      // P -> LDS (bf16), D-frag layout -> A-frag layout round trip
#pragma unroll
    for (int ni = 0; ni < 4; ni++)
#pragma unroll
      for (int r = 0; r < 4; r++)
        Ps[wid][fq * 4 + r][ni * 16 + fr] = f2bf(sacc[ni][r]);
#pragma unroll
    for (int s2 = 0; s2 < 2; s2++) {
      s16x8 pa = *(const s16x8*)&Ps[wid][fr][s2 * 32 + fq * 8];
#pragma unroll
      for (int ni = 0; ni < 4; ni++) {
        s16x8 vf = *(const s16x8*)&Vs[ni * 16 + fr][s2 * 32 + fq * 8];
        yacc[ni] = __builtin_amdgcn_mfma_f32_16x16x32_bf16(pa, vf, yacc[ni], 0, 0, 0);
      }
    }
  }
  int b = bh >> 4, h = bh & 15;
  float* yo = y + ((size_t)(b * LQ_ + qt * 64 + wid * 16 + fq * 4)) * D_ + h * 64;
#pragma unroll
  for (int ni = 0; ni < 4; ni++) {
#pragma unroll
    for (int r = 0; r < 4; r++)
      yo[(size_t)r * D_ + ni * 16 + fr] = yacc[ni][r] / lrun[r];
  }
}

extern "C" void kernel_launch(void* const* d_in, const int* in_sizes, int n_in,
                              void* d_out, int out_size, void* d_ws, size_t ws_size,
                              hipStream_t stream) {
  (void)in_sizes; (void)n_in; (void)out_size;
  const float* queries = (const float*)d_in[0];
  const float* kv = (const float*)d_in[1];
  const float* wq = (const float*)d_in[2];
  const float* wkv = (const float*)d_in[3];
  const float* wo = (const float*)d_in[4];
  const float* qnw = (const float*)d_in[5];
  const float* knw = (const float*)d_in[6];
  const int* pos_q = (const int*)d_in[7];
  const int* pos_k = (const int*)d_in[8];
  float* out = (float*)d_out;

  char* ws = (char*)d_ws;
  size_t off = 0;
  auto alloc = [&](size_t sz) { void* p = ws + off; off += sz; return p; };
  u16* Aq3 = (u16*)alloc((size_t)4096 * 3072 * 2);   // reused as Y3 later
  u16* Wq3 = (u16*)alloc((size_t)1024 * 3072 * 2);
  u16* Akv3 = (u16*)alloc((size_t)8192 * 3072 * 2);
  u16* Wkv3 = (u16*)alloc((size_t)2048 * 3072 * 2);
  u16* Wo3 = (u16*)alloc((size_t)1024 * 3072 * 2);
  float* Qp = (float*)alloc((size_t)4096 * 1024 * 4);  // reused as Y later
  float* KVp = (float*)alloc((size_t)8192 * 2048 * 4);
  u16* Qb = (u16*)alloc((size_t)64 * 1024 * 64 * 2);
  u16* Kb = (u16*)alloc((size_t)64 * 2048 * 64 * 2);
  u16* Vt = (u16*)alloc((size_t)64 * 2048 * 64 * 2);
  if (off > ws_size) return;  // insufficient workspace — bail loudly (validation fails)

  u16* Y3 = Aq3;
  float* Y = Qp;

  // 1) Dekker splits: activations [hi|lo|hi], weights [hi|hi|lo]
  split3a_k<<<4096 * 1024 / 256, 256, 0, stream>>>(queries, Aq3, 4096 * 1024);
  split3w_k<<<1024 * 1024 / 256, 256, 0, stream>>>(wq, Wq3, 1024 * 1024);
  split3a_k<<<8192 * 1024 / 256, 256, 0, stream>>>(kv, Akv3, 8192 * 1024);
  split3w_k<<<2048 * 1024 / 256, 256, 0, stream>>>(wkv, Wkv3, 2048 * 1024);
  split3w_k<<<1024 * 1024 / 256, 256, 0, stream>>>(wo, Wo3, 1024 * 1024);
  // 2) projections (fp32-equivalent via 3-term split)
  gemm_bt<<<dim3(4096 / 128, 1024 / 128), 256, 0, stream>>>(Aq3, Wq3, Qp, 1024, 3072);
  gemm_bt<<<dim3(8192 / 128, 2048 / 128), 256, 0, stream>>>(Akv3, Wkv3, KVp, 2048, 3072);
  // 3) RMSNorm + RoPE -> bf16 head-major
  norm_rope_k<<<4096 * 16 / 4, 256, 0, stream>>>(Qp, 1024, 64, qnw, pos_q, Qb, 1024);
  norm_rope_k<<<8192 * 16 / 4, 256, 0, stream>>>(KVp, 2048, 128, knw, pos_k, Kb, 2048);
  vtrans_k<<<64 * 32, 256, 0, stream>>>(KVp, Vt);
  // 4) flash attention -> Y fp32 [b][lq][h*64+dh]
  flash_k<<<64 * 16, 256, 0, stream>>>(Qb, Kb, Vt, Y);
  // 5) output projection (split + GEMM) -> d_out
  split3a_k<<<4096 * 1024 / 256, 256, 0, stream>>>(Y, Y3, 4096 * 1024);
  gemm_bt<<<dim3(4096 / 128, 1024 / 128), 256, 0, stream>>>(Y3, Wo3, out, 1024, 3072);
}

// Round 3
// 500.889 us; speedup vs baseline: 1.0585x; 1.0585x over previous
//
#include <hip/hip_runtime.h>
#include <stdint.h>

typedef unsigned short u16;
typedef u16 u16x8 __attribute__((ext_vector_type(8)));
typedef short s16x8 __attribute__((ext_vector_type(8)));
typedef float f32x4 __attribute__((ext_vector_type(4)));

#define B_ 4
#define LQ_ 1024
#define LK_ 2048
#define D_ 1024
#define H_ 16
#define DH_ 64
#define K3_ 3072

__device__ __forceinline__ u16 f2bf(float x) {
  uint32_t u = __float_as_uint(x);
  u += 0x7FFFu + ((u >> 16) & 1u);   // round-to-nearest-even
  return (u16)(u >> 16);
}
__device__ __forceinline__ float bf2f(u16 h) {
  return __uint_as_float(((uint32_t)h) << 16);
}

// ---------- split (activation side): rows x 1024 fp32 -> rows x 3072 bf16 [hi | lo | hi]
__global__ __launch_bounds__(256) void split3a_k(const float* __restrict__ src,
                                                 u16* __restrict__ dst, int n) {
  int i = blockIdx.x * 256 + threadIdx.x;
  if (i >= n) return;
  int k = i & 1023;
  int r = i >> 10;
  float x = src[i];
  u16 hi = f2bf(x);
  u16 lo = f2bf(x - bf2f(hi));
  u16* d = dst + (size_t)r * 3072;
  d[k] = hi;
  d[1024 + k] = lo;
  d[2048 + k] = hi;
}

// ---------- split (weight side): rows x 1024 fp32 -> rows x 3072 bf16 [hi | hi | lo]
// Paired with the activation layout: hi*hi + lo*hi + hi*lo (Dekker 3-term).
__global__ __launch_bounds__(256) void split3w_k(const float* __restrict__ src,
                                                 u16* __restrict__ dst, int n) {
  int i = blockIdx.x * 256 + threadIdx.x;
  if (i >= n) return;
  int k = i & 1023;
  int r = i >> 10;
  float x = src[i];
  u16 hi = f2bf(x);
  u16 lo = f2bf(x - bf2f(hi));
  u16* d = dst + (size_t)r * 3072;
  d[k] = hi;
  d[1024 + k] = hi;
  d[2048 + k] = lo;
}

// ---------- C[M,N] = A[M,K] * B[N,K]^T (bf16 in, fp32 out), 128x128 tile ----------
__global__ __launch_bounds__(256) void gemm_bt(const u16* __restrict__ A,
                                               const u16* __restrict__ Bm,
                                               float* __restrict__ C,
                                               int N, int K) {
  __shared__ __align__(16) u16 As[128 * 32];
  __shared__ __align__(16) u16 Bs[128 * 32];
  const int tid = threadIdx.x;
  const int lane = tid & 63;
  const int wid = tid >> 6;
  const int m0 = blockIdx.x * 128;
  const int n0 = blockIdx.y * 128;
  const int wr = (wid >> 1) * 64;
  const int wc = (wid & 1) * 64;
  const int fr = lane & 15;
  const int fq = lane >> 4;
  const int srow = lane >> 2;   // 0..15
  const int schunk = lane & 3;  // 0..3

  f32x4 zero = {0.f, 0.f, 0.f, 0.f};
  f32x4 acc[4][4];
  for (int i = 0; i < 4; i++)
    for (int j = 0; j < 4; j++) acc[i][j] = zero;

  const int r0 = wid * 32;  // each wave stages 32 rows of A and B
  const u16* gA = A + (size_t)(m0 + r0 + srow) * K + schunk * 8;
  const u16* gB = Bm + (size_t)(n0 + r0 + srow) * K + schunk * 8;
  u16* lA = &As[r0 * 32];
  u16* lB = &Bs[r0 * 32];

  for (int k0 = 0; k0 < K; k0 += 32) {
    __syncthreads();
    __builtin_amdgcn_global_load_lds(
        (const __attribute__((address_space(1))) void*)(gA + k0),
        (__attribute__((address_space(3))) void*)(lA), 16, 0, 0);
    __builtin_amdgcn_global_load_lds(
        (const __attribute__((address_space(1))) void*)(gA + k0 + (size_t)16 * K),
        (__attribute__((address_space(3))) void*)(lA + 16 * 32), 16, 0, 0);
    __builtin_amdgcn_global_load_lds(
        (const __attribute__((address_space(1))) void*)(gB + k0),
        (__attribute__((address_space(3))) void*)(lB), 16, 0, 0);
    __builtin_amdgcn_global_load_lds(
        (const __attribute__((address_space(1))) void*)(gB + k0 + (size_t)16 * K),
        (__attribute__((address_space(3))) void*)(lB + 16 * 32), 16, 0, 0);
    asm volatile("s_waitcnt vmcnt(0)" ::: "memory");
    __syncthreads();

    s16x8 af[4], bf[4];
#pragma unroll
    for (int mi = 0; mi < 4; mi++)
      af[mi] = *(const s16x8*)&As[(wr + mi * 16 + fr) * 32 + fq * 8];
#pragma unroll
    for (int ni = 0; ni < 4; ni++)
      bf[ni] = *(const s16x8*)&Bs[(wc + ni * 16 + fr) * 32 + fq * 8];
#pragma unroll
    for (int mi = 0; mi < 4; mi++)
#pragma unroll
      for (int ni = 0; ni < 4; ni++)
        acc[mi][ni] = __builtin_amdgcn_mfma_f32_16x16x32_bf16(af[mi], bf[ni],
                                                              acc[mi][ni], 0, 0, 0);
  }
#pragma unroll
  for (int mi = 0; mi < 4; mi++) {
#pragma unroll
    for (int ni = 0; ni < 4; ni++) {
      int row = m0 + wr + mi * 16 + fq * 4;
      int col = n0 + wc + ni * 16 + fr;
#pragma unroll
      for (int r = 0; r < 4; r++) C[(size_t)(row + r) * N + col] = acc[mi][ni][r];
    }
  }
}

// ---------- per-head RMSNorm + RoPE, fp32 in -> bf16 [b][h][l][64] out ----------
__global__ __launch_bounds__(256) void norm_rope_k(const float* __restrict__ src,
                                                   int srcStride, int hs,
                                                   const float* __restrict__ w,
                                                   const int* __restrict__ pos,
                                                   u16* __restrict__ dst, int L) {
  int wid = threadIdx.x >> 6;
  int lane = threadIdx.x & 63;
  int g = blockIdx.x * 4 + wid;  // (b*L + l)*H + h
  int h = g & 15;
  int bl = g >> 4;
  int b = bl / L;
  int l = bl - b * L;
  float x = src[(size_t)bl * srcStride + h * hs + lane];
  float ss = x * x;
#pragma unroll
  for (int m = 1; m < 64; m <<= 1) ss += __shfl_xor(ss, m, 64);
  float xn = x * rsqrtf(ss * (1.0f / 64.0f) + 1e-6f) * w[lane];
  float p = __shfl_xor(xn, 32, 64);
  int j = lane & 31;
  float freq = powf(10000.0f, -(float)j * (1.0f / 32.0f));
  float ang = (float)pos[l] * freq;
  float c = cosf(ang), s = sinf(ang);
  float o = (lane < 32) ? (xn * c - p * s) : (p * s + xn * c);
  dst[((size_t)(b * 16 + h) * L + l) * 64 + lane] = f2bf(o);
}

// ---------- V transpose: kvp v-part -> vt[b][h][dh][lk] bf16 ----------
__global__ __launch_bounds__(256) void vtrans_k(const float* __restrict__ kvp,
                                                u16* __restrict__ vt) {
  __shared__ float tile[64][65];
  int kt = blockIdx.x & 31;  // LK/64
  int bh = blockIdx.x >> 5;
  int h = bh & 15;
  int b = bh >> 4;
  int c = threadIdx.x & 63;
  int r4 = threadIdx.x >> 6;
  const float* src = kvp + ((size_t)(b * LK_ + kt * 64)) * 2048 + h * 128 + 64;
#pragma unroll
  for (int p = 0; p < 16; p++) {
    int lk = p * 4 + r4;
    tile[lk][c] = src[(size_t)lk * 2048 + c];
  }
  __syncthreads();
  u16* dst = vt + (size_t)bh * 64 * LK_ + kt * 64;
#pragma unroll
  for (int p = 0; p < 16; p++) {
    int dh = p * 4 + r4;
    dst[(size_t)dh * LK_ + c] = f2bf(tile[c][dh]);
  }
}

// ---------- flash attention (swapped QK^T: lane-local softmax) ----------
// q[b][h][lq][64], k[b][h][lk][64], vT[b][h][64][lk]
// S = mfma(K, Q): lane holds S[j = ni*16 + fq*4 + r][q = fr] — each lane owns
// ONE q-row (fr) with 16 lane-local scores; row-reduce = local ops + 2 shuffles.
__global__ __launch_bounds__(256) void flash_k(const u16* __restrict__ qb,
                                               const u16* __restrict__ kb,
                                               const u16* __restrict__ vb,
                                               float* __restrict__ y) {
  __shared__ __align__(16) u16 Ks[64][72];
  __shared__ __align__(16) u16 Vs[64][72];       // Vs[dh][kv]
  __shared__ __align__(16) u16 Ps[4][16][72];    // per-wave P[q][j]
  const int tid = threadIdx.x;
  const int lane = tid & 63;
  const int wid = tid >> 6;
  const int fr = lane & 15;
  const int fq = lane >> 4;
  int qt = blockIdx.x & 15;  // LQ/64
  int bh = blockIdx.x >> 4;  // b*16+h
  const u16* qbase = qb + ((size_t)bh * LQ_ + qt * 64 + wid * 16) * 64;
  const u16* kbase = kb + (size_t)bh * LK_ * 64;
  const u16* vbase = vb + (size_t)bh * 64 * LK_;
  // Q fragment (B-operand): lane holds Q[q=fr][d = fq*8 .. +8] (+32 for qf1)
  s16x8 qf0 = *(const s16x8*)(qbase + (size_t)fr * 64 + fq * 8);
  s16x8 qf1 = *(const s16x8*)(qbase + (size_t)fr * 64 + 32 + fq * 8);
  float mrun = -1e30f, lrun = 0.f;  // lane owns q-row fr
  f32x4 zero = {0.f, 0.f, 0.f, 0.f};
  f32x4 yacc[4];
#pragma unroll
  for (int ni = 0; ni < 4; ni++) yacc[ni] = zero;
  const int srow = tid >> 3;   // 0..31
  const int schunk = tid & 7;  // 0..7

  for (int kt = 0; kt < LK_; kt += 64) {
    __syncthreads();
#pragma unroll
    for (int ps = 0; ps < 2; ps++) {
      int row = srow + ps * 32;
      *(u16x8*)&Ks[row][schunk * 8] =
          *(const u16x8*)(kbase + (size_t)(kt + row) * 64 + schunk * 8);
      *(u16x8*)&Vs[row][schunk * 8] =
          *(const u16x8*)(vbase + (size_t)row * LK_ + kt + schunk * 8);
    }
    __syncthreads();
    // QK^T, swapped: A = K rows (j), B = Q rows (q), MFMA-K = d
    f32x4 sacc[4];
#pragma unroll
    for (int ni = 0; ni < 4; ni++) sacc[ni] = zero;
#pragma unroll
    for (int ni = 0; ni < 4; ni++) {
      s16x8 kf0 = *(const s16x8*)&Ks[ni * 16 + fr][fq * 8];
      s16x8 kf1 = *(const s16x8*)&Ks[ni * 16 + fr][32 + fq * 8];
      sacc[ni] = __builtin_amdgcn_mfma_f32_16x16x32_bf16(kf0, qf0, sacc[ni], 0, 0, 0);
      sacc[ni] = __builtin_amdgcn_mfma_f32_16x16x32_bf16(kf1, qf1, sacc[ni], 0, 0, 0);
    }
    // online softmax over this tile's 64 j-values of q-row fr
    float mx = -1e30f;
#pragma unroll
    for (int ni = 0; ni < 4; ni++)
#pragma unroll
      for (int r = 0; r < 4; r++) {
        float sv = sacc[ni][r] * 0.125f;
        sacc[ni][r] = sv;
        mx = fmaxf(mx, sv);
      }
    mx = fmaxf(mx, __shfl_xor(mx, 16, 64));
    mx = fmaxf(mx, __shfl_xor(mx, 32, 64));
    float mn = fmaxf(mrun, mx);
    float alpha = __expf(mrun - mn);
    mrun = mn;
    float ts = 0.f;
#pragma unroll
    for (int ni = 0; ni < 4; ni++)
#pragma unroll
      for (int r = 0; r < 4; r++) {
        float pv = __expf(sacc[ni][r] - mn);
        sacc[ni][r] = pv;
        ts += pv;
      }
    ts += __shfl_xor(ts, 16, 64);
    ts += __shfl_xor(ts, 32, 64);
    lrun = lrun * alpha + ts;
    // rescale yacc: yacc[ni][r] belongs to q-row fq*4+r — fetch that row's alpha
    float va[4];
#pragma unroll
    for (int r = 0; r < 4; r++) va[r] = __shfl(alpha, fq * 4 + r, 64);
#pragma unroll
    for (int ni = 0; ni < 4; ni++)
#pragma unroll
      for (int r = 0; r < 4; r++) yacc[ni][r] *= va[r];
    // P -> LDS: lane's j-values per ni are 4 contiguous (j = ni*16 + fq*4 + r)
#pragma unroll
    for (int ni = 0; ni < 4; ni++) {
      uint2 w;
      w.x = (uint32_t)f2bf(sacc[ni][0]) | ((uint32_t)f2bf(sacc[ni][1]) << 16);
      w.y = (uint32_t)f2bf(sacc[ni][2]) | ((uint32_t)f2bf(sacc[ni][3]) << 16);
      *(uint2*)&Ps[wid][fr][ni * 16 + fq * 4] = w;
    }
    // PV: A = P[q][j], B = Vt[dh][j]
#pragma unroll
    for (int s2 = 0; s2 < 2; s2++) {
      s16x8 pa = *(const s16x8*)&Ps[wid][fr][s2 * 32 + fq * 8];
#pragma unroll
      for (int ni = 0; ni < 4; ni++) {
        s16x8 vf = *(const s16x8*)&Vs[ni * 16 + fr][s2 * 32 + fq * 8];
        yacc[ni] = __builtin_amdgcn_mfma_f32_16x16x32_bf16(pa, vf, yacc[ni], 0, 0, 0);
      }
    }
  }
  int b = bh >> 4, h = bh & 15;
  float lr[4];
#pragma unroll
  for (int r = 0; r < 4; r++) lr[r] = __shfl(lrun, fq * 4 + r, 64);
  float* yo = y + ((size_t)(b * LQ_ + qt * 64 + wid * 16 + fq * 4)) * D_ + h * 64;
#pragma unroll
  for (int ni = 0; ni < 4; ni++) {
#pragma unroll
    for (int r = 0; r < 4; r++)
      yo[(size_t)r * D_ + ni * 16 + fr] = yacc[ni][r] / lr[r];
  }
}

extern "C" void kernel_launch(void* const* d_in, const int* in_sizes, int n_in,
                              void* d_out, int out_size, void* d_ws, size_t ws_size,
                              hipStream_t stream) {
  (void)in_sizes; (void)n_in; (void)out_size;
  const float* queries = (const float*)d_in[0];
  const float* kv = (const float*)d_in[1];
  const float* wq = (const float*)d_in[2];
  const float* wkv = (const float*)d_in[3];
  const float* wo = (const float*)d_in[4];
  const float* qnw = (const float*)d_in[5];
  const float* knw = (const float*)d_in[6];
  const int* pos_q = (const int*)d_in[7];
  const int* pos_k = (const int*)d_in[8];
  float* out = (float*)d_out;

  char* ws = (char*)d_ws;
  size_t off = 0;
  auto alloc = [&](size_t sz) { void* p = ws + off; off += sz; return p; };
  u16* Aq3 = (u16*)alloc((size_t)4096 * 3072 * 2);   // reused as Y3 later
  u16* Wq3 = (u16*)alloc((size_t)1024 * 3072 * 2);
  u16* Akv3 = (u16*)alloc((size_t)8192 * 3072 * 2);
  u16* Wkv3 = (u16*)alloc((size_t)2048 * 3072 * 2);
  u16* Wo3 = (u16*)alloc((size_t)1024 * 3072 * 2);
  float* Qp = (float*)alloc((size_t)4096 * 1024 * 4);  // reused as Y later
  float* KVp = (float*)alloc((size_t)8192 * 2048 * 4);
  u16* Qb = (u16*)alloc((size_t)64 * 1024 * 64 * 2);
  u16* Kb = (u16*)alloc((size_t)64 * 2048 * 64 * 2);
  u16* Vt = (u16*)alloc((size_t)64 * 2048 * 64 * 2);
  if (off > ws_size) return;  // insufficient workspace — bail loudly (validation fails)

  u16* Y3 = Aq3;
  float* Y = Qp;

  // 1) Dekker splits: activations [hi|lo|hi], weights [hi|hi|lo]
  split3a_k<<<4096 * 1024 / 256, 256, 0, stream>>>(queries, Aq3, 4096 * 1024);
  split3w_k<<<1024 * 1024 / 256, 256, 0, stream>>>(wq, Wq3, 1024 * 1024);
  split3a_k<<<8192 * 1024 / 256, 256, 0, stream>>>(kv, Akv3, 8192 * 1024);
  split3w_k<<<2048 * 1024 / 256, 256, 0, stream>>>(wkv, Wkv3, 2048 * 1024);
  split3w_k<<<1024 * 1024 / 256, 256, 0, stream>>>(wo, Wo3, 1024 * 1024);
  // 2) projections (fp32-equivalent via 3-term split)
  gemm_bt<<<dim3(4096 / 128, 1024 / 128), 256, 0, stream>>>(Aq3, Wq3, Qp, 1024, 3072);
  gemm_bt<<<dim3(8192 / 128, 2048 / 128), 256, 0, stream>>>(Akv3, Wkv3, KVp, 2048, 3072);
  // 3) RMSNorm + RoPE -> bf16 head-major
  norm_rope_k<<<4096 * 16 / 4, 256, 0, stream>>>(Qp, 1024, 64, qnw, pos_q, Qb, 1024);
  norm_rope_k<<<8192 * 16 / 4, 256, 0, stream>>>(KVp, 2048, 128, knw, pos_k, Kb, 2048);
  vtrans_k<<<64 * 32, 256, 0, stream>>>(KVp, Vt);
  // 4) flash attention -> Y fp32 [b][lq][h*64+dh]
  flash_k<<<64 * 16, 256, 0, stream>>>(Qb, Kb, Vt, Y);
  // 5) output projection (split + GEMM) -> d_out
  split3a_k<<<4096 * 1024 / 256, 256, 0, stream>>>(Y, Y3, 4096 * 1024);
  gemm_bt<<<dim3(4096 / 128, 1024 / 128), 256, 0, stream>>>(Y3, Wo3, out, 1024, 3072);
}

// Round 4
// 472.747 us; speedup vs baseline: 1.1215x; 1.0595x over previous
//
#include <hip/hip_runtime.h>
#include <stdint.h>

typedef unsigned short u16;
typedef u16 u16x8 __attribute__((ext_vector_type(8)));
typedef short s16x8 __attribute__((ext_vector_type(8)));
typedef float f32x4 __attribute__((ext_vector_type(4)));

#define B_ 4
#define LQ_ 1024
#define LK_ 2048
#define D_ 1024
#define H_ 16
#define DH_ 64
#define K3_ 3072

__device__ __forceinline__ u16 f2bf(float x) {
  uint32_t u = __float_as_uint(x);
  u += 0x7FFFu + ((u >> 16) & 1u);   // round-to-nearest-even
  return (u16)(u >> 16);
}
__device__ __forceinline__ float bf2f(u16 h) {
  return __uint_as_float(((uint32_t)h) << 16);
}

// ---------- split (activation side): rows x 1024 fp32 -> rows x 3072 bf16 [hi | lo | hi]
__global__ __launch_bounds__(256) void split3a_k(const float* __restrict__ src,
                                                 u16* __restrict__ dst, int n) {
  int i = blockIdx.x * 256 + threadIdx.x;
  if (i >= n) return;
  int k = i & 1023;
  int r = i >> 10;
  float x = src[i];
  u16 hi = f2bf(x);
  u16 lo = f2bf(x - bf2f(hi));
  u16* d = dst + (size_t)r * 3072;
  d[k] = hi;
  d[1024 + k] = lo;
  d[2048 + k] = hi;
}

// ---------- split (weight side): rows x 1024 fp32 -> rows x 3072 bf16 [hi | hi | lo]
// Paired with the activation layout: hi*hi + lo*hi + hi*lo (Dekker 3-term).
__global__ __launch_bounds__(256) void split3w_k(const float* __restrict__ src,
                                                 u16* __restrict__ dst, int n) {
  int i = blockIdx.x * 256 + threadIdx.x;
  if (i >= n) return;
  int k = i & 1023;
  int r = i >> 10;
  float x = src[i];
  u16 hi = f2bf(x);
  u16 lo = f2bf(x - bf2f(hi));
  u16* d = dst + (size_t)r * 3072;
  d[k] = hi;
  d[1024 + k] = hi;
  d[2048 + k] = lo;
}

// ---------- small-tile GEMM (kept for Q/O projections): C = A * B^T, 128x128 ----------
__global__ __launch_bounds__(256) void gemm_bt(const u16* __restrict__ A,
                                               const u16* __restrict__ Bm,
                                               float* __restrict__ C,
                                               int N, int K) {
  __shared__ __align__(16) u16 As[128 * 32];
  __shared__ __align__(16) u16 Bs[128 * 32];
  const int tid = threadIdx.x;
  const int lane = tid & 63;
  const int wid = tid >> 6;
  const int m0 = blockIdx.x * 128;
  const int n0 = blockIdx.y * 128;
  const int wr = (wid >> 1) * 64;
  const int wc = (wid & 1) * 64;
  const int fr = lane & 15;
  const int fq = lane >> 4;
  const int srow = lane >> 2;
  const int schunk = lane & 3;

  f32x4 zero = {0.f, 0.f, 0.f, 0.f};
  f32x4 acc[4][4];
  for (int i = 0; i < 4; i++)
    for (int j = 0; j < 4; j++) acc[i][j] = zero;

  const int r0 = wid * 32;
  const u16* gA = A + (size_t)(m0 + r0 + srow) * K + schunk * 8;
  const u16* gB = Bm + (size_t)(n0 + r0 + srow) * K + schunk * 8;
  u16* lA = &As[r0 * 32];
  u16* lB = &Bs[r0 * 32];

  for (int k0 = 0; k0 < K; k0 += 32) {
    __syncthreads();
    __builtin_amdgcn_global_load_lds(
        (const __attribute__((address_space(1))) void*)(gA + k0),
        (__attribute__((address_space(3))) void*)(lA), 16, 0, 0);
    __builtin_amdgcn_global_load_lds(
        (const __attribute__((address_space(1))) void*)(gA + k0 + (size_t)16 * K),
        (__attribute__((address_space(3))) void*)(lA + 16 * 32), 16, 0, 0);
    __builtin_amdgcn_global_load_lds(
        (const __attribute__((address_space(1))) void*)(gB + k0),
        (__attribute__((address_space(3))) void*)(lB), 16, 0, 0);
    __builtin_amdgcn_global_load_lds(
        (const __attribute__((address_space(1))) void*)(gB + k0 + (size_t)16 * K),
        (__attribute__((address_space(3))) void*)(lB + 16 * 32), 16, 0, 0);
    asm volatile("s_waitcnt vmcnt(0)" ::: "memory");
    __syncthreads();

    s16x8 af[4], bf[4];
#pragma unroll
    for (int mi = 0; mi < 4; mi++)
      af[mi] = *(const s16x8*)&As[(wr + mi * 16 + fr) * 32 + fq * 8];
#pragma unroll
    for (int ni = 0; ni < 4; ni++)
      bf[ni] = *(const s16x8*)&Bs[(wc + ni * 16 + fr) * 32 + fq * 8];
#pragma unroll
    for (int mi = 0; mi < 4; mi++)
#pragma unroll
      for (int ni = 0; ni < 4; ni++)
        acc[mi][ni] = __builtin_amdgcn_mfma_f32_16x16x32_bf16(af[mi], bf[ni],
                                                              acc[mi][ni], 0, 0, 0);
  }
#pragma unroll
  for (int mi = 0; mi < 4; mi++) {
#pragma unroll
    for (int ni = 0; ni < 4; ni++) {
      int row = m0 + wr + mi * 16 + fq * 4;
      int col = n0 + wc + ni * 16 + fr;
#pragma unroll
      for (int r = 0; r < 4; r++) C[(size_t)(row + r) * N + col] = acc[mi][ni][r];
    }
  }
}

// ---------- 8-phase 256x128 GEMM (T2 swizzle + T3/T4 counted vmcnt + T5 setprio) ----------
// C[M,N] = A[M,K] * B[N,K]^T, bf16 in fp32 out. 512 threads = 8 waves (4 M x 2 N),
// per-wave output 64x64 (M_rep=4, N_rep=4), BK=64, 3-buffer LDS ring (144 KiB).
// LDS layout per buffer: A 256x64 (chunk-XOR-swizzled), B 128x64. Staging writes
// linear LDS (gload_lds) from inverse-swizzled GLOBAL source; reads apply the swizzle.
#define BAR8 asm volatile("s_barrier" ::: "memory")
__global__ __launch_bounds__(512, 2) void gemm_bt8(const u16* __restrict__ A,
                                                   const u16* __restrict__ Bm,
                                                   float* __restrict__ C,
                                                   int N, int K) {
  __shared__ __align__(16) u16 lds[73728];  // 3 x (16384 A + 8192 B) u16 = 144 KiB
  const int tid = threadIdx.x;
  const int lane = tid & 63;
  const int w = tid >> 6;
  const int wr = w >> 1;   // 0..3
  const int wc = w & 1;    // 0..1
  const int fr = lane & 15;
  const int fq = lane >> 4;
  // bijective XCD swizzle (grid is a multiple of 8)
  const int nwg = gridDim.x;
  const int cpx = nwg >> 3;
  const int bid = blockIdx.x;
  const int swz = (bid & 7) * cpx + (bid >> 3);
  const int nbn = N >> 7;
  const int bm = swz / nbn, bn = swz % nbn;
  const int gm0 = bm * 256, gn0 = bn * 128;
  const int NT = K >> 6;

  f32x4 zero = {0.f, 0.f, 0.f, 0.f};
  f32x4 acc[4][4];
#pragma unroll
  for (int i = 0; i < 4; i++)
#pragma unroll
    for (int j = 0; j < 4; j++) acc[i][j] = zero;

  // stage one 16B chunk per thread; s = 0..3 A-loads, 4..5 B-loads
  auto stage = [&](int buf, int u, int s) {
    int ku0 = u << 6;
    if (s < 4) {
      int q = s * 512 + tid;
      int row = q >> 3, p = q & 7;
      int l = p ^ (row & 7);  // inverse-swizzled global source
      const u16* src = A + (size_t)(gm0 + row) * K + ku0 + l * 8;
      u16* dst = &lds[buf * 24576 + (s * 512 + w * 64) * 8];  // wave-uniform + lane*16B
      __builtin_amdgcn_global_load_lds(
          (const __attribute__((address_space(1))) void*)src,
          (__attribute__((address_space(3))) void*)dst, 16, 0, 0);
    } else {
      int q = (s - 4) * 512 + tid;
      int row = q >> 3, p = q & 7;
      int l = p ^ (row & 7);
      const u16* src = Bm + (size_t)(gn0 + row) * K + ku0 + l * 8;
      u16* dst = &lds[buf * 24576 + 16384 + ((s - 4) * 512 + w * 64) * 8];
      __builtin_amdgcn_global_load_lds(
          (const __attribute__((address_space(1))) void*)src,
          (__attribute__((address_space(3))) void*)dst, 16, 0, 0);
    }
  };
  auto rdA = [&](int buf, int mi, int kk) -> s16x8 {
    int row = wr * 64 + mi * 16 + fr;
    int l = (kk * 4 + fq) ^ (fr & 7);  // swizzled read
    return *(const s16x8*)&lds[buf * 24576 + row * 64 + l * 8];
  };
  auto rdB = [&](int buf, int ni, int kk) -> s16x8 {
    int row = wc * 64 + ni * 16 + fr;
    int l = (kk * 4 + fq) ^ (fr & 7);
    return *(const s16x8*)&lds[buf * 24576 + 16384 + row * 64 + l * 8];
  };

  s16x8 af[4][2], bf[4][2];

  // prologue: stage tiles 0 and 1; wait tile 0 (6 loads of tile 1 stay in flight)
#pragma unroll
  for (int s = 0; s < 6; s++) stage(0, 0, s);
#pragma unroll
  for (int s = 0; s < 6; s++) stage(1, 1, s);
  asm volatile("s_waitcnt vmcnt(6)" ::: "memory");
  BAR8;

  int cur = 0, stg = 2;
  for (int t = 0; t < NT; t++) {
    const bool st = (t + 2 < NT);
    // ---- phase 0: read A{0,1}+B{0,1}, stage 2, MFMA quadrant (mi01 x ni01)
#pragma unroll
    for (int mi = 0; mi < 2; mi++)
#pragma unroll
      for (int kk = 0; kk < 2; kk++) af[mi][kk] = rdA(cur, mi, kk);
#pragma unroll
    for (int ni = 0; ni < 2; ni++)
#pragma unroll
      for (int kk = 0; kk < 2; kk++) bf[ni][kk] = rdB(cur, ni, kk);
    if (st) { stage(stg, t + 2, 0); stage(stg, t + 2, 1); }
    BAR8;
    __builtin_amdgcn_s_setprio(1);
#pragma unroll
    for (int mi = 0; mi < 2; mi++)
#pragma unroll
      for (int ni = 0; ni < 2; ni++)
#pragma unroll
        for (int kk = 0; kk < 2; kk++)
          acc[mi][ni] = __builtin_amdgcn_mfma_f32_16x16x32_bf16(af[mi][kk], bf[ni][kk],
                                                                acc[mi][ni], 0, 0, 0);
    __builtin_amdgcn_s_setprio(0);
    BAR8;
    // ---- phase 1: read B{2,3}, stage 2, MFMA (mi01 x ni23)
#pragma unroll
    for (int ni = 2; ni < 4; ni++)
#pragma unroll
      for (int kk = 0; kk < 2; kk++) bf[ni][kk] = rdB(cur, ni, kk);
    if (st) { stage(stg, t + 2, 2); stage(stg, t + 2, 3); }
    BAR8;
    __builtin_amdgcn_s_setprio(1);
#pragma unroll
    for (int mi = 0; mi < 2; mi++)
#pragma unroll
      for (int ni = 2; ni < 4; ni++)
#pragma unroll
        for (int kk = 0; kk < 2; kk++)
          acc[mi][ni] = __builtin_amdgcn_mfma_f32_16x16x32_bf16(af[mi][kk], bf[ni][kk],
                                                                acc[mi][ni], 0, 0, 0);
    __builtin_amdgcn_s_setprio(0);
    BAR8;
    // ---- phase 2: read A{2,3}, stage 1, MFMA (mi23 x ni23)
#pragma unroll
    for (int mi = 2; mi < 4; mi++)
#pragma unroll
      for (int kk = 0; kk < 2; kk++) af[mi][kk] = rdA(cur, mi, kk);
    if (st) stage(stg, t + 2, 4);
    BAR8;
    __builtin_amdgcn_s_setprio(1);
#pragma unroll
    for (int mi = 2; mi < 4; mi++)
#pragma unroll
      for (int ni = 2; ni < 4; ni++)
#pragma unroll
        for (int kk = 0; kk < 2; kk++)
          acc[mi][ni] = __builtin_amdgcn_mfma_f32_16x16x32_bf16(af[mi][kk], bf[ni][kk],
                                                                acc[mi][ni], 0, 0, 0);
    __builtin_amdgcn_s_setprio(0);
    BAR8;
    // ---- phase 3: stage 1, counted vmcnt (next tile ready), MFMA (mi23 x ni01)
    if (st) stage(stg, t + 2, 5);
    if (t + 2 < NT) {
      asm volatile("s_waitcnt vmcnt(6)" ::: "memory");  // t+1 landed; t+2's 6 in flight
    } else {
      asm volatile("s_waitcnt vmcnt(0)" ::: "memory");  // tail drain
    }
    BAR8;
    __builtin_amdgcn_s_setprio(1);
#pragma unroll
    for (int mi = 2; mi < 4; mi++)
#pragma unroll
      for (int ni = 0; ni < 2; ni++)
#pragma unroll
        for (int kk = 0; kk < 2; kk++)
          acc[mi][ni] = __builtin_amdgcn_mfma_f32_16x16x32_bf16(af[mi][kk], bf[ni][kk],
                                                                acc[mi][ni], 0, 0, 0);
    __builtin_amdgcn_s_setprio(0);
    BAR8;
    cur = (cur == 2) ? 0 : cur + 1;
    stg = (stg == 2) ? 0 : stg + 1;
  }
  // epilogue
#pragma unroll
  for (int mi = 0; mi < 4; mi++) {
#pragma unroll
    for (int ni = 0; ni < 4; ni++) {
      int row = gm0 + wr * 64 + mi * 16 + fq * 4;
      int col = gn0 + wc * 64 + ni * 16 + fr;
#pragma unroll
      for (int r = 0; r < 4; r++) C[(size_t)(row + r) * N + col] = acc[mi][ni][r];
    }
  }
}

// ---------- per-head RMSNorm + RoPE, fp32 in -> bf16 [b][h][l][64] out ----------
__global__ __launch_bounds__(256) void norm_rope_k(const float* __restrict__ src,
                                                   int srcStride, int hs,
                                                   const float* __restrict__ w,
                                                   const int* __restrict__ pos,
                                                   u16* __restrict__ dst, int L) {
  int wid = threadIdx.x >> 6;
  int lane = threadIdx.x & 63;
  int g = blockIdx.x * 4 + wid;  // (b*L + l)*H + h
  int h = g & 15;
  int bl = g >> 4;
  int b = bl / L;
  int l = bl - b * L;
  float x = src[(size_t)bl * srcStride + h * hs + lane];
  float ss = x * x;
#pragma unroll
  for (int m = 1; m < 64; m <<= 1) ss += __shfl_xor(ss, m, 64);
  float xn = x * rsqrtf(ss * (1.0f / 64.0f) + 1e-6f) * w[lane];
  float p = __shfl_xor(xn, 32, 64);
  int j = lane & 31;
  float freq = powf(10000.0f, -(float)j * (1.0f / 32.0f));
  float ang = (float)pos[l] * freq;
  float c = cosf(ang), s = sinf(ang);
  float o = (lane < 32) ? (xn * c - p * s) : (p * s + xn * c);
  dst[((size_t)(b * 16 + h) * L + l) * 64 + lane] = f2bf(o);
}

// ---------- V transpose: kvp v-part -> vt[b][h][dh][lk] bf16 ----------
__global__ __launch_bounds__(256) void vtrans_k(const float* __restrict__ kvp,
                                                u16* __restrict__ vt) {
  __shared__ float tile[64][65];
  int kt = blockIdx.x & 31;  // LK/64
  int bh = blockIdx.x >> 5;
  int h = bh & 15;
  int b = bh >> 4;
  int c = threadIdx.x & 63;
  int r4 = threadIdx.x >> 6;
  const float* src = kvp + ((size_t)(b * LK_ + kt * 64)) * 2048 + h * 128 + 64;
#pragma unroll
  for (int p = 0; p < 16; p++) {
    int lk = p * 4 + r4;
    tile[lk][c] = src[(size_t)lk * 2048 + c];
  }
  __syncthreads();
  u16* dst = vt + (size_t)bh * 64 * LK_ + kt * 64;
#pragma unroll
  for (int p = 0; p < 16; p++) {
    int dh = p * 4 + r4;
    dst[(size_t)dh * LK_ + c] = f2bf(tile[c][dh]);
  }
}

// ---------- flash attention (swapped QK^T: lane-local softmax) ----------
__global__ __launch_bounds__(256) void flash_k(const u16* __restrict__ qb,
                                               const u16* __restrict__ kb,
                                               const u16* __restrict__ vb,
                                               float* __restrict__ y) {
  __shared__ __align__(16) u16 Ks[64][72];
  __shared__ __align__(16) u16 Vs[64][72];       // Vs[dh][kv]
  __shared__ __align__(16) u16 Ps[4][16][72];    // per-wave P[q][j]
  const int tid = threadIdx.x;
  const int lane = tid & 63;
  const int wid = tid >> 6;
  const int fr = lane & 15;
  const int fq = lane >> 4;
  int qt = blockIdx.x & 15;  // LQ/64
  int bh = blockIdx.x >> 4;  // b*16+h
  const u16* qbase = qb + ((size_t)bh * LQ_ + qt * 64 + wid * 16) * 64;
  const u16* kbase = kb + (size_t)bh * LK_ * 64;
  const u16* vbase = vb + (size_t)bh * 64 * LK_;
  s16x8 qf0 = *(const s16x8*)(qbase + (size_t)fr * 64 + fq * 8);
  s16x8 qf1 = *(const s16x8*)(qbase + (size_t)fr * 64 + 32 + fq * 8);
  float mrun = -1e30f, lrun = 0.f;  // lane owns q-row fr
  f32x4 zero = {0.f, 0.f, 0.f, 0.f};
  f32x4 yacc[4];
#pragma unroll
  for (int ni = 0; ni < 4; ni++) yacc[ni] = zero;
  const int srow = tid >> 3;
  const int schunk = tid & 7;

  for (int kt = 0; kt < LK_; kt += 64) {
    __syncthreads();
#pragma unroll
    for (int ps = 0; ps < 2; ps++) {
      int row = srow + ps * 32;
      *(u16x8*)&Ks[row][schunk * 8] =
          *(const u16x8*)(kbase + (size_t)(kt + row) * 64 + schunk * 8);
      *(u16x8*)&Vs[row][schunk * 8] =
          *(const u16x8*)(vbase + (size_t)row * LK_ + kt + schunk * 8);
    }
    __syncthreads();
    f32x4 sacc[4];
#pragma unroll
    for (int ni = 0; ni < 4; ni++) sacc[ni] = zero;
#pragma unroll
    for (int ni = 0; ni < 4; ni++) {
      s16x8 kf0 = *(const s16x8*)&Ks[ni * 16 + fr][fq * 8];
      s16x8 kf1 = *(const s16x8*)&Ks[ni * 16 + fr][32 + fq * 8];
      sacc[ni] = __builtin_amdgcn_mfma_f32_16x16x32_bf16(kf0, qf0, sacc[ni], 0, 0, 0);
      sacc[ni] = __builtin_amdgcn_mfma_f32_16x16x32_bf16(kf1, qf1, sacc[ni], 0, 0, 0);
    }
    float mx = -1e30f;
#pragma unroll
    for (int ni = 0; ni < 4; ni++)
#pragma unroll
      for (int r = 0; r < 4; r++) {
        float sv = sacc[ni][r] * 0.125f;
        sacc[ni][r] = sv;
        mx = fmaxf(mx, sv);
      }
    mx = fmaxf(mx, __shfl_xor(mx, 16, 64));
    mx = fmaxf(mx, __shfl_xor(mx, 32, 64));
    float mn = fmaxf(mrun, mx);
    float alpha = __expf(mrun - mn);
    mrun = mn;
    float ts = 0.f;
#pragma unroll
    for (int ni = 0; ni < 4; ni++)
#pragma unroll
      for (int r = 0; r < 4; r++) {
        float pv = __expf(sacc[ni][r] - mn);
        sacc[ni][r] = pv;
        ts += pv;
      }
    ts += __shfl_xor(ts, 16, 64);
    ts += __shfl_xor(ts, 32, 64);
    lrun = lrun * alpha + ts;
    float va[4];
#pragma unroll
    for (int r = 0; r < 4; r++) va[r] = __shfl(alpha, fq * 4 + r, 64);
#pragma unroll
    for (int ni = 0; ni < 4; ni++)
#pragma unroll
      for (int r = 0; r < 4; r++) yacc[ni][r] *= va[r];
#pragma unroll
    for (int ni = 0; ni < 4; ni++) {
      uint2 wv;
      wv.x = (uint32_t)f2bf(sacc[ni][0]) | ((uint32_t)f2bf(sacc[ni][1]) << 16);
      wv.y = (uint32_t)f2bf(sacc[ni][2]) | ((uint32_t)f2bf(sacc[ni][3]) << 16);
      *(uint2*)&Ps[wid][fr][ni * 16 + fq * 4] = wv;
    }
#pragma unroll
    for (int s2 = 0; s2 < 2; s2++) {
      s16x8 pa = *(const s16x8*)&Ps[wid][fr][s2 * 32 + fq * 8];
#pragma unroll
      for (int ni = 0; ni < 4; ni++) {
        s16x8 vf = *(const s16x8*)&Vs[ni * 16 + fr][s2 * 32 + fq * 8];
        yacc[ni] = __builtin_amdgcn_mfma_f32_16x16x32_bf16(pa, vf, yacc[ni], 0, 0, 0);
      }
    }
  }
  int b = bh >> 4, h = bh & 15;
  float lr[4];
#pragma unroll
  for (int r = 0; r < 4; r++) lr[r] = __shfl(lrun, fq * 4 + r, 64);
  float* yo = y + ((size_t)(b * LQ_ + qt * 64 + wid * 16 + fq * 4)) * D_ + h * 64;
#pragma unroll
  for (int ni = 0; ni < 4; ni++) {
#pragma unroll
    for (int r = 0; r < 4; r++)
      yo[(size_t)r * D_ + ni * 16 + fr] = yacc[ni][r] / lr[r];
  }
}

extern "C" void kernel_launch(void* const* d_in, const int* in_sizes, int n_in,
                              void* d_out, int out_size, void* d_ws, size_t ws_size,
                              hipStream_t stream) {
  (void)in_sizes; (void)n_in; (void)out_size;
  const float* queries = (const float*)d_in[0];
  const float* kv = (const float*)d_in[1];
  const float* wq = (const float*)d_in[2];
  const float* wkv = (const float*)d_in[3];
  const float* wo = (const float*)d_in[4];
  const float* qnw = (const float*)d_in[5];
  const float* knw = (const float*)d_in[6];
  const int* pos_q = (const int*)d_in[7];
  const int* pos_k = (const int*)d_in[8];
  float* out = (float*)d_out;

  char* ws = (char*)d_ws;
  size_t off = 0;
  auto alloc = [&](size_t sz) { void* p = ws + off; off += sz; return p; };
  u16* Aq3 = (u16*)alloc((size_t)4096 * 3072 * 2);   // reused as Y3 later
  u16* Wq3 = (u16*)alloc((size_t)1024 * 3072 * 2);
  u16* Akv3 = (u16*)alloc((size_t)8192 * 3072 * 2);
  u16* Wkv3 = (u16*)alloc((size_t)2048 * 3072 * 2);
  u16* Wo3 = (u16*)alloc((size_t)1024 * 3072 * 2);
  float* Qp = (float*)alloc((size_t)4096 * 1024 * 4);  // reused as Y later
  float* KVp = (float*)alloc((size_t)8192 * 2048 * 4);
  u16* Qb = (u16*)alloc((size_t)64 * 1024 * 64 * 2);
  u16* Kb = (u16*)alloc((size_t)64 * 2048 * 64 * 2);
  u16* Vt = (u16*)alloc((size_t)64 * 2048 * 64 * 2);
  if (off > ws_size) return;  // insufficient workspace — bail loudly (validation fails)

  u16* Y3 = Aq3;
  float* Y = Qp;

  // 1) Dekker splits: activations [hi|lo|hi], weights [hi|hi|lo]
  split3a_k<<<4096 * 1024 / 256, 256, 0, stream>>>(queries, Aq3, 4096 * 1024);
  split3w_k<<<1024 * 1024 / 256, 256, 0, stream>>>(wq, Wq3, 1024 * 1024);
  split3a_k<<<8192 * 1024 / 256, 256, 0, stream>>>(kv, Akv3, 8192 * 1024);
  split3w_k<<<2048 * 1024 / 256, 256, 0, stream>>>(wkv, Wkv3, 2048 * 1024);
  split3w_k<<<1024 * 1024 / 256, 256, 0, stream>>>(wo, Wo3, 1024 * 1024);
  // 2) projections: KV via 8-phase 256x128 kernel (512 blocks), Q via 128^2
  gemm_bt<<<dim3(4096 / 128, 1024 / 128), 256, 0, stream>>>(Aq3, Wq3, Qp, 1024, 3072);
  gemm_bt8<<<(8192 / 256) * (2048 / 128), 512, 0, stream>>>(Akv3, Wkv3, KVp, 2048, 3072);
  // 3) RMSNorm + RoPE -> bf16 head-major
  norm_rope_k<<<4096 * 16 / 4, 256, 0, stream>>>(Qp, 1024, 64, qnw, pos_q, Qb, 1024);
  norm_rope_k<<<8192 * 16 / 4, 256, 0, stream>>>(KVp, 2048, 128, knw, pos_k, Kb, 2048);
  vtrans_k<<<64 * 32, 256, 0, stream>>>(KVp, Vt);
  // 4) flash attention -> Y fp32 [b][lq][h*64+dh]
  flash_k<<<64 * 16, 256, 0, stream>>>(Qb, Kb, Vt, Y);
  // 5) output projection (split + GEMM) -> d_out
  split3a_k<<<4096 * 1024 / 256, 256, 0, stream>>>(Y, Y3, 4096 * 1024);
  gemm_bt<<<dim3(4096 / 128, 1024 / 128), 256, 0, stream>>>(Y3, Wo3, out, 1024, 3072);
}

// Round 5
// 450.082 us; speedup vs baseline: 1.1780x; 1.0504x over previous
//
#include <hip/hip_runtime.h>
#include <stdint.h>

typedef unsigned short u16;
typedef u16 u16x8 __attribute__((ext_vector_type(8)));
typedef short s16x8 __attribute__((ext_vector_type(8)));
typedef float f32x4 __attribute__((ext_vector_type(4)));

#define B_ 4
#define LQ_ 1024
#define LK_ 2048
#define D_ 1024
#define H_ 16
#define DH_ 64
#define K3_ 3072

__device__ __forceinline__ u16 f2bf(float x) {
  uint32_t u = __float_as_uint(x);
  u += 0x7FFFu + ((u >> 16) & 1u);   // round-to-nearest-even
  return (u16)(u >> 16);
}
__device__ __forceinline__ float bf2f(u16 h) {
  return __uint_as_float(((uint32_t)h) << 16);
}

// ---------- split (activation side): rows x 1024 fp32 -> rows x 3072 bf16 [hi | lo | hi]
__global__ __launch_bounds__(256) void split3a_k(const float* __restrict__ src,
                                                 u16* __restrict__ dst, int n) {
  int i = blockIdx.x * 256 + threadIdx.x;
  if (i >= n) return;
  int k = i & 1023;
  int r = i >> 10;
  float x = src[i];
  u16 hi = f2bf(x);
  u16 lo = f2bf(x - bf2f(hi));
  u16* d = dst + (size_t)r * 3072;
  d[k] = hi;
  d[1024 + k] = lo;
  d[2048 + k] = hi;
}

// ---------- split (weight side): rows x 1024 fp32 -> rows x 3072 bf16 [hi | hi | lo]
// Paired with the activation layout: hi*hi + lo*hi + hi*lo (Dekker 3-term).
__global__ __launch_bounds__(256) void split3w_k(const float* __restrict__ src,
                                                 u16* __restrict__ dst, int n) {
  int i = blockIdx.x * 256 + threadIdx.x;
  if (i >= n) return;
  int k = i & 1023;
  int r = i >> 10;
  float x = src[i];
  u16 hi = f2bf(x);
  u16 lo = f2bf(x - bf2f(hi));
  u16* d = dst + (size_t)r * 3072;
  d[k] = hi;
  d[1024 + k] = hi;
  d[2048 + k] = lo;
}

// ---------- small-tile GEMM (kept for Q/O projections): C = A * B^T, 128x128 ----------
__global__ __launch_bounds__(256) void gemm_bt(const u16* __restrict__ A,
                                               const u16* __restrict__ Bm,
                                               float* __restrict__ C,
                                               int N, int K) {
  __shared__ __align__(16) u16 As[128 * 32];
  __shared__ __align__(16) u16 Bs[128 * 32];
  const int tid = threadIdx.x;
  const int lane = tid & 63;
  const int wid = tid >> 6;
  const int m0 = blockIdx.x * 128;
  const int n0 = blockIdx.y * 128;
  const int wr = (wid >> 1) * 64;
  const int wc = (wid & 1) * 64;
  const int fr = lane & 15;
  const int fq = lane >> 4;
  const int srow = lane >> 2;
  const int schunk = lane & 3;

  f32x4 zero = {0.f, 0.f, 0.f, 0.f};
  f32x4 acc[4][4];
  for (int i = 0; i < 4; i++)
    for (int j = 0; j < 4; j++) acc[i][j] = zero;

  const int r0 = wid * 32;
  const u16* gA = A + (size_t)(m0 + r0 + srow) * K + schunk * 8;
  const u16* gB = Bm + (size_t)(n0 + r0 + srow) * K + schunk * 8;
  u16* lA = &As[r0 * 32];
  u16* lB = &Bs[r0 * 32];

  for (int k0 = 0; k0 < K; k0 += 32) {
    __syncthreads();
    __builtin_amdgcn_global_load_lds(
        (const __attribute__((address_space(1))) void*)(gA + k0),
        (__attribute__((address_space(3))) void*)(lA), 16, 0, 0);
    __builtin_amdgcn_global_load_lds(
        (const __attribute__((address_space(1))) void*)(gA + k0 + (size_t)16 * K),
        (__attribute__((address_space(3))) void*)(lA + 16 * 32), 16, 0, 0);
    __builtin_amdgcn_global_load_lds(
        (const __attribute__((address_space(1))) void*)(gB + k0),
        (__attribute__((address_space(3))) void*)(lB), 16, 0, 0);
    __builtin_amdgcn_global_load_lds(
        (const __attribute__((address_space(1))) void*)(gB + k0 + (size_t)16 * K),
        (__attribute__((address_space(3))) void*)(lB + 16 * 32), 16, 0, 0);
    asm volatile("s_waitcnt vmcnt(0)" ::: "memory");
    __syncthreads();

    s16x8 af[4], bf[4];
#pragma unroll
    for (int mi = 0; mi < 4; mi++)
      af[mi] = *(const s16x8*)&As[(wr + mi * 16 + fr) * 32 + fq * 8];
#pragma unroll
    for (int ni = 0; ni < 4; ni++)
      bf[ni] = *(const s16x8*)&Bs[(wc + ni * 16 + fr) * 32 + fq * 8];
#pragma unroll
    for (int mi = 0; mi < 4; mi++)
#pragma unroll
      for (int ni = 0; ni < 4; ni++)
        acc[mi][ni] = __builtin_amdgcn_mfma_f32_16x16x32_bf16(af[mi], bf[ni],
                                                              acc[mi][ni], 0, 0, 0);
  }
#pragma unroll
  for (int mi = 0; mi < 4; mi++) {
#pragma unroll
    for (int ni = 0; ni < 4; ni++) {
      int row = m0 + wr + mi * 16 + fq * 4;
      int col = n0 + wc + ni * 16 + fr;
#pragma unroll
      for (int r = 0; r < 4; r++) C[(size_t)(row + r) * N + col] = acc[mi][ni][r];
    }
  }
}

// ---------- 256x256 4-phase GEMM (T1 XCD swizzle + T2 LDS swizzle + T4 early-issue + T5) ----
// C[M,N] = A[M,K] * B[N,K]^T, bf16 in fp32 out. 512 threads = 8 waves (2M x 4N),
// per-wave output 128x64 (acc[8][4]), BK=64, double-buffered LDS 128 KiB.
// Stage loads of tile t+1 issue in phases 1-2 (>=2 phases before the boundary wait).
#define BAR8 asm volatile("s_barrier" ::: "memory")
__global__ __launch_bounds__(512, 2) void gemm_bt256(const u16* __restrict__ A,
                                                     const u16* __restrict__ Bm,
                                                     float* __restrict__ C,
                                                     int N, int K) {
  __shared__ __align__(16) u16 lds[65536];  // 2 x (A 256x64 + B 256x64) u16 = 128 KiB
  const int tid = threadIdx.x;
  const int lane = tid & 63;
  const int w = tid >> 6;
  const int wr = w >> 2;   // 0..1 (M)
  const int wc = w & 3;    // 0..3 (N)
  const int fr = lane & 15;
  const int fq = lane >> 4;
  // bijective XCD swizzle (grid multiple of 8)
  const int nwg = gridDim.x;
  const int cpx = nwg >> 3;
  const int bid = blockIdx.x;
  const int swz = (bid & 7) * cpx + (bid >> 3);
  const int nbn = N >> 8;
  const int bm = swz / nbn, bn = swz % nbn;
  const int gm0 = bm * 256, gn0 = bn * 256;
  const int NT = K >> 6;

  f32x4 zero = {0.f, 0.f, 0.f, 0.f};
  f32x4 acc[8][4];
#pragma unroll
  for (int i = 0; i < 8; i++)
#pragma unroll
    for (int j = 0; j < 4; j++) acc[i][j] = zero;

  // stage one 16B chunk per thread; s = 0..3 A, 4..7 B. LDS dest linear,
  // global source inverse-chunk-swizzled (rule #21 both-sides involution).
  auto stage = [&](int buf, int t, int s) {
    int q = (s & 3) * 512 + tid;
    int row = q >> 3, p = q & 7;
    int l = p ^ (row & 7);
    const u16* src = ((s < 4) ? A + (size_t)(gm0 + row) * K
                              : Bm + (size_t)(gn0 + row) * K) + (t << 6) + l * 8;
    u16* dst = &lds[buf * 32768 + ((s < 4) ? 0 : 16384) + ((s & 3) * 512 + w * 64) * 8];
    __builtin_amdgcn_global_load_lds(
        (const __attribute__((address_space(1))) void*)src,
        (__attribute__((address_space(3))) void*)dst, 16, 0, 0);
  };
  auto rdA = [&](int buf, int mi, int kk) -> s16x8 {  // mi logical 0..7
    int row = wr * 128 + mi * 16 + fr;
    int l = (kk * 4 + fq) ^ (fr & 7);
    return *(const s16x8*)&lds[buf * 32768 + row * 64 + l * 8];
  };
  auto rdB = [&](int buf, int ni, int kk) -> s16x8 {
    int row = wc * 64 + ni * 16 + fr;
    int l = (kk * 4 + fq) ^ (fr & 7);
    return *(const s16x8*)&lds[buf * 32768 + 16384 + row * 64 + l * 8];
  };

  s16x8 af[4][2], bf[4][2];

  // prologue: stage tile 0 into buf 0
#pragma unroll
  for (int s = 0; s < 8; s++) stage(0, 0, s);
  asm volatile("s_waitcnt vmcnt(0)" ::: "memory");
  BAR8;

  for (int t = 0; t < NT; t++) {
    const int cur = t & 1;
    const bool st = (t + 1 < NT);
    // ---- phase 1: read A-lo + B-lo frags; stage A of t+1; MFMA (mi0-3 x ni0-1)
#pragma unroll
    for (int mi = 0; mi < 4; mi++)
#pragma unroll
      for (int kk = 0; kk < 2; kk++) af[mi][kk] = rdA(cur, mi, kk);
#pragma unroll
    for (int ni = 0; ni < 2; ni++)
#pragma unroll
      for (int kk = 0; kk < 2; kk++) bf[ni][kk] = rdB(cur, ni, kk);
    if (st) {
#pragma unroll
      for (int s = 0; s < 4; s++) stage(cur ^ 1, t + 1, s);
    }
    BAR8;
    __builtin_amdgcn_s_setprio(1);
#pragma unroll
    for (int mi = 0; mi < 4; mi++)
#pragma unroll
      for (int ni = 0; ni < 2; ni++)
#pragma unroll
        for (int kk = 0; kk < 2; kk++)
          acc[mi][ni] = __builtin_amdgcn_mfma_f32_16x16x32_bf16(af[mi][kk], bf[ni][kk],
                                                                acc[mi][ni], 0, 0, 0);
    __builtin_amdgcn_s_setprio(0);
    BAR8;
    // ---- phase 2: read B-hi frags; stage B of t+1; MFMA (mi0-3 x ni2-3)
#pragma unroll
    for (int ni = 2; ni < 4; ni++)
#pragma unroll
      for (int kk = 0; kk < 2; kk++) bf[ni][kk] = rdB(cur, ni, kk);
    if (st) {
#pragma unroll
      for (int s = 4; s < 8; s++) stage(cur ^ 1, t + 1, s);
    }
    BAR8;
    __builtin_amdgcn_s_setprio(1);
#pragma unroll
    for (int mi = 0; mi < 4; mi++)
#pragma unroll
      for (int ni = 2; ni < 4; ni++)
#pragma unroll
        for (int kk = 0; kk < 2; kk++)
          acc[mi][ni] = __builtin_amdgcn_mfma_f32_16x16x32_bf16(af[mi][kk], bf[ni][kk],
                                                                acc[mi][ni], 0, 0, 0);
    __builtin_amdgcn_s_setprio(0);
    BAR8;
    // ---- phase 3: read A-hi frags (reuse af regs); MFMA (mi4-7 x ni2-3)
#pragma unroll
    for (int mi = 0; mi < 4; mi++)
#pragma unroll
      for (int kk = 0; kk < 2; kk++) af[mi][kk] = rdA(cur, mi + 4, kk);
    BAR8;
    __builtin_amdgcn_s_setprio(1);
#pragma unroll
    for (int mi = 0; mi < 4; mi++)
#pragma unroll
      for (int ni = 2; ni < 4; ni++)
#pragma unroll
        for (int kk = 0; kk < 2; kk++)
          acc[mi + 4][ni] = __builtin_amdgcn_mfma_f32_16x16x32_bf16(
              af[mi][kk], bf[ni][kk], acc[mi + 4][ni], 0, 0, 0);
    __builtin_amdgcn_s_setprio(0);
    BAR8;
    // ---- phase 4: boundary wait (loads 2-3 phases old -> near-free); MFMA (mi4-7 x ni0-1)
    asm volatile("s_waitcnt vmcnt(0)" ::: "memory");
    BAR8;
    __builtin_amdgcn_s_setprio(1);
#pragma unroll
    for (int mi = 0; mi < 4; mi++)
#pragma unroll
      for (int ni = 0; ni < 2; ni++)
#pragma unroll
        for (int kk = 0; kk < 2; kk++)
          acc[mi + 4][ni] = __builtin_amdgcn_mfma_f32_16x16x32_bf16(
              af[mi][kk], bf[ni][kk], acc[mi + 4][ni], 0, 0, 0);
    __builtin_amdgcn_s_setprio(0);
    BAR8;
  }
  // epilogue
#pragma unroll
  for (int mi = 0; mi < 8; mi++) {
#pragma unroll
    for (int ni = 0; ni < 4; ni++) {
      int row = gm0 + wr * 128 + mi * 16 + fq * 4;
      int col = gn0 + wc * 64 + ni * 16 + fr;
#pragma unroll
      for (int r = 0; r < 4; r++) C[(size_t)(row + r) * N + col] = acc[mi][ni][r];
    }
  }
}

// ---------- per-head RMSNorm + RoPE, fp32 in -> bf16 [b][h][l][64] out ----------
__global__ __launch_bounds__(256) void norm_rope_k(const float* __restrict__ src,
                                                   int srcStride, int hs,
                                                   const float* __restrict__ w,
                                                   const int* __restrict__ pos,
                                                   u16* __restrict__ dst, int L) {
  int wid = threadIdx.x >> 6;
  int lane = threadIdx.x & 63;
  int g = blockIdx.x * 4 + wid;  // (b*L + l)*H + h
  int h = g & 15;
  int bl = g >> 4;
  int b = bl / L;
  int l = bl - b * L;
  float x = src[(size_t)bl * srcStride + h * hs + lane];
  float ss = x * x;
#pragma unroll
  for (int m = 1; m < 64; m <<= 1) ss += __shfl_xor(ss, m, 64);
  float xn = x * rsqrtf(ss * (1.0f / 64.0f) + 1e-6f) * w[lane];
  float p = __shfl_xor(xn, 32, 64);
  int j = lane & 31;
  float freq = powf(10000.0f, -(float)j * (1.0f / 32.0f));
  float ang = (float)pos[l] * freq;
  float c = cosf(ang), s = sinf(ang);
  float o = (lane < 32) ? (xn * c - p * s) : (p * s + xn * c);
  dst[((size_t)(b * 16 + h) * L + l) * 64 + lane] = f2bf(o);
}

// ---------- V transpose: kvp v-part -> vt[b][h][dh][lk] bf16 ----------
__global__ __launch_bounds__(256) void vtrans_k(const float* __restrict__ kvp,
                                                u16* __restrict__ vt) {
  __shared__ float tile[64][65];
  int kt = blockIdx.x & 31;  // LK/64
  int bh = blockIdx.x >> 5;
  int h = bh & 15;
  int b = bh >> 4;
  int c = threadIdx.x & 63;
  int r4 = threadIdx.x >> 6;
  const float* src = kvp + ((size_t)(b * LK_ + kt * 64)) * 2048 + h * 128 + 64;
#pragma unroll
  for (int p = 0; p < 16; p++) {
    int lk = p * 4 + r4;
    tile[lk][c] = src[(size_t)lk * 2048 + c];
  }
  __syncthreads();
  u16* dst = vt + (size_t)bh * 64 * LK_ + kt * 64;
#pragma unroll
  for (int p = 0; p < 16; p++) {
    int dh = p * 4 + r4;
    dst[(size_t)dh * LK_ + c] = f2bf(tile[c][dh]);
  }
}

// ---------- flash attention (swapped QK^T: lane-local softmax) ----------
__global__ __launch_bounds__(256) void flash_k(const u16* __restrict__ qb,
                                               const u16* __restrict__ kb,
                                               const u16* __restrict__ vb,
                                               float* __restrict__ y) {
  __shared__ __align__(16) u16 Ks[64][72];
  __shared__ __align__(16) u16 Vs[64][72];       // Vs[dh][kv]
  __shared__ __align__(16) u16 Ps[4][16][72];    // per-wave P[q][j]
  const int tid = threadIdx.x;
  const int lane = tid & 63;
  const int wid = tid >> 6;
  const int fr = lane & 15;
  const int fq = lane >> 4;
  int qt = blockIdx.x & 15;  // LQ/64
  int bh = blockIdx.x >> 4;  // b*16+h
  const u16* qbase = qb + ((size_t)bh * LQ_ + qt * 64 + wid * 16) * 64;
  const u16* kbase = kb + (size_t)bh * LK_ * 64;
  const u16* vbase = vb + (size_t)bh * 64 * LK_;
  s16x8 qf0 = *(const s16x8*)(qbase + (size_t)fr * 64 + fq * 8);
  s16x8 qf1 = *(const s16x8*)(qbase + (size_t)fr * 64 + 32 + fq * 8);
  float mrun = -1e30f, lrun = 0.f;  // lane owns q-row fr
  f32x4 zero = {0.f, 0.f, 0.f, 0.f};
  f32x4 yacc[4];
#pragma unroll
  for (int ni = 0; ni < 4; ni++) yacc[ni] = zero;
  const int srow = tid >> 3;
  const int schunk = tid & 7;

  for (int kt = 0; kt < LK_; kt += 64) {
    __syncthreads();
#pragma unroll
    for (int ps = 0; ps < 2; ps++) {
      int row = srow + ps * 32;
      *(u16x8*)&Ks[row][schunk * 8] =
          *(const u16x8*)(kbase + (size_t)(kt + row) * 64 + schunk * 8);
      *(u16x8*)&Vs[row][schunk * 8] =
          *(const u16x8*)(vbase + (size_t)row * LK_ + kt + schunk * 8);
    }
    __syncthreads();
    f32x4 sacc[4];
#pragma unroll
    for (int ni = 0; ni < 4; ni++) sacc[ni] = zero;
#pragma unroll
    for (int ni = 0; ni < 4; ni++) {
      s16x8 kf0 = *(const s16x8*)&Ks[ni * 16 + fr][fq * 8];
      s16x8 kf1 = *(const s16x8*)&Ks[ni * 16 + fr][32 + fq * 8];
      sacc[ni] = __builtin_amdgcn_mfma_f32_16x16x32_bf16(kf0, qf0, sacc[ni], 0, 0, 0);
      sacc[ni] = __builtin_amdgcn_mfma_f32_16x16x32_bf16(kf1, qf1, sacc[ni], 0, 0, 0);
    }
    float mx = -1e30f;
#pragma unroll
    for (int ni = 0; ni < 4; ni++)
#pragma unroll
      for (int r = 0; r < 4; r++) {
        float sv = sacc[ni][r] * 0.125f;
        sacc[ni][r] = sv;
        mx = fmaxf(mx, sv);
      }
    mx = fmaxf(mx, __shfl_xor(mx, 16, 64));
    mx = fmaxf(mx, __shfl_xor(mx, 32, 64));
    float mn = fmaxf(mrun, mx);
    float alpha = __expf(mrun - mn);
    mrun = mn;
    float ts = 0.f;
#pragma unroll
    for (int ni = 0; ni < 4; ni++)
#pragma unroll
      for (int r = 0; r < 4; r++) {
        float pv = __expf(sacc[ni][r] - mn);
        sacc[ni][r] = pv;
        ts += pv;
      }
    ts += __shfl_xor(ts, 16, 64);
    ts += __shfl_xor(ts, 32, 64);
    lrun = lrun * alpha + ts;
    float va[4];
#pragma unroll
    for (int r = 0; r < 4; r++) va[r] = __shfl(alpha, fq * 4 + r, 64);
#pragma unroll
    for (int ni = 0; ni < 4; ni++)
#pragma unroll
      for (int r = 0; r < 4; r++) yacc[ni][r] *= va[r];
#pragma unroll
    for (int ni = 0; ni < 4; ni++) {
      uint2 wv;
      wv.x = (uint32_t)f2bf(sacc[ni][0]) | ((uint32_t)f2bf(sacc[ni][1]) << 16);
      wv.y = (uint32_t)f2bf(sacc[ni][2]) | ((uint32_t)f2bf(sacc[ni][3]) << 16);
      *(uint2*)&Ps[wid][fr][ni * 16 + fq * 4] = wv;
    }
#pragma unroll
    for (int s2 = 0; s2 < 2; s2++) {
      s16x8 pa = *(const s16x8*)&Ps[wid][fr][s2 * 32 + fq * 8];
#pragma unroll
      for (int ni = 0; ni < 4; ni++) {
        s16x8 vf = *(const s16x8*)&Vs[ni * 16 + fr][s2 * 32 + fq * 8];
        yacc[ni] = __builtin_amdgcn_mfma_f32_16x16x32_bf16(pa, vf, yacc[ni], 0, 0, 0);
      }
    }
  }
  int b = bh >> 4, h = bh & 15;
  float lr[4];
#pragma unroll
  for (int r = 0; r < 4; r++) lr[r] = __shfl(lrun, fq * 4 + r, 64);
  float* yo = y + ((size_t)(b * LQ_ + qt * 64 + wid * 16 + fq * 4)) * D_ + h * 64;
#pragma unroll
  for (int ni = 0; ni < 4; ni++) {
#pragma unroll
    for (int r = 0; r < 4; r++)
      yo[(size_t)r * D_ + ni * 16 + fr] = yacc[ni][r] / lr[r];
  }
}

extern "C" void kernel_launch(void* const* d_in, const int* in_sizes, int n_in,
                              void* d_out, int out_size, void* d_ws, size_t ws_size,
                              hipStream_t stream) {
  (void)in_sizes; (void)n_in; (void)out_size;
  const float* queries = (const float*)d_in[0];
  const float* kv = (const float*)d_in[1];
  const float* wq = (const float*)d_in[2];
  const float* wkv = (const float*)d_in[3];
  const float* wo = (const float*)d_in[4];
  const float* qnw = (const float*)d_in[5];
  const float* knw = (const float*)d_in[6];
  const int* pos_q = (const int*)d_in[7];
  const int* pos_k = (const int*)d_in[8];
  float* out = (float*)d_out;

  char* ws = (char*)d_ws;
  size_t off = 0;
  auto alloc = [&](size_t sz) { void* p = ws + off; off += sz; return p; };
  u16* Aq3 = (u16*)alloc((size_t)4096 * 3072 * 2);   // reused as Y3 later
  u16* Wq3 = (u16*)alloc((size_t)1024 * 3072 * 2);
  u16* Akv3 = (u16*)alloc((size_t)8192 * 3072 * 2);
  u16* Wkv3 = (u16*)alloc((size_t)2048 * 3072 * 2);
  u16* Wo3 = (u16*)alloc((size_t)1024 * 3072 * 2);
  float* Qp = (float*)alloc((size_t)4096 * 1024 * 4);  // reused as Y later
  float* KVp = (float*)alloc((size_t)8192 * 2048 * 4);
  u16* Qb = (u16*)alloc((size_t)64 * 1024 * 64 * 2);
  u16* Kb = (u16*)alloc((size_t)64 * 2048 * 64 * 2);
  u16* Vt = (u16*)alloc((size_t)64 * 2048 * 64 * 2);
  if (off > ws_size) return;  // insufficient workspace — bail loudly (validation fails)

  u16* Y3 = Aq3;
  float* Y = Qp;

  // 1) Dekker splits: activations [hi|lo|hi], weights [hi|hi|lo]
  split3a_k<<<4096 * 1024 / 256, 256, 0, stream>>>(queries, Aq3, 4096 * 1024);
  split3w_k<<<1024 * 1024 / 256, 256, 0, stream>>>(wq, Wq3, 1024 * 1024);
  split3a_k<<<8192 * 1024 / 256, 256, 0, stream>>>(kv, Akv3, 8192 * 1024);
  split3w_k<<<2048 * 1024 / 256, 256, 0, stream>>>(wkv, Wkv3, 2048 * 1024);
  split3w_k<<<1024 * 1024 / 256, 256, 0, stream>>>(wo, Wo3, 1024 * 1024);
  // 2) projections: KV via 256x256 4-phase kernel (256 blocks = 1/CU), Q via 128^2
  gemm_bt<<<dim3(4096 / 128, 1024 / 128), 256, 0, stream>>>(Aq3, Wq3, Qp, 1024, 3072);
  gemm_bt256<<<(8192 / 256) * (2048 / 256), 512, 0, stream>>>(Akv3, Wkv3, KVp, 2048, 3072);
  // 3) RMSNorm + RoPE -> bf16 head-major
  norm_rope_k<<<4096 * 16 / 4, 256, 0, stream>>>(Qp, 1024, 64, qnw, pos_q, Qb, 1024);
  norm_rope_k<<<8192 * 16 / 4, 256, 0, stream>>>(KVp, 2048, 128, knw, pos_k, Kb, 2048);
  vtrans_k<<<64 * 32, 256, 0, stream>>>(KVp, Vt);
  // 4) flash attention -> Y fp32 [b][lq][h*64+dh]
  flash_k<<<64 * 16, 256, 0, stream>>>(Qb, Kb, Vt, Y);
  // 5) output projection (split + GEMM) -> d_out
  split3a_k<<<4096 * 1024 / 256, 256, 0, stream>>>(Y, Y3, 4096 * 1024);
  gemm_bt<<<dim3(4096 / 128, 1024 / 128), 256, 0, stream>>>(Y3, Wo3, out, 1024, 3072);
}

// Round 6
// 407.024 us; speedup vs baseline: 1.3026x; 1.1058x over previous
//
#include <hip/hip_runtime.h>
#include <stdint.h>

typedef unsigned short u16;
typedef u16 u16x8 __attribute__((ext_vector_type(8)));
typedef short s16x8 __attribute__((ext_vector_type(8)));
typedef float f32x4 __attribute__((ext_vector_type(4)));

#define B_ 4
#define LQ_ 1024
#define LK_ 2048
#define D_ 1024
#define H_ 16
#define DH_ 64
#define K3_ 3072

__device__ __forceinline__ u16 f2bf(float x) {
  uint32_t u = __float_as_uint(x);
  u += 0x7FFFu + ((u >> 16) & 1u);   // round-to-nearest-even
  return (u16)(u >> 16);
}
__device__ __forceinline__ float bf2f(u16 h) {
  return __uint_as_float(((uint32_t)h) << 16);
}

// ---------- split (activation side): rows x 1024 fp32 -> rows x 3072 bf16 [hi | lo | hi]
__global__ __launch_bounds__(256) void split3a_k(const float* __restrict__ src,
                                                 u16* __restrict__ dst, int n) {
  int i = blockIdx.x * 256 + threadIdx.x;
  if (i >= n) return;
  int k = i & 1023;
  int r = i >> 10;
  float x = src[i];
  u16 hi = f2bf(x);
  u16 lo = f2bf(x - bf2f(hi));
  u16* d = dst + (size_t)r * 3072;
  d[k] = hi;
  d[1024 + k] = lo;
  d[2048 + k] = hi;
}

// ---------- split (weight side): rows x 1024 fp32 -> rows x 3072 bf16 [hi | hi | lo]
// Paired with the activation layout: hi*hi + lo*hi + hi*lo (Dekker 3-term).
__global__ __launch_bounds__(256) void split3w_k(const float* __restrict__ src,
                                                 u16* __restrict__ dst, int n) {
  int i = blockIdx.x * 256 + threadIdx.x;
  if (i >= n) return;
  int k = i & 1023;
  int r = i >> 10;
  float x = src[i];
  u16 hi = f2bf(x);
  u16 lo = f2bf(x - bf2f(hi));
  u16* d = dst + (size_t)r * 3072;
  d[k] = hi;
  d[1024 + k] = hi;
  d[2048 + k] = lo;
}

// ---------- 128x128 GEMM with split-K (Q/O projections): C_z = A * B^T over K-slice z ----
// grid (M/128, N/128, KS); each z writes its own partial C of size M*N.
__global__ __launch_bounds__(256) void gemm_bt(const u16* __restrict__ A,
                                               const u16* __restrict__ Bm,
                                               float* __restrict__ C,
                                               int N, int ldK) {
  __shared__ __align__(16) u16 As[128 * 32];
  __shared__ __align__(16) u16 Bs[128 * 32];
  const int tid = threadIdx.x;
  const int lane = tid & 63;
  const int wid = tid >> 6;
  const int m0 = blockIdx.x * 128;
  const int n0 = blockIdx.y * 128;
  const int slice = ldK / gridDim.z;
  const int kStart = blockIdx.z * slice;
  const int kEnd = kStart + slice;
  C += (size_t)blockIdx.z * (size_t)gridDim.x * 128 * N;
  const int wr = (wid >> 1) * 64;
  const int wc = (wid & 1) * 64;
  const int fr = lane & 15;
  const int fq = lane >> 4;
  const int srow = lane >> 2;
  const int schunk = lane & 3;

  f32x4 zero = {0.f, 0.f, 0.f, 0.f};
  f32x4 acc[4][4];
  for (int i = 0; i < 4; i++)
    for (int j = 0; j < 4; j++) acc[i][j] = zero;

  const int r0 = wid * 32;
  const u16* gA = A + (size_t)(m0 + r0 + srow) * ldK + schunk * 8;
  const u16* gB = Bm + (size_t)(n0 + r0 + srow) * ldK + schunk * 8;
  u16* lA = &As[r0 * 32];
  u16* lB = &Bs[r0 * 32];

  for (int k0 = kStart; k0 < kEnd; k0 += 32) {
    __syncthreads();
    __builtin_amdgcn_global_load_lds(
        (const __attribute__((address_space(1))) void*)(gA + k0),
        (__attribute__((address_space(3))) void*)(lA), 16, 0, 0);
    __builtin_amdgcn_global_load_lds(
        (const __attribute__((address_space(1))) void*)(gA + k0 + (size_t)16 * ldK),
        (__attribute__((address_space(3))) void*)(lA + 16 * 32), 16, 0, 0);
    __builtin_amdgcn_global_load_lds(
        (const __attribute__((address_space(1))) void*)(gB + k0),
        (__attribute__((address_space(3))) void*)(lB), 16, 0, 0);
    __builtin_amdgcn_global_load_lds(
        (const __attribute__((address_space(1))) void*)(gB + k0 + (size_t)16 * ldK),
        (__attribute__((address_space(3))) void*)(lB + 16 * 32), 16, 0, 0);
    asm volatile("s_waitcnt vmcnt(0)" ::: "memory");
    __syncthreads();

    s16x8 af[4], bf[4];
#pragma unroll
    for (int mi = 0; mi < 4; mi++)
      af[mi] = *(const s16x8*)&As[(wr + mi * 16 + fr) * 32 + fq * 8];
#pragma unroll
    for (int ni = 0; ni < 4; ni++)
      bf[ni] = *(const s16x8*)&Bs[(wc + ni * 16 + fr) * 32 + fq * 8];
#pragma unroll
    for (int mi = 0; mi < 4; mi++)
#pragma unroll
      for (int ni = 0; ni < 4; ni++)
        acc[mi][ni] = __builtin_amdgcn_mfma_f32_16x16x32_bf16(af[mi], bf[ni],
                                                              acc[mi][ni], 0, 0, 0);
  }
#pragma unroll
  for (int mi = 0; mi < 4; mi++) {
#pragma unroll
    for (int ni = 0; ni < 4; ni++) {
      int row = m0 + wr + mi * 16 + fq * 4;
      int col = n0 + wc + ni * 16 + fr;
#pragma unroll
      for (int r = 0; r < 4; r++) C[(size_t)(row + r) * N + col] = acc[mi][ni][r];
    }
  }
}

// ---------- 256x256 GEMM, 6-barrier pipeline (T1+T2+T4+T5), for KV projection ----------
#define BAR8 asm volatile("s_barrier" ::: "memory")
__global__ __launch_bounds__(512, 2) void gemm_bt256(const u16* __restrict__ A,
                                                     const u16* __restrict__ Bm,
                                                     float* __restrict__ C,
                                                     int N, int K) {
  __shared__ __align__(16) u16 lds[65536];  // 2 x (A 256x64 + B 256x64) u16 = 128 KiB
  const int tid = threadIdx.x;
  const int lane = tid & 63;
  const int w = tid >> 6;
  const int wr = w >> 2;   // 0..1 (M)
  const int wc = w & 3;    // 0..3 (N)
  const int fr = lane & 15;
  const int fq = lane >> 4;
  const int nwg = gridDim.x;
  const int cpx = nwg >> 3;
  const int bid = blockIdx.x;
  const int swz = (bid & 7) * cpx + (bid >> 3);
  const int nbn = N >> 8;
  const int bm = swz / nbn, bn = swz % nbn;
  const int gm0 = bm * 256, gn0 = bn * 256;
  const int NT = K >> 6;

  f32x4 zero = {0.f, 0.f, 0.f, 0.f};
  f32x4 acc[8][4];
#pragma unroll
  for (int i = 0; i < 8; i++)
#pragma unroll
    for (int j = 0; j < 4; j++) acc[i][j] = zero;

  auto stage = [&](int buf, int t, int s) {
    int q = (s & 3) * 512 + tid;
    int row = q >> 3, p = q & 7;
    int l = p ^ (row & 7);
    const u16* src = ((s < 4) ? A + (size_t)(gm0 + row) * K
                              : Bm + (size_t)(gn0 + row) * K) + (t << 6) + l * 8;
    u16* dst = &lds[buf * 32768 + ((s < 4) ? 0 : 16384) + ((s & 3) * 512 + w * 64) * 8];
    __builtin_amdgcn_global_load_lds(
        (const __attribute__((address_space(1))) void*)src,
        (__attribute__((address_space(3))) void*)dst, 16, 0, 0);
  };
  auto rdA = [&](int buf, int mi, int kk) -> s16x8 {
    int row = wr * 128 + mi * 16 + fr;
    int l = (kk * 4 + fq) ^ (fr & 7);
    return *(const s16x8*)&lds[buf * 32768 + row * 64 + l * 8];
  };
  auto rdB = [&](int buf, int ni, int kk) -> s16x8 {
    int row = wc * 64 + ni * 16 + fr;
    int l = (kk * 4 + fq) ^ (fr & 7);
    return *(const s16x8*)&lds[buf * 32768 + 16384 + row * 64 + l * 8];
  };

  s16x8 af[4][2], bf[4][2];

#pragma unroll
  for (int s = 0; s < 8; s++) stage(0, 0, s);
  asm volatile("s_waitcnt vmcnt(0)" ::: "memory");
  BAR8;

  for (int t = 0; t < NT; t++) {
    const int cur = t & 1;
    const bool st = (t + 1 < NT);
    // ---- P1: read A-lo + B-lo; stage A of t+1; MFMA (mi0-3 x ni0-1)
#pragma unroll
    for (int mi = 0; mi < 4; mi++)
#pragma unroll
      for (int kk = 0; kk < 2; kk++) af[mi][kk] = rdA(cur, mi, kk);
#pragma unroll
    for (int ni = 0; ni < 2; ni++)
#pragma unroll
      for (int kk = 0; kk < 2; kk++) bf[ni][kk] = rdB(cur, ni, kk);
    if (st) {
#pragma unroll
      for (int s = 0; s < 4; s++) stage(cur ^ 1, t + 1, s);
    }
    BAR8;
    __builtin_amdgcn_s_setprio(1);
#pragma unroll
    for (int mi = 0; mi < 4; mi++)
#pragma unroll
      for (int ni = 0; ni < 2; ni++)
#pragma unroll
        for (int kk = 0; kk < 2; kk++)
          acc[mi][ni] = __builtin_amdgcn_mfma_f32_16x16x32_bf16(af[mi][kk], bf[ni][kk],
                                                                acc[mi][ni], 0, 0, 0);
    __builtin_amdgcn_s_setprio(0);
    BAR8;
    // ---- P2: read B-hi; stage B of t+1; MFMA (mi0-3 x ni2-3)
#pragma unroll
    for (int ni = 2; ni < 4; ni++)
#pragma unroll
      for (int kk = 0; kk < 2; kk++) bf[ni][kk] = rdB(cur, ni, kk);
    if (st) {
#pragma unroll
      for (int s = 4; s < 8; s++) stage(cur ^ 1, t + 1, s);
    }
    BAR8;
    __builtin_amdgcn_s_setprio(1);
#pragma unroll
    for (int mi = 0; mi < 4; mi++)
#pragma unroll
      for (int ni = 2; ni < 4; ni++)
#pragma unroll
        for (int kk = 0; kk < 2; kk++)
          acc[mi][ni] = __builtin_amdgcn_mfma_f32_16x16x32_bf16(af[mi][kk], bf[ni][kk],
                                                                acc[mi][ni], 0, 0, 0);
    __builtin_amdgcn_s_setprio(0);
    BAR8;
    // ---- P3: read A-hi (reuse af); MFMA (mi4-7 x ni2-3); vmcnt; BAR
    // (A-hi ds_reads are consumed by THIS cluster's lgkmcnt before the BAR,
    //  so next-tile stage writes into this buffer cannot WAR an in-flight read.)
#pragma unroll
    for (int mi = 0; mi < 4; mi++)
#pragma unroll
      for (int kk = 0; kk < 2; kk++) af[mi][kk] = rdA(cur, mi + 4, kk);
    BAR8;
    __builtin_amdgcn_s_setprio(1);
#pragma unroll
    for (int mi = 0; mi < 4; mi++)
#pragma unroll
      for (int ni = 2; ni < 4; ni++)
#pragma unroll
        for (int kk = 0; kk < 2; kk++)
          acc[mi + 4][ni] = __builtin_amdgcn_mfma_f32_16x16x32_bf16(
              af[mi][kk], bf[ni][kk], acc[mi + 4][ni], 0, 0, 0);
    __builtin_amdgcn_s_setprio(0);
    asm volatile("s_waitcnt vmcnt(0)" ::: "memory");
    BAR8;
    // ---- P4: register-only MFMA (mi4-7 x ni0-1); no barriers, flows into next P1
    __builtin_amdgcn_s_setprio(1);
#pragma unroll
    for (int mi = 0; mi < 4; mi++)
#pragma unroll
      for (int ni = 0; ni < 2; ni++)
#pragma unroll
        for (int kk = 0; kk < 2; kk++)
          acc[mi + 4][ni] = __builtin_amdgcn_mfma_f32_16x16x32_bf16(
              af[mi][kk], bf[ni][kk], acc[mi + 4][ni], 0, 0, 0);
    __builtin_amdgcn_s_setprio(0);
  }
#pragma unroll
  for (int mi = 0; mi < 8; mi++) {
#pragma unroll
    for (int ni = 0; ni < 4; ni++) {
      int row = gm0 + wr * 128 + mi * 16 + fq * 4;
      int col = gn0 + wc * 64 + ni * 16 + fr;
#pragma unroll
      for (int r = 0; r < 4; r++) C[(size_t)(row + r) * N + col] = acc[mi][ni][r];
    }
  }
}

// ---------- per-head RMSNorm + RoPE (sums nparts split-K partials), fp32 -> bf16 ----------
__global__ __launch_bounds__(256) void norm_rope_k(const float* __restrict__ src,
                                                   int srcStride, int hs,
                                                   int nparts, size_t partStride,
                                                   const float* __restrict__ w,
                                                   const int* __restrict__ pos,
                                                   u16* __restrict__ dst, int L) {
  int wid = threadIdx.x >> 6;
  int lane = threadIdx.x & 63;
  int g = blockIdx.x * 4 + wid;  // (b*L + l)*H + h
  int h = g & 15;
  int bl = g >> 4;
  int b = bl / L;
  int l = bl - b * L;
  size_t idx = (size_t)bl * srcStride + h * hs + lane;
  float x = src[idx];
  for (int pp = 1; pp < nparts; pp++) x += src[pp * partStride + idx];
  float ss = x * x;
#pragma unroll
  for (int m = 1; m < 64; m <<= 1) ss += __shfl_xor(ss, m, 64);
  float xn = x * rsqrtf(ss * (1.0f / 64.0f) + 1e-6f) * w[lane];
  float p = __shfl_xor(xn, 32, 64);
  int j = lane & 31;
  float freq = powf(10000.0f, -(float)j * (1.0f / 32.0f));
  float ang = (float)pos[l] * freq;
  float c = cosf(ang), s = sinf(ang);
  float o = (lane < 32) ? (xn * c - p * s) : (p * s + xn * c);
  dst[((size_t)(b * 16 + h) * L + l) * 64 + lane] = f2bf(o);
}

// ---------- sum of 3 split-K partials -> out ----------
__global__ __launch_bounds__(256) void reduce3_k(const float* __restrict__ p,
                                                 float* __restrict__ out, int n) {
  int i = (blockIdx.x * 256 + threadIdx.x) * 4;
  if (i >= n) return;
  float4 a = *(const float4*)(p + i);
  float4 b = *(const float4*)(p + (size_t)n + i);
  float4 c = *(const float4*)(p + (size_t)2 * n + i);
  float4 r = make_float4(a.x + b.x + c.x, a.y + b.y + c.y,
                         a.z + b.z + c.z, a.w + b.w + c.w);
  *(float4*)(out + i) = r;
}

// ---------- V transpose: kvp v-part -> vt[b][h][dh][lk] bf16 ----------
__global__ __launch_bounds__(256) void vtrans_k(const float* __restrict__ kvp,
                                                u16* __restrict__ vt) {
  __shared__ float tile[64][65];
  int kt = blockIdx.x & 31;  // LK/64
  int bh = blockIdx.x >> 5;
  int h = bh & 15;
  int b = bh >> 4;
  int c = threadIdx.x & 63;
  int r4 = threadIdx.x >> 6;
  const float* src = kvp + ((size_t)(b * LK_ + kt * 64)) * 2048 + h * 128 + 64;
#pragma unroll
  for (int p = 0; p < 16; p++) {
    int lk = p * 4 + r4;
    tile[lk][c] = src[(size_t)lk * 2048 + c];
  }
  __syncthreads();
  u16* dst = vt + (size_t)bh * 64 * LK_ + kt * 64;
#pragma unroll
  for (int p = 0; p < 16; p++) {
    int dh = p * 4 + r4;
    dst[(size_t)dh * LK_ + c] = f2bf(tile[c][dh]);
  }
}

// ---------- flash attention (swapped QK^T: lane-local softmax) ----------
__global__ __launch_bounds__(256) void flash_k(const u16* __restrict__ qb,
                                               const u16* __restrict__ kb,
                                               const u16* __restrict__ vb,
                                               float* __restrict__ y) {
  __shared__ __align__(16) u16 Ks[64][72];
  __shared__ __align__(16) u16 Vs[64][72];       // Vs[dh][kv]
  __shared__ __align__(16) u16 Ps[4][16][72];    // per-wave P[q][j]
  const int tid = threadIdx.x;
  const int lane = tid & 63;
  const int wid = tid >> 6;
  const int fr = lane & 15;
  const int fq = lane >> 4;
  int qt = blockIdx.x & 15;  // LQ/64
  int bh = blockIdx.x >> 4;  // b*16+h
  const u16* qbase = qb + ((size_t)bh * LQ_ + qt * 64 + wid * 16) * 64;
  const u16* kbase = kb + (size_t)bh * LK_ * 64;
  const u16* vbase = vb + (size_t)bh * 64 * LK_;
  s16x8 qf0 = *(const s16x8*)(qbase + (size_t)fr * 64 + fq * 8);
  s16x8 qf1 = *(const s16x8*)(qbase + (size_t)fr * 64 + 32 + fq * 8);
  float mrun = -1e30f, lrun = 0.f;  // lane owns q-row fr
  f32x4 zero = {0.f, 0.f, 0.f, 0.f};
  f32x4 yacc[4];
#pragma unroll
  for (int ni = 0; ni < 4; ni++) yacc[ni] = zero;
  const int srow = tid >> 3;
  const int schunk = tid & 7;

  for (int kt = 0; kt < LK_; kt += 64) {
    __syncthreads();
#pragma unroll
    for (int ps = 0; ps < 2; ps++) {
      int row = srow + ps * 32;
      *(u16x8*)&Ks[row][schunk * 8] =
          *(const u16x8*)(kbase + (size_t)(kt + row) * 64 + schunk * 8);
      *(u16x8*)&Vs[row][schunk * 8] =
          *(const u16x8*)(vbase + (size_t)row * LK_ + kt + schunk * 8);
    }
    __syncthreads();
    f32x4 sacc[4];
#pragma unroll
    for (int ni = 0; ni < 4; ni++) sacc[ni] = zero;
#pragma unroll
    for (int ni = 0; ni < 4; ni++) {
      s16x8 kf0 = *(const s16x8*)&Ks[ni * 16 + fr][fq * 8];
      s16x8 kf1 = *(const s16x8*)&Ks[ni * 16 + fr][32 + fq * 8];
      sacc[ni] = __builtin_amdgcn_mfma_f32_16x16x32_bf16(kf0, qf0, sacc[ni], 0, 0, 0);
      sacc[ni] = __builtin_amdgcn_mfma_f32_16x16x32_bf16(kf1, qf1, sacc[ni], 0, 0, 0);
    }
    float mx = -1e30f;
#pragma unroll
    for (int ni = 0; ni < 4; ni++)
#pragma unroll
      for (int r = 0; r < 4; r++) {
        float sv = sacc[ni][r] * 0.125f;
        sacc[ni][r] = sv;
        mx = fmaxf(mx, sv);
      }
    mx = fmaxf(mx, __shfl_xor(mx, 16, 64));
    mx = fmaxf(mx, __shfl_xor(mx, 32, 64));
    float mn = fmaxf(mrun, mx);
    float alpha = __expf(mrun - mn);
    mrun = mn;
    float ts = 0.f;
#pragma unroll
    for (int ni = 0; ni < 4; ni++)
#pragma unroll
      for (int r = 0; r < 4; r++) {
        float pv = __expf(sacc[ni][r] - mn);
        sacc[ni][r] = pv;
        ts += pv;
      }
    ts += __shfl_xor(ts, 16, 64);
    ts += __shfl_xor(ts, 32, 64);
    lrun = lrun * alpha + ts;
    float va[4];
#pragma unroll
    for (int r = 0; r < 4; r++) va[r] = __shfl(alpha, fq * 4 + r, 64);
#pragma unroll
    for (int ni = 0; ni < 4; ni++)
#pragma unroll
      for (int r = 0; r < 4; r++) yacc[ni][r] *= va[r];
#pragma unroll
    for (int ni = 0; ni < 4; ni++) {
      uint2 wv;
      wv.x = (uint32_t)f2bf(sacc[ni][0]) | ((uint32_t)f2bf(sacc[ni][1]) << 16);
      wv.y = (uint32_t)f2bf(sacc[ni][2]) | ((uint32_t)f2bf(sacc[ni][3]) << 16);
      *(uint2*)&Ps[wid][fr][ni * 16 + fq * 4] = wv;
    }
#pragma unroll
    for (int s2 = 0; s2 < 2; s2++) {
      s16x8 pa = *(const s16x8*)&Ps[wid][fr][s2 * 32 + fq * 8];
#pragma unroll
      for (int ni = 0; ni < 4; ni++) {
        s16x8 vf = *(const s16x8*)&Vs[ni * 16 + fr][s2 * 32 + fq * 8];
        yacc[ni] = __builtin_amdgcn_mfma_f32_16x16x32_bf16(pa, vf, yacc[ni], 0, 0, 0);
      }
    }
  }
  int b = bh >> 4, h = bh & 15;
  float lr[4];
#pragma unroll
  for (int r = 0; r < 4; r++) lr[r] = __shfl(lrun, fq * 4 + r, 64);
  float* yo = y + ((size_t)(b * LQ_ + qt * 64 + wid * 16 + fq * 4)) * D_ + h * 64;
#pragma unroll
  for (int ni = 0; ni < 4; ni++) {
#pragma unroll
    for (int r = 0; r < 4; r++)
      yo[(size_t)r * D_ + ni * 16 + fr] = yacc[ni][r] / lr[r];
  }
}

extern "C" void kernel_launch(void* const* d_in, const int* in_sizes, int n_in,
                              void* d_out, int out_size, void* d_ws, size_t ws_size,
                              hipStream_t stream) {
  (void)in_sizes; (void)n_in; (void)out_size;
  const float* queries = (const float*)d_in[0];
  const float* kv = (const float*)d_in[1];
  const float* wq = (const float*)d_in[2];
  const float* wkv = (const float*)d_in[3];
  const float* wo = (const float*)d_in[4];
  const float* qnw = (const float*)d_in[5];
  const float* knw = (const float*)d_in[6];
  const int* pos_q = (const int*)d_in[7];
  const int* pos_k = (const int*)d_in[8];
  float* out = (float*)d_out;

  char* ws = (char*)d_ws;
  size_t off = 0;
  auto alloc = [&](size_t sz) { void* p = ws + off; off += sz; return p; };
  u16* Aq3 = (u16*)alloc((size_t)4096 * 3072 * 2);   // reused as Y3 later
  u16* Wq3 = (u16*)alloc((size_t)1024 * 3072 * 2);
  u16* Akv3 = (u16*)alloc((size_t)8192 * 3072 * 2);  // reused as Qpart/Opart (50.33 MB)
  u16* Wkv3 = (u16*)alloc((size_t)2048 * 3072 * 2);
  u16* Wo3 = (u16*)alloc((size_t)1024 * 3072 * 2);
  float* Qp = (float*)alloc((size_t)4096 * 1024 * 4);  // reused as Y later
  float* KVp = (float*)alloc((size_t)8192 * 2048 * 4);
  u16* Qb = (u16*)alloc((size_t)64 * 1024 * 64 * 2);
  u16* Kb = (u16*)alloc((size_t)64 * 2048 * 64 * 2);
  u16* Vt = (u16*)alloc((size_t)64 * 2048 * 64 * 2);
  if (off > ws_size) return;  // insufficient workspace — bail loudly (validation fails)

  u16* Y3 = Aq3;
  float* Y = Qp;
  float* Part = (float*)Akv3;  // 3 x 4096 x 1024 fp32 = exactly sizeof(Akv3)
  const size_t PSTRIDE = (size_t)4096 * 1024;

  // 1) Dekker splits: activations [hi|lo|hi], weights [hi|hi|lo]
  split3a_k<<<4096 * 1024 / 256, 256, 0, stream>>>(queries, Aq3, 4096 * 1024);
  split3w_k<<<1024 * 1024 / 256, 256, 0, stream>>>(wq, Wq3, 1024 * 1024);
  split3a_k<<<8192 * 1024 / 256, 256, 0, stream>>>(kv, Akv3, 8192 * 1024);
  split3w_k<<<2048 * 1024 / 256, 256, 0, stream>>>(wkv, Wkv3, 2048 * 1024);
  split3w_k<<<1024 * 1024 / 256, 256, 0, stream>>>(wo, Wo3, 1024 * 1024);
  // 2) KV projection first (so Akv3 is dead before Part overlays it)
  gemm_bt256<<<(8192 / 256) * (2048 / 256), 512, 0, stream>>>(Akv3, Wkv3, KVp, 2048, 3072);
  // 3) Q projection, split-K=3 (768 blocks = 3/CU) -> Part
  gemm_bt<<<dim3(4096 / 128, 1024 / 128, 3), 256, 0, stream>>>(Aq3, Wq3, Part, 1024, 3072);
  // 4) RMSNorm + RoPE -> bf16 head-major (Q sums the 3 partials)
  norm_rope_k<<<4096 * 16 / 4, 256, 0, stream>>>(Part, 1024, 64, 3, PSTRIDE, qnw, pos_q, Qb, 1024);
  norm_rope_k<<<8192 * 16 / 4, 256, 0, stream>>>(KVp, 2048, 128, 1, 0, knw, pos_k, Kb, 2048);
  vtrans_k<<<64 * 32, 256, 0, stream>>>(KVp, Vt);
  // 5) flash attention -> Y fp32 [b][lq][h*64+dh]
  flash_k<<<64 * 16, 256, 0, stream>>>(Qb, Kb, Vt, Y);
  // 6) output projection: split + split-K=3 GEMM + reduce -> d_out
  split3a_k<<<4096 * 1024 / 256, 256, 0, stream>>>(Y, Y3, 4096 * 1024);
  gemm_bt<<<dim3(4096 / 128, 1024 / 128, 3), 256, 0, stream>>>(Y3, Wo3, Part, 1024, 3072);
  reduce3_k<<<4096, 256, 0, stream>>>(Part, out, 4096 * 1024);
}

// Round 7
// 326.876 us; speedup vs baseline: 1.6220x; 1.2452x over previous
//
#include <hip/hip_runtime.h>
#include <stdint.h>

typedef unsigned short u16;
typedef u16 u16x8 __attribute__((ext_vector_type(8)));
typedef short s16x8 __attribute__((ext_vector_type(8)));
typedef float f32x4 __attribute__((ext_vector_type(4)));

#define B_ 4
#define LQ_ 1024
#define LK_ 2048
#define D_ 1024
#define H_ 16
#define DH_ 64

__device__ __forceinline__ u16 f2bf(float x) {
  uint32_t u = __float_as_uint(x);
  u += 0x7FFFu + ((u >> 16) & 1u);   // round-to-nearest-even
  return (u16)(u >> 16);
}
__device__ __forceinline__ float bf2f(u16 h) {
  return __uint_as_float(((uint32_t)h) << 16);
}

// ---------- activation split: rows x 1024 fp32 -> rows x 2048 bf16 [hi | lo] ----------
// 2-term Dekker: GEMM over K'=2048 with W=[hi,hi] computes A*bf16(W) exactly (fp32 acc).
__global__ __launch_bounds__(256) void split2a_k(const float* __restrict__ src,
                                                 u16* __restrict__ dst, int n) {
  int i = blockIdx.x * 256 + threadIdx.x;
  if (i >= n) return;
  int k = i & 1023;
  int r = i >> 10;
  float x = src[i];
  u16 hi = f2bf(x);
  u16 lo = f2bf(x - bf2f(hi));
  u16* d = dst + (size_t)r * 2048;
  d[k] = hi;
  d[1024 + k] = lo;
}

// ---------- weight cast: fp32 -> bf16 (hi only), vectorized x4 ----------
__global__ __launch_bounds__(256) void castw_k(const float* __restrict__ src,
                                               u16* __restrict__ dst, int n) {
  int i = (blockIdx.x * 256 + threadIdx.x) * 4;
  if (i >= n) return;
  float4 v = *(const float4*)(src + i);
  ushort4 o;
  o.x = f2bf(v.x); o.y = f2bf(v.y); o.z = f2bf(v.z); o.w = f2bf(v.w);
  *(ushort4*)(dst + i) = o;
}

// ---------- 128x128 GEMM, split-K (Q/O): A[M,2048] ([hi|lo]) x W[N,1024]^T ----------
// grid (M/128, N/128, KS). B k-index = k & 1023 (lo-half pairs with W-hi again).
// Partial z sums A-segment z*slice.. -> sum over z = (Ahi+Alo)*Whi = A*bf16(W).
__global__ __launch_bounds__(256) void gemm_bt(const u16* __restrict__ A,
                                               const u16* __restrict__ Bm,
                                               float* __restrict__ C,
                                               int N) {
  __shared__ __align__(16) u16 As[128 * 32];
  __shared__ __align__(16) u16 Bs[128 * 32];
  const int tid = threadIdx.x;
  const int lane = tid & 63;
  const int wid = tid >> 6;
  const int m0 = blockIdx.x * 128;
  const int n0 = blockIdx.y * 128;
  const int slice = 2048 / gridDim.z;
  const int kStart = blockIdx.z * slice;
  const int kEnd = kStart + slice;
  C += (size_t)blockIdx.z * (size_t)gridDim.x * 128 * N;
  const int wr = (wid >> 1) * 64;
  const int wc = (wid & 1) * 64;
  const int fr = lane & 15;
  const int fq = lane >> 4;
  const int srow = lane >> 2;
  const int schunk = lane & 3;

  f32x4 zero = {0.f, 0.f, 0.f, 0.f};
  f32x4 acc[4][4];
  for (int i = 0; i < 4; i++)
    for (int j = 0; j < 4; j++) acc[i][j] = zero;

  const int r0 = wid * 32;
  const u16* gA = A + (size_t)(m0 + r0 + srow) * 2048 + schunk * 8;
  const u16* gB = Bm + (size_t)(n0 + r0 + srow) * 1024 + schunk * 8;
  u16* lA = &As[r0 * 32];
  u16* lB = &Bs[r0 * 32];

  for (int k0 = kStart; k0 < kEnd; k0 += 32) {
    int kw = k0 & 1023;
    __syncthreads();
    __builtin_amdgcn_global_load_lds(
        (const __attribute__((address_space(1))) void*)(gA + k0),
        (__attribute__((address_space(3))) void*)(lA), 16, 0, 0);
    __builtin_amdgcn_global_load_lds(
        (const __attribute__((address_space(1))) void*)(gA + k0 + (size_t)16 * 2048),
        (__attribute__((address_space(3))) void*)(lA + 16 * 32), 16, 0, 0);
    __builtin_amdgcn_global_load_lds(
        (const __attribute__((address_space(1))) void*)(gB + kw),
        (__attribute__((address_space(3))) void*)(lB), 16, 0, 0);
    __builtin_amdgcn_global_load_lds(
        (const __attribute__((address_space(1))) void*)(gB + kw + (size_t)16 * 1024),
        (__attribute__((address_space(3))) void*)(lB + 16 * 32), 16, 0, 0);
    asm volatile("s_waitcnt vmcnt(0)" ::: "memory");
    __syncthreads();

    s16x8 af[4], bf[4];
#pragma unroll
    for (int mi = 0; mi < 4; mi++)
      af[mi] = *(const s16x8*)&As[(wr + mi * 16 + fr) * 32 + fq * 8];
#pragma unroll
    for (int ni = 0; ni < 4; ni++)
      bf[ni] = *(const s16x8*)&Bs[(wc + ni * 16 + fr) * 32 + fq * 8];
#pragma unroll
    for (int mi = 0; mi < 4; mi++)
#pragma unroll
      for (int ni = 0; ni < 4; ni++)
        acc[mi][ni] = __builtin_amdgcn_mfma_f32_16x16x32_bf16(af[mi], bf[ni],
                                                              acc[mi][ni], 0, 0, 0);
  }
#pragma unroll
  for (int mi = 0; mi < 4; mi++) {
#pragma unroll
    for (int ni = 0; ni < 4; ni++) {
      int row = m0 + wr + mi * 16 + fq * 4;
      int col = n0 + wc + ni * 16 + fr;
#pragma unroll
      for (int r = 0; r < 4; r++) C[(size_t)(row + r) * N + col] = acc[mi][ni][r];
    }
  }
}

// ---------- 256x256 GEMM, 6-barrier pipeline (KV projection) ----------
// A[M,2048] ([hi|lo]) x W[N,1024]^T, K'=2048 (B wraps at 1024).
#define BAR8 asm volatile("s_barrier" ::: "memory")
__global__ __launch_bounds__(512, 2) void gemm_bt256(const u16* __restrict__ A,
                                                     const u16* __restrict__ Bm,
                                                     float* __restrict__ C,
                                                     int N) {
  __shared__ __align__(16) u16 lds[65536];  // 2 x (A 256x64 + B 256x64) u16 = 128 KiB
  const int tid = threadIdx.x;
  const int lane = tid & 63;
  const int w = tid >> 6;
  const int wr = w >> 2;
  const int wc = w & 3;
  const int fr = lane & 15;
  const int fq = lane >> 4;
  const int nwg = gridDim.x;
  const int cpx = nwg >> 3;
  const int bid = blockIdx.x;
  const int swz = (bid & 7) * cpx + (bid >> 3);
  const int nbn = N >> 8;
  const int bm = swz / nbn, bn = swz % nbn;
  const int gm0 = bm * 256, gn0 = bn * 256;
  const int NT = 32;  // 2048 / 64

  f32x4 zero = {0.f, 0.f, 0.f, 0.f};
  f32x4 acc[8][4];
#pragma unroll
  for (int i = 0; i < 8; i++)
#pragma unroll
    for (int j = 0; j < 4; j++) acc[i][j] = zero;

  auto stage = [&](int buf, int t, int s) {
    int q = (s & 3) * 512 + tid;
    int row = q >> 3, p = q & 7;
    int l = p ^ (row & 7);
    const u16* src = (s < 4)
        ? A + (size_t)(gm0 + row) * 2048 + (t << 6) + l * 8
        : Bm + (size_t)(gn0 + row) * 1024 + ((t << 6) & 1023) + l * 8;
    u16* dst = &lds[buf * 32768 + ((s < 4) ? 0 : 16384) + ((s & 3) * 512 + w * 64) * 8];
    __builtin_amdgcn_global_load_lds(
        (const __attribute__((address_space(1))) void*)src,
        (__attribute__((address_space(3))) void*)dst, 16, 0, 0);
  };
  auto rdA = [&](int buf, int mi, int kk) -> s16x8 {
    int row = wr * 128 + mi * 16 + fr;
    int l = (kk * 4 + fq) ^ (fr & 7);
    return *(const s16x8*)&lds[buf * 32768 + row * 64 + l * 8];
  };
  auto rdB = [&](int buf, int ni, int kk) -> s16x8 {
    int row = wc * 64 + ni * 16 + fr;
    int l = (kk * 4 + fq) ^ (fr & 7);
    return *(const s16x8*)&lds[buf * 32768 + 16384 + row * 64 + l * 8];
  };

  s16x8 af[4][2], bf[4][2];

#pragma unroll
  for (int s = 0; s < 8; s++) stage(0, 0, s);
  asm volatile("s_waitcnt vmcnt(0)" ::: "memory");
  BAR8;

  for (int t = 0; t < NT; t++) {
    const int cur = t & 1;
    const bool st = (t + 1 < NT);
    // ---- P1: read A-lo + B-lo; stage A of t+1; MFMA (mi0-3 x ni0-1)
#pragma unroll
    for (int mi = 0; mi < 4; mi++)
#pragma unroll
      for (int kk = 0; kk < 2; kk++) af[mi][kk] = rdA(cur, mi, kk);
#pragma unroll
    for (int ni = 0; ni < 2; ni++)
#pragma unroll
      for (int kk = 0; kk < 2; kk++) bf[ni][kk] = rdB(cur, ni, kk);
    if (st) {
#pragma unroll
      for (int s = 0; s < 4; s++) stage(cur ^ 1, t + 1, s);
    }
    BAR8;
    __builtin_amdgcn_s_setprio(1);
#pragma unroll
    for (int mi = 0; mi < 4; mi++)
#pragma unroll
      for (int ni = 0; ni < 2; ni++)
#pragma unroll
        for (int kk = 0; kk < 2; kk++)
          acc[mi][ni] = __builtin_amdgcn_mfma_f32_16x16x32_bf16(af[mi][kk], bf[ni][kk],
                                                                acc[mi][ni], 0, 0, 0);
    __builtin_amdgcn_s_setprio(0);
    BAR8;
    // ---- P2: read B-hi; stage B of t+1; MFMA (mi0-3 x ni2-3)
#pragma unroll
    for (int ni = 2; ni < 4; ni++)
#pragma unroll
      for (int kk = 0; kk < 2; kk++) bf[ni][kk] = rdB(cur, ni, kk);
    if (st) {
#pragma unroll
      for (int s = 4; s < 8; s++) stage(cur ^ 1, t + 1, s);
    }
    BAR8;
    __builtin_amdgcn_s_setprio(1);
#pragma unroll
    for (int mi = 0; mi < 4; mi++)
#pragma unroll
      for (int ni = 2; ni < 4; ni++)
#pragma unroll
        for (int kk = 0; kk < 2; kk++)
          acc[mi][ni] = __builtin_amdgcn_mfma_f32_16x16x32_bf16(af[mi][kk], bf[ni][kk],
                                                                acc[mi][ni], 0, 0, 0);
    __builtin_amdgcn_s_setprio(0);
    BAR8;
    // ---- P3: read A-hi (reuse af); MFMA (mi4-7 x ni2-3); vmcnt; BAR
#pragma unroll
    for (int mi = 0; mi < 4; mi++)
#pragma unroll
      for (int kk = 0; kk < 2; kk++) af[mi][kk] = rdA(cur, mi + 4, kk);
    BAR8;
    __builtin_amdgcn_s_setprio(1);
#pragma unroll
    for (int mi = 0; mi < 4; mi++)
#pragma unroll
      for (int ni = 2; ni < 4; ni++)
#pragma unroll
        for (int kk = 0; kk < 2; kk++)
          acc[mi + 4][ni] = __builtin_amdgcn_mfma_f32_16x16x32_bf16(
              af[mi][kk], bf[ni][kk], acc[mi + 4][ni], 0, 0, 0);
    __builtin_amdgcn_s_setprio(0);
    asm volatile("s_waitcnt vmcnt(0)" ::: "memory");
    BAR8;
    // ---- P4: register-only MFMA (mi4-7 x ni0-1); flows into next P1
    __builtin_amdgcn_s_setprio(1);
#pragma unroll
    for (int mi = 0; mi < 4; mi++)
#pragma unroll
      for (int ni = 0; ni < 2; ni++)
#pragma unroll
        for (int kk = 0; kk < 2; kk++)
          acc[mi + 4][ni] = __builtin_amdgcn_mfma_f32_16x16x32_bf16(
              af[mi][kk], bf[ni][kk], acc[mi + 4][ni], 0, 0, 0);
    __builtin_amdgcn_s_setprio(0);
  }
#pragma unroll
  for (int mi = 0; mi < 8; mi++) {
#pragma unroll
    for (int ni = 0; ni < 4; ni++) {
      int row = gm0 + wr * 128 + mi * 16 + fq * 4;
      int col = gn0 + wc * 64 + ni * 16 + fr;
#pragma unroll
      for (int r = 0; r < 4; r++) C[(size_t)(row + r) * N + col] = acc[mi][ni][r];
    }
  }
}

// ---------- per-head RMSNorm + RoPE (sums nparts split-K partials), fp32 -> bf16 ----------
__global__ __launch_bounds__(256) void norm_rope_k(const float* __restrict__ src,
                                                   int srcStride, int hs,
                                                   int nparts, size_t partStride,
                                                   const float* __restrict__ w,
                                                   const int* __restrict__ pos,
                                                   u16* __restrict__ dst, int L) {
  int wid = threadIdx.x >> 6;
  int lane = threadIdx.x & 63;
  int g = blockIdx.x * 4 + wid;  // (b*L + l)*H + h
  int h = g & 15;
  int bl = g >> 4;
  int b = bl / L;
  int l = bl - b * L;
  size_t idx = (size_t)bl * srcStride + h * hs + lane;
  float x = src[idx];
  for (int pp = 1; pp < nparts; pp++) x += src[pp * partStride + idx];
  float ss = x * x;
#pragma unroll
  for (int m = 1; m < 64; m <<= 1) ss += __shfl_xor(ss, m, 64);
  float xn = x * rsqrtf(ss * (1.0f / 64.0f) + 1e-6f) * w[lane];
  float p = __shfl_xor(xn, 32, 64);
  int j = lane & 31;
  float freq = powf(10000.0f, -(float)j * (1.0f / 32.0f));
  float ang = (float)pos[l] * freq;
  float c = cosf(ang), s = sinf(ang);
  float o = (lane < 32) ? (xn * c - p * s) : (p * s + xn * c);
  dst[((size_t)(b * 16 + h) * L + l) * 64 + lane] = f2bf(o);
}

// ---------- sum of 2 split-K partials -> out ----------
__global__ __launch_bounds__(256) void reduce2_k(const float* __restrict__ p,
                                                 float* __restrict__ out, int n) {
  int i = (blockIdx.x * 256 + threadIdx.x) * 4;
  if (i >= n) return;
  float4 a = *(const float4*)(p + i);
  float4 b = *(const float4*)(p + (size_t)n + i);
  float4 r = make_float4(a.x + b.x, a.y + b.y, a.z + b.z, a.w + b.w);
  *(float4*)(out + i) = r;
}

// ---------- V transpose: kvp v-part -> vt[b][h][dh][lk] bf16 ----------
__global__ __launch_bounds__(256) void vtrans_k(const float* __restrict__ kvp,
                                                u16* __restrict__ vt) {
  __shared__ float tile[64][65];
  int kt = blockIdx.x & 31;  // LK/64
  int bh = blockIdx.x >> 5;
  int h = bh & 15;
  int b = bh >> 4;
  int c = threadIdx.x & 63;
  int r4 = threadIdx.x >> 6;
  const float* src = kvp + ((size_t)(b * LK_ + kt * 64)) * 2048 + h * 128 + 64;
#pragma unroll
  for (int p = 0; p < 16; p++) {
    int lk = p * 4 + r4;
    tile[lk][c] = src[(size_t)lk * 2048 + c];
  }
  __syncthreads();
  u16* dst = vt + (size_t)bh * 64 * LK_ + kt * 64;
#pragma unroll
  for (int p = 0; p < 16; p++) {
    int dh = p * 4 + r4;
    dst[(size_t)dh * LK_ + c] = f2bf(tile[c][dh]);
  }
}

// ---------- flash attention (swapped QK^T); epilogue writes Y as [hi|lo] bf16 ----------
__global__ __launch_bounds__(256) void flash_k(const u16* __restrict__ qb,
                                               const u16* __restrict__ kb,
                                               const u16* __restrict__ vb,
                                               u16* __restrict__ y2) {
  __shared__ __align__(16) u16 Ks[64][72];
  __shared__ __align__(16) u16 Vs[64][72];       // Vs[dh][kv]
  __shared__ __align__(16) u16 Ps[4][16][72];    // per-wave P[q][j]
  const int tid = threadIdx.x;
  const int lane = tid & 63;
  const int wid = tid >> 6;
  const int fr = lane & 15;
  const int fq = lane >> 4;
  int qt = blockIdx.x & 15;  // LQ/64
  int bh = blockIdx.x >> 4;  // b*16+h
  const u16* qbase = qb + ((size_t)bh * LQ_ + qt * 64 + wid * 16) * 64;
  const u16* kbase = kb + (size_t)bh * LK_ * 64;
  const u16* vbase = vb + (size_t)bh * 64 * LK_;
  s16x8 qf0 = *(const s16x8*)(qbase + (size_t)fr * 64 + fq * 8);
  s16x8 qf1 = *(const s16x8*)(qbase + (size_t)fr * 64 + 32 + fq * 8);
  float mrun = -1e30f, lrun = 0.f;  // lane owns q-row fr
  f32x4 zero = {0.f, 0.f, 0.f, 0.f};
  f32x4 yacc[4];
#pragma unroll
  for (int ni = 0; ni < 4; ni++) yacc[ni] = zero;
  const int srow = tid >> 3;
  const int schunk = tid & 7;

  for (int kt = 0; kt < LK_; kt += 64) {
    __syncthreads();
#pragma unroll
    for (int ps = 0; ps < 2; ps++) {
      int row = srow + ps * 32;
      *(u16x8*)&Ks[row][schunk * 8] =
          *(const u16x8*)(kbase + (size_t)(kt + row) * 64 + schunk * 8);
      *(u16x8*)&Vs[row][schunk * 8] =
          *(const u16x8*)(vbase + (size_t)row * LK_ + kt + schunk * 8);
    }
    __syncthreads();
    f32x4 sacc[4];
#pragma unroll
    for (int ni = 0; ni < 4; ni++) sacc[ni] = zero;
#pragma unroll
    for (int ni = 0; ni < 4; ni++) {
      s16x8 kf0 = *(const s16x8*)&Ks[ni * 16 + fr][fq * 8];
      s16x8 kf1 = *(const s16x8*)&Ks[ni * 16 + fr][32 + fq * 8];
      sacc[ni] = __builtin_amdgcn_mfma_f32_16x16x32_bf16(kf0, qf0, sacc[ni], 0, 0, 0);
      sacc[ni] = __builtin_amdgcn_mfma_f32_16x16x32_bf16(kf1, qf1, sacc[ni], 0, 0, 0);
    }
    float mx = -1e30f;
#pragma unroll
    for (int ni = 0; ni < 4; ni++)
#pragma unroll
      for (int r = 0; r < 4; r++) {
        float sv = sacc[ni][r] * 0.125f;
        sacc[ni][r] = sv;
        mx = fmaxf(mx, sv);
      }
    mx = fmaxf(mx, __shfl_xor(mx, 16, 64));
    mx = fmaxf(mx, __shfl_xor(mx, 32, 64));
    float mn = fmaxf(mrun, mx);
    float alpha = __expf(mrun - mn);
    mrun = mn;
    float ts = 0.f;
#pragma unroll
    for (int ni = 0; ni < 4; ni++)
#pragma unroll
      for (int r = 0; r < 4; r++) {
        float pv = __expf(sacc[ni][r] - mn);
        sacc[ni][r] = pv;
        ts += pv;
      }
    ts += __shfl_xor(ts, 16, 64);
    ts += __shfl_xor(ts, 32, 64);
    lrun = lrun * alpha + ts;
    float va[4];
#pragma unroll
    for (int r = 0; r < 4; r++) va[r] = __shfl(alpha, fq * 4 + r, 64);
#pragma unroll
    for (int ni = 0; ni < 4; ni++)
#pragma unroll
      for (int r = 0; r < 4; r++) yacc[ni][r] *= va[r];
#pragma unroll
    for (int ni = 0; ni < 4; ni++) {
      uint2 wv;
      wv.x = (uint32_t)f2bf(sacc[ni][0]) | ((uint32_t)f2bf(sacc[ni][1]) << 16);
      wv.y = (uint32_t)f2bf(sacc[ni][2]) | ((uint32_t)f2bf(sacc[ni][3]) << 16);
      *(uint2*)&Ps[wid][fr][ni * 16 + fq * 4] = wv;
    }
#pragma unroll
    for (int s2 = 0; s2 < 2; s2++) {
      s16x8 pa = *(const s16x8*)&Ps[wid][fr][s2 * 32 + fq * 8];
#pragma unroll
      for (int ni = 0; ni < 4; ni++) {
        s16x8 vf = *(const s16x8*)&Vs[ni * 16 + fr][s2 * 32 + fq * 8];
        yacc[ni] = __builtin_amdgcn_mfma_f32_16x16x32_bf16(pa, vf, yacc[ni], 0, 0, 0);
      }
    }
  }
  int b = bh >> 4, h = bh & 15;
  float lr[4];
#pragma unroll
  for (int r = 0; r < 4; r++) lr[r] = __shfl(lrun, fq * 4 + r, 64);
  // write Y directly as [hi|lo] (ld 2048) — feeds the O-projection's 2-term GEMM
  u16* yo = y2 + ((size_t)(b * LQ_ + qt * 64 + wid * 16 + fq * 4)) * 2048 + h * 64;
#pragma unroll
  for (int ni = 0; ni < 4; ni++) {
#pragma unroll
    for (int r = 0; r < 4; r++) {
      float v = yacc[ni][r] / lr[r];
      u16 hi = f2bf(v);
      u16 lo = f2bf(v - bf2f(hi));
      yo[(size_t)r * 2048 + ni * 16 + fr] = hi;
      yo[(size_t)r * 2048 + 1024 + ni * 16 + fr] = lo;
    }
  }
}

extern "C" void kernel_launch(void* const* d_in, const int* in_sizes, int n_in,
                              void* d_out, int out_size, void* d_ws, size_t ws_size,
                              hipStream_t stream) {
  (void)in_sizes; (void)n_in; (void)out_size;
  const float* queries = (const float*)d_in[0];
  const float* kv = (const float*)d_in[1];
  const float* wq = (const float*)d_in[2];
  const float* wkv = (const float*)d_in[3];
  const float* wo = (const float*)d_in[4];
  const float* qnw = (const float*)d_in[5];
  const float* knw = (const float*)d_in[6];
  const int* pos_q = (const int*)d_in[7];
  const int* pos_k = (const int*)d_in[8];
  float* out = (float*)d_out;

  char* ws = (char*)d_ws;
  size_t off = 0;
  auto alloc = [&](size_t sz) { void* p = ws + off; off += sz; return p; };
  u16* Aq2 = (u16*)alloc((size_t)4096 * 2048 * 2);   // queries [hi|lo]
  u16* Wqh = (u16*)alloc((size_t)1024 * 1024 * 2);
  u16* Akv2 = (u16*)alloc((size_t)8192 * 2048 * 2);  // kv [hi|lo]; reused as Part (2x16.78MB)
  u16* Wkvh = (u16*)alloc((size_t)2048 * 1024 * 2);
  u16* Woh = (u16*)alloc((size_t)1024 * 1024 * 2);
  float* KVp = (float*)alloc((size_t)8192 * 2048 * 4);
  u16* Qb = (u16*)alloc((size_t)64 * 1024 * 64 * 2);
  u16* Kb = (u16*)alloc((size_t)64 * 2048 * 64 * 2);
  u16* Vt = (u16*)alloc((size_t)64 * 2048 * 64 * 2);
  u16* Y2 = (u16*)alloc((size_t)4096 * 2048 * 2);    // flash out [hi|lo]
  if (off > ws_size) return;  // insufficient workspace — bail loudly (validation fails)

  float* Part = (float*)Akv2;  // 2 x 4096 x 1024 fp32 = 33.55 MB = sizeof(Akv2)
  const size_t PSTRIDE = (size_t)4096 * 1024;

  // 1) activation splits [hi|lo]; weight casts (hi only)
  split2a_k<<<4096 * 1024 / 256, 256, 0, stream>>>(queries, Aq2, 4096 * 1024);
  castw_k<<<1024 * 1024 / 1024, 256, 0, stream>>>(wq, Wqh, 1024 * 1024);
  split2a_k<<<8192 * 1024 / 256, 256, 0, stream>>>(kv, Akv2, 8192 * 1024);
  castw_k<<<2048 * 1024 / 1024, 256, 0, stream>>>(wkv, Wkvh, 2048 * 1024);
  castw_k<<<1024 * 1024 / 1024, 256, 0, stream>>>(wo, Woh, 1024 * 1024);
  // 2) KV projection first (Akv2 dead before Part overlays it)
  gemm_bt256<<<(8192 / 256) * (2048 / 256), 512, 0, stream>>>(Akv2, Wkvh, KVp, 2048);
  // 3) Q projection, split-K=2 (512 blocks = 2/CU) -> Part
  gemm_bt<<<dim3(4096 / 128, 1024 / 128, 2), 256, 0, stream>>>(Aq2, Wqh, Part, 1024);
  // 4) RMSNorm + RoPE -> bf16 head-major (Q sums the 2 partials)
  norm_rope_k<<<4096 * 16 / 4, 256, 0, stream>>>(Part, 1024, 64, 2, PSTRIDE, qnw, pos_q, Qb, 1024);
  norm_rope_k<<<8192 * 16 / 4, 256, 0, stream>>>(KVp, 2048, 128, 1, 0, knw, pos_k, Kb, 2048);
  vtrans_k<<<64 * 32, 256, 0, stream>>>(KVp, Vt);
  // 5) flash attention -> Y2 [hi|lo] bf16
  flash_k<<<64 * 16, 256, 0, stream>>>(Qb, Kb, Vt, Y2);
  // 6) output projection: split-K=2 GEMM + reduce -> d_out
  gemm_bt<<<dim3(4096 / 128, 1024 / 128, 2), 256, 0, stream>>>(Y2, Woh, Part, 1024);
  reduce2_k<<<4096, 256, 0, stream>>>(Part, out, 4096 * 1024);
}

// Round 8
// 311.321 us; speedup vs baseline: 1.7031x; 1.0500x over previous
//
#include <hip/hip_runtime.h>
#include <stdint.h>

typedef unsigned short u16;
typedef u16 u16x8 __attribute__((ext_vector_type(8)));
typedef u16 u16x4 __attribute__((ext_vector_type(4)));
typedef short s16x8 __attribute__((ext_vector_type(8)));
typedef float f32x4 __attribute__((ext_vector_type(4)));

#define B_ 4
#define LQ_ 1024
#define LK_ 2048
#define D_ 1024
#define H_ 16
#define DH_ 64

__device__ __forceinline__ u16 f2bf(float x) {
  uint32_t u = __float_as_uint(x);
  u += 0x7FFFu + ((u >> 16) & 1u);   // round-to-nearest-even
  return (u16)(u >> 16);
}
__device__ __forceinline__ float bf2f(u16 h) {
  return __uint_as_float(((uint32_t)h) << 16);
}
__device__ __forceinline__ uint32_t cvtpk(float lo, float hi) {
  uint32_t r;
  asm("v_cvt_pk_bf16_f32 %0, %1, %2" : "=v"(r) : "v"(lo), "v"(hi));
  return r;
}

// ---------- activation split: rows x 1024 fp32 -> rows x 2048 bf16 [hi | lo] ----------
__global__ __launch_bounds__(256) void split2a_k(const float* __restrict__ src,
                                                 u16* __restrict__ dst, int n) {
  int i = blockIdx.x * 256 + threadIdx.x;
  if (i >= n) return;
  int k = i & 1023;
  int r = i >> 10;
  float x = src[i];
  u16 hi = f2bf(x);
  u16 lo = f2bf(x - bf2f(hi));
  u16* d = dst + (size_t)r * 2048;
  d[k] = hi;
  d[1024 + k] = lo;
}

// ---------- weight cast: fp32 -> bf16 (hi only), vectorized x4 ----------
__global__ __launch_bounds__(256) void castw_k(const float* __restrict__ src,
                                               u16* __restrict__ dst, int n) {
  int i = (blockIdx.x * 256 + threadIdx.x) * 4;
  if (i >= n) return;
  float4 v = *(const float4*)(src + i);
  ushort4 o;
  o.x = f2bf(v.x); o.y = f2bf(v.y); o.z = f2bf(v.z); o.w = f2bf(v.w);
  *(ushort4*)(dst + i) = o;
}

// ---------- 128x128 GEMM, split-K (Q/O): A[M,2048] ([hi|lo]) x W[N,1024]^T ----------
__global__ __launch_bounds__(256) void gemm_bt(const u16* __restrict__ A,
                                               const u16* __restrict__ Bm,
                                               float* __restrict__ C,
                                               int N) {
  __shared__ __align__(16) u16 As[128 * 32];
  __shared__ __align__(16) u16 Bs[128 * 32];
  const int tid = threadIdx.x;
  const int lane = tid & 63;
  const int wid = tid >> 6;
  const int m0 = blockIdx.x * 128;
  const int n0 = blockIdx.y * 128;
  const int slice = 2048 / gridDim.z;
  const int kStart = blockIdx.z * slice;
  const int kEnd = kStart + slice;
  C += (size_t)blockIdx.z * (size_t)gridDim.x * 128 * N;
  const int wr = (wid >> 1) * 64;
  const int wc = (wid & 1) * 64;
  const int fr = lane & 15;
  const int fq = lane >> 4;
  const int srow = lane >> 2;
  const int schunk = lane & 3;

  f32x4 zero = {0.f, 0.f, 0.f, 0.f};
  f32x4 acc[4][4];
  for (int i = 0; i < 4; i++)
    for (int j = 0; j < 4; j++) acc[i][j] = zero;

  const int r0 = wid * 32;
  const u16* gA = A + (size_t)(m0 + r0 + srow) * 2048 + schunk * 8;
  const u16* gB = Bm + (size_t)(n0 + r0 + srow) * 1024 + schunk * 8;
  u16* lA = &As[r0 * 32];
  u16* lB = &Bs[r0 * 32];

  for (int k0 = kStart; k0 < kEnd; k0 += 32) {
    int kw = k0 & 1023;
    __syncthreads();
    __builtin_amdgcn_global_load_lds(
        (const __attribute__((address_space(1))) void*)(gA + k0),
        (__attribute__((address_space(3))) void*)(lA), 16, 0, 0);
    __builtin_amdgcn_global_load_lds(
        (const __attribute__((address_space(1))) void*)(gA + k0 + (size_t)16 * 2048),
        (__attribute__((address_space(3))) void*)(lA + 16 * 32), 16, 0, 0);
    __builtin_amdgcn_global_load_lds(
        (const __attribute__((address_space(1))) void*)(gB + kw),
        (__attribute__((address_space(3))) void*)(lB), 16, 0, 0);
    __builtin_amdgcn_global_load_lds(
        (const __attribute__((address_space(1))) void*)(gB + kw + (size_t)16 * 1024),
        (__attribute__((address_space(3))) void*)(lB + 16 * 32), 16, 0, 0);
    asm volatile("s_waitcnt vmcnt(0)" ::: "memory");
    __syncthreads();

    s16x8 af[4], bf[4];
#pragma unroll
    for (int mi = 0; mi < 4; mi++)
      af[mi] = *(const s16x8*)&As[(wr + mi * 16 + fr) * 32 + fq * 8];
#pragma unroll
    for (int ni = 0; ni < 4; ni++)
      bf[ni] = *(const s16x8*)&Bs[(wc + ni * 16 + fr) * 32 + fq * 8];
#pragma unroll
    for (int mi = 0; mi < 4; mi++)
#pragma unroll
      for (int ni = 0; ni < 4; ni++)
        acc[mi][ni] = __builtin_amdgcn_mfma_f32_16x16x32_bf16(af[mi], bf[ni],
                                                              acc[mi][ni], 0, 0, 0);
  }
#pragma unroll
  for (int mi = 0; mi < 4; mi++) {
#pragma unroll
    for (int ni = 0; ni < 4; ni++) {
      int row = m0 + wr + mi * 16 + fq * 4;
      int col = n0 + wc + ni * 16 + fr;
#pragma unroll
      for (int r = 0; r < 4; r++) C[(size_t)(row + r) * N + col] = acc[mi][ni][r];
    }
  }
}

// ---------- 256x256 GEMM, 6-barrier pipeline (KV projection) ----------
#define BAR8 asm volatile("s_barrier" ::: "memory")
__global__ __launch_bounds__(512, 2) void gemm_bt256(const u16* __restrict__ A,
                                                     const u16* __restrict__ Bm,
                                                     float* __restrict__ C,
                                                     int N) {
  __shared__ __align__(16) u16 lds[65536];
  const int tid = threadIdx.x;
  const int lane = tid & 63;
  const int w = tid >> 6;
  const int wr = w >> 2;
  const int wc = w & 3;
  const int fr = lane & 15;
  const int fq = lane >> 4;
  const int nwg = gridDim.x;
  const int cpx = nwg >> 3;
  const int bid = blockIdx.x;
  const int swz = (bid & 7) * cpx + (bid >> 3);
  const int nbn = N >> 8;
  const int bm = swz / nbn, bn = swz % nbn;
  const int gm0 = bm * 256, gn0 = bn * 256;
  const int NT = 32;  // 2048 / 64

  f32x4 zero = {0.f, 0.f, 0.f, 0.f};
  f32x4 acc[8][4];
#pragma unroll
  for (int i = 0; i < 8; i++)
#pragma unroll
    for (int j = 0; j < 4; j++) acc[i][j] = zero;

  auto stage = [&](int buf, int t, int s) {
    int q = (s & 3) * 512 + tid;
    int row = q >> 3, p = q & 7;
    int l = p ^ (row & 7);
    const u16* src = (s < 4)
        ? A + (size_t)(gm0 + row) * 2048 + (t << 6) + l * 8
        : Bm + (size_t)(gn0 + row) * 1024 + ((t << 6) & 1023) + l * 8;
    u16* dst = &lds[buf * 32768 + ((s < 4) ? 0 : 16384) + ((s & 3) * 512 + w * 64) * 8];
    __builtin_amdgcn_global_load_lds(
        (const __attribute__((address_space(1))) void*)src,
        (__attribute__((address_space(3))) void*)dst, 16, 0, 0);
  };
  auto rdA = [&](int buf, int mi, int kk) -> s16x8 {
    int row = wr * 128 + mi * 16 + fr;
    int l = (kk * 4 + fq) ^ (fr & 7);
    return *(const s16x8*)&lds[buf * 32768 + row * 64 + l * 8];
  };
  auto rdB = [&](int buf, int ni, int kk) -> s16x8 {
    int row = wc * 64 + ni * 16 + fr;
    int l = (kk * 4 + fq) ^ (fr & 7);
    return *(const s16x8*)&lds[buf * 32768 + 16384 + row * 64 + l * 8];
  };

  s16x8 af[4][2], bf[4][2];

#pragma unroll
  for (int s = 0; s < 8; s++) stage(0, 0, s);
  asm volatile("s_waitcnt vmcnt(0)" ::: "memory");
  BAR8;

  for (int t = 0; t < NT; t++) {
    const int cur = t & 1;
    const bool st = (t + 1 < NT);
#pragma unroll
    for (int mi = 0; mi < 4; mi++)
#pragma unroll
      for (int kk = 0; kk < 2; kk++) af[mi][kk] = rdA(cur, mi, kk);
#pragma unroll
    for (int ni = 0; ni < 2; ni++)
#pragma unroll
      for (int kk = 0; kk < 2; kk++) bf[ni][kk] = rdB(cur, ni, kk);
    if (st) {
#pragma unroll
      for (int s = 0; s < 4; s++) stage(cur ^ 1, t + 1, s);
    }
    BAR8;
    __builtin_amdgcn_s_setprio(1);
#pragma unroll
    for (int mi = 0; mi < 4; mi++)
#pragma unroll
      for (int ni = 0; ni < 2; ni++)
#pragma unroll
        for (int kk = 0; kk < 2; kk++)
          acc[mi][ni] = __builtin_amdgcn_mfma_f32_16x16x32_bf16(af[mi][kk], bf[ni][kk],
                                                                acc[mi][ni], 0, 0, 0);
    __builtin_amdgcn_s_setprio(0);
    BAR8;
#pragma unroll
    for (int ni = 2; ni < 4; ni++)
#pragma unroll
      for (int kk = 0; kk < 2; kk++) bf[ni][kk] = rdB(cur, ni, kk);
    if (st) {
#pragma unroll
      for (int s = 4; s < 8; s++) stage(cur ^ 1, t + 1, s);
    }
    BAR8;
    __builtin_amdgcn_s_setprio(1);
#pragma unroll
    for (int mi = 0; mi < 4; mi++)
#pragma unroll
      for (int ni = 2; ni < 4; ni++)
#pragma unroll
        for (int kk = 0; kk < 2; kk++)
          acc[mi][ni] = __builtin_amdgcn_mfma_f32_16x16x32_bf16(af[mi][kk], bf[ni][kk],
                                                                acc[mi][ni], 0, 0, 0);
    __builtin_amdgcn_s_setprio(0);
    BAR8;
#pragma unroll
    for (int mi = 0; mi < 4; mi++)
#pragma unroll
      for (int kk = 0; kk < 2; kk++) af[mi][kk] = rdA(cur, mi + 4, kk);
    BAR8;
    __builtin_amdgcn_s_setprio(1);
#pragma unroll
    for (int mi = 0; mi < 4; mi++)
#pragma unroll
      for (int ni = 2; ni < 4; ni++)
#pragma unroll
        for (int kk = 0; kk < 2; kk++)
          acc[mi + 4][ni] = __builtin_amdgcn_mfma_f32_16x16x32_bf16(
              af[mi][kk], bf[ni][kk], acc[mi + 4][ni], 0, 0, 0);
    __builtin_amdgcn_s_setprio(0);
    asm volatile("s_waitcnt vmcnt(0)" ::: "memory");
    BAR8;
    __builtin_amdgcn_s_setprio(1);
#pragma unroll
    for (int mi = 0; mi < 4; mi++)
#pragma unroll
      for (int ni = 0; ni < 2; ni++)
#pragma unroll
        for (int kk = 0; kk < 2; kk++)
          acc[mi + 4][ni] = __builtin_amdgcn_mfma_f32_16x16x32_bf16(
              af[mi][kk], bf[ni][kk], acc[mi + 4][ni], 0, 0, 0);
    __builtin_amdgcn_s_setprio(0);
  }
#pragma unroll
  for (int mi = 0; mi < 8; mi++) {
#pragma unroll
    for (int ni = 0; ni < 4; ni++) {
      int row = gm0 + wr * 128 + mi * 16 + fq * 4;
      int col = gn0 + wc * 64 + ni * 16 + fr;
#pragma unroll
      for (int r = 0; r < 4; r++) C[(size_t)(row + r) * N + col] = acc[mi][ni][r];
    }
  }
}

// ---------- per-head RMSNorm + RoPE (sums nparts split-K partials), fp32 -> bf16 ----------
__global__ __launch_bounds__(256) void norm_rope_k(const float* __restrict__ src,
                                                   int srcStride, int hs,
                                                   int nparts, size_t partStride,
                                                   const float* __restrict__ w,
                                                   const int* __restrict__ pos,
                                                   u16* __restrict__ dst, int L) {
  int wid = threadIdx.x >> 6;
  int lane = threadIdx.x & 63;
  int g = blockIdx.x * 4 + wid;  // (b*L + l)*H + h
  int h = g & 15;
  int bl = g >> 4;
  int b = bl / L;
  int l = bl - b * L;
  size_t idx = (size_t)bl * srcStride + h * hs + lane;
  float x = src[idx];
  for (int pp = 1; pp < nparts; pp++) x += src[pp * partStride + idx];
  float ss = x * x;
#pragma unroll
  for (int m = 1; m < 64; m <<= 1) ss += __shfl_xor(ss, m, 64);
  float xn = x * rsqrtf(ss * (1.0f / 64.0f) + 1e-6f) * w[lane];
  float p = __shfl_xor(xn, 32, 64);
  int j = lane & 31;
  float freq = powf(10000.0f, -(float)j * (1.0f / 32.0f));
  float ang = (float)pos[l] * freq;
  float c = cosf(ang), s = sinf(ang);
  float o = (lane < 32) ? (xn * c - p * s) : (p * s + xn * c);
  dst[((size_t)(b * 16 + h) * L + l) * 64 + lane] = f2bf(o);
}

// ---------- sum of 2 split-K partials -> out ----------
__global__ __launch_bounds__(256) void reduce2_k(const float* __restrict__ p,
                                                 float* __restrict__ out, int n) {
  int i = (blockIdx.x * 256 + threadIdx.x) * 4;
  if (i >= n) return;
  float4 a = *(const float4*)(p + i);
  float4 b = *(const float4*)(p + (size_t)n + i);
  float4 r = make_float4(a.x + b.x, a.y + b.y, a.z + b.z, a.w + b.w);
  *(float4*)(out + i) = r;
}

// ---------- V transpose: kvp v-part -> vt[b][h][dh][lk] bf16 ----------
__global__ __launch_bounds__(256) void vtrans_k(const float* __restrict__ kvp,
                                                u16* __restrict__ vt) {
  __shared__ float tile[64][65];
  int kt = blockIdx.x & 31;  // LK/64
  int bh = blockIdx.x >> 5;
  int h = bh & 15;
  int b = bh >> 4;
  int c = threadIdx.x & 63;
  int r4 = threadIdx.x >> 6;
  const float* src = kvp + ((size_t)(b * LK_ + kt * 64)) * 2048 + h * 128 + 64;
#pragma unroll
  for (int p = 0; p < 16; p++) {
    int lk = p * 4 + r4;
    tile[lk][c] = src[(size_t)lk * 2048 + c];
  }
  __syncthreads();
  u16* dst = vt + (size_t)bh * 64 * LK_ + kt * 64;
#pragma unroll
  for (int p = 0; p < 16; p++) {
    int dh = p * 4 + r4;
    dst[(size_t)dh * LK_ + c] = f2bf(tile[c][dh]);
  }
}

// ---------- flash attention v2 ----------
// Swapped QK^T (lane-local softmax), P stays in registers: PV's A-frag mismatch is
// absorbed by a bijective kv-permutation sigma applied to V's LDS columns at staging
// (sigma = bit-rotate j[4:2]: (f1 f0 t) -> (t f1 f0)). K/V double-buffered, XOR-granule
// swizzled; t+1 global loads issued at tile top (T14); one barrier per tile; XCD swizzle.
__global__ __launch_bounds__(256) void flash_k(const u16* __restrict__ qb,
                                               const u16* __restrict__ kb,
                                               const u16* __restrict__ vb,
                                               u16* __restrict__ y2) {
  __shared__ __align__(16) u16 Ks[2][64][64];
  __shared__ __align__(16) u16 Vs[2][64][64];
  const int tid = threadIdx.x;
  const int lane = tid & 63;
  const int wid = tid >> 6;
  const int fr = lane & 15;
  const int fq = lane >> 4;
  // XCD swizzle: all 16 q-blocks of one head land on one XCD (K/V L2-resident)
  int bid = blockIdx.x;
  int vbid = (bid & 7) * 128 + (bid >> 3);
  int qt = vbid & 15;
  int bh = vbid >> 4;
  const u16* qbase = qb + ((size_t)bh * LQ_ + qt * 64 + wid * 16) * 64;
  const u16* kbase = kb + (size_t)bh * LK_ * 64;
  const u16* vbase = vb + (size_t)bh * 64 * LK_;
  s16x8 qf0 = *(const s16x8*)(qbase + (size_t)fr * 64 + fq * 8);
  s16x8 qf1 = *(const s16x8*)(qbase + (size_t)fr * 64 + 32 + fq * 8);
  float mrun = -1e30f, lrun = 0.f;
  f32x4 zero = {0.f, 0.f, 0.f, 0.f};
  f32x4 yacc[4];
#pragma unroll
  for (int ni = 0; ni < 4; ni++) yacc[ni] = zero;
  const int srow = tid >> 3;   // 0..31
  const int schunk = tid & 7;  // 0..7
  // V sigma-permuted write slots: schunk bits c2c1c0
  const int c2 = schunk >> 2, c1 = (schunk >> 1) & 1, c0 = schunk & 1;
  const int vg1 = 4 * c2 + 2 * c0;   // granule of e=0..3 run; +1 for e=4..7 run
  const int voff = 4 * c1;           // u16 offset within granule

  // staging helpers (registers -> LDS with swizzle)
  auto kaddr = [&](int bufi, int row) -> u16* {
    return &Ks[bufi][row][(schunk ^ (row & 7)) << 3];
  };
  auto stageV = [&](int bufi, int row, u16x8 v) {
    u16x4 lo4 = __builtin_shufflevector(v, v, 0, 1, 2, 3);
    u16x4 hi4 = __builtin_shufflevector(v, v, 4, 5, 6, 7);
    *(u16x4*)&Vs[bufi][row][((vg1 ^ (row & 7)) << 3) + voff] = lo4;
    *(u16x4*)&Vs[bufi][row][(((vg1 + 1) ^ (row & 7)) << 3) + voff] = hi4;
  };

  // prologue: stage tile 0 into buffer 0
  {
    u16x8 k0 = *(const u16x8*)(kbase + (size_t)srow * 64 + schunk * 8);
    u16x8 k1 = *(const u16x8*)(kbase + (size_t)(srow + 32) * 64 + schunk * 8);
    u16x8 v0 = *(const u16x8*)(vbase + (size_t)srow * LK_ + schunk * 8);
    u16x8 v1 = *(const u16x8*)(vbase + (size_t)(srow + 32) * LK_ + schunk * 8);
    *(u16x8*)kaddr(0, srow) = k0;
    *(u16x8*)kaddr(0, srow + 32) = k1;
    stageV(0, srow, v0);
    stageV(0, srow + 32, v1);
    __syncthreads();
  }

  const int NT = LK_ / 64;
  for (int t = 0; t < NT; t++) {
    const int cur = t & 1;
    const bool st = (t + 1 < NT);
    // T14: issue next tile's global loads now; consumed after PV
    u16x8 kr0, kr1, vr0, vr1;
    if (st) {
      int kt = (t + 1) * 64;
      kr0 = *(const u16x8*)(kbase + (size_t)(kt + srow) * 64 + schunk * 8);
      kr1 = *(const u16x8*)(kbase + (size_t)(kt + srow + 32) * 64 + schunk * 8);
      vr0 = *(const u16x8*)(vbase + (size_t)srow * LK_ + kt + schunk * 8);
      vr1 = *(const u16x8*)(vbase + (size_t)(srow + 32) * LK_ + kt + schunk * 8);
    }
    // QK^T (swapped): lane owns q-row fr, 16 j-scores
    f32x4 sacc[4];
#pragma unroll
    for (int ni = 0; ni < 4; ni++) sacc[ni] = zero;
#pragma unroll
    for (int ni = 0; ni < 4; ni++) {
      int row = ni * 16 + fr;
      s16x8 kf0 = *(const s16x8*)&Ks[cur][row][(fq ^ (fr & 7)) << 3];
      s16x8 kf1 = *(const s16x8*)&Ks[cur][row][((4 + fq) ^ (fr & 7)) << 3];
      sacc[ni] = __builtin_amdgcn_mfma_f32_16x16x32_bf16(kf0, qf0, sacc[ni], 0, 0, 0);
      sacc[ni] = __builtin_amdgcn_mfma_f32_16x16x32_bf16(kf1, qf1, sacc[ni], 0, 0, 0);
    }
    // online softmax
    float mx = -1e30f;
#pragma unroll
    for (int ni = 0; ni < 4; ni++)
#pragma unroll
      for (int r = 0; r < 4; r++) {
        float sv = sacc[ni][r] * 0.125f;
        sacc[ni][r] = sv;
        mx = fmaxf(mx, sv);
      }
    mx = fmaxf(mx, __shfl_xor(mx, 16, 64));
    mx = fmaxf(mx, __shfl_xor(mx, 32, 64));
    float mn = fmaxf(mrun, mx);
    float alpha = __expf(mrun - mn);
    mrun = mn;
    float ts = 0.f;
#pragma unroll
    for (int ni = 0; ni < 4; ni++)
#pragma unroll
      for (int r = 0; r < 4; r++) {
        float pv = __expf(sacc[ni][r] - mn);
        sacc[ni][r] = pv;
        ts += pv;
      }
    ts += __shfl_xor(ts, 16, 64);
    ts += __shfl_xor(ts, 32, 64);
    lrun = lrun * alpha + ts;
    float va[4];
#pragma unroll
    for (int r = 0; r < 4; r++) va[r] = __shfl(alpha, fq * 4 + r, 64);
#pragma unroll
    for (int ni = 0; ni < 4; ni++)
#pragma unroll
      for (int r = 0; r < 4; r++) yacc[ni][r] *= va[r];
    // P pack in-register (cvt_pk); sigma-permuted V makes this the exact A-frag
#pragma unroll
    for (int s2 = 0; s2 < 2; s2++) {
      union { uint32_t u[4]; s16x8 v8; } pu;
      pu.u[0] = cvtpk(sacc[2 * s2][0], sacc[2 * s2][1]);
      pu.u[1] = cvtpk(sacc[2 * s2][2], sacc[2 * s2][3]);
      pu.u[2] = cvtpk(sacc[2 * s2 + 1][0], sacc[2 * s2 + 1][1]);
      pu.u[3] = cvtpk(sacc[2 * s2 + 1][2], sacc[2 * s2 + 1][3]);
#pragma unroll
      for (int ni = 0; ni < 4; ni++) {
        int row = ni * 16 + fr;
        s16x8 vf = *(const s16x8*)&Vs[cur][row][(((4 * s2 + fq) ^ (fr & 7)) << 3)];
        yacc[ni] = __builtin_amdgcn_mfma_f32_16x16x32_bf16(pu.v8, vf, yacc[ni], 0, 0, 0);
      }
    }
    // write next tile to the other buffer (all waves done reading it last tile)
    if (st) {
      *(u16x8*)kaddr(cur ^ 1, srow) = kr0;
      *(u16x8*)kaddr(cur ^ 1, srow + 32) = kr1;
      stageV(cur ^ 1, srow, vr0);
      stageV(cur ^ 1, srow + 32, vr1);
    }
    __syncthreads();
  }
  int b = bh >> 4, h = bh & 15;
  float lr[4];
#pragma unroll
  for (int r = 0; r < 4; r++) lr[r] = __shfl(lrun, fq * 4 + r, 64);
  u16* yo = y2 + ((size_t)(b * LQ_ + qt * 64 + wid * 16 + fq * 4)) * 2048 + h * 64;
#pragma unroll
  for (int ni = 0; ni < 4; ni++) {
#pragma unroll
    for (int r = 0; r < 4; r++) {
      float v = yacc[ni][r] / lr[r];
      u16 hi = f2bf(v);
      u16 lo = f2bf(v - bf2f(hi));
      yo[(size_t)r * 2048 + ni * 16 + fr] = hi;
      yo[(size_t)r * 2048 + 1024 + ni * 16 + fr] = lo;
    }
  }
}

extern "C" void kernel_launch(void* const* d_in, const int* in_sizes, int n_in,
                              void* d_out, int out_size, void* d_ws, size_t ws_size,
                              hipStream_t stream) {
  (void)in_sizes; (void)n_in; (void)out_size;
  const float* queries = (const float*)d_in[0];
  const float* kv = (const float*)d_in[1];
  const float* wq = (const float*)d_in[2];
  const float* wkv = (const float*)d_in[3];
  const float* wo = (const float*)d_in[4];
  const float* qnw = (const float*)d_in[5];
  const float* knw = (const float*)d_in[6];
  const int* pos_q = (const int*)d_in[7];
  const int* pos_k = (const int*)d_in[8];
  float* out = (float*)d_out;

  char* ws = (char*)d_ws;
  size_t off = 0;
  auto alloc = [&](size_t sz) { void* p = ws + off; off += sz; return p; };
  u16* Aq2 = (u16*)alloc((size_t)4096 * 2048 * 2);
  u16* Wqh = (u16*)alloc((size_t)1024 * 1024 * 2);
  u16* Akv2 = (u16*)alloc((size_t)8192 * 2048 * 2);  // reused as Part
  u16* Wkvh = (u16*)alloc((size_t)2048 * 1024 * 2);
  u16* Woh = (u16*)alloc((size_t)1024 * 1024 * 2);
  float* KVp = (float*)alloc((size_t)8192 * 2048 * 4);
  u16* Qb = (u16*)alloc((size_t)64 * 1024 * 64 * 2);
  u16* Kb = (u16*)alloc((size_t)64 * 2048 * 64 * 2);
  u16* Vt = (u16*)alloc((size_t)64 * 2048 * 64 * 2);
  u16* Y2 = (u16*)alloc((size_t)4096 * 2048 * 2);
  if (off > ws_size) return;

  float* Part = (float*)Akv2;
  const size_t PSTRIDE = (size_t)4096 * 1024;

  split2a_k<<<4096 * 1024 / 256, 256, 0, stream>>>(queries, Aq2, 4096 * 1024);
  castw_k<<<1024 * 1024 / 1024, 256, 0, stream>>>(wq, Wqh, 1024 * 1024);
  split2a_k<<<8192 * 1024 / 256, 256, 0, stream>>>(kv, Akv2, 8192 * 1024);
  castw_k<<<2048 * 1024 / 1024, 256, 0, stream>>>(wkv, Wkvh, 2048 * 1024);
  castw_k<<<1024 * 1024 / 1024, 256, 0, stream>>>(wo, Woh, 1024 * 1024);
  gemm_bt256<<<(8192 / 256) * (2048 / 256), 512, 0, stream>>>(Akv2, Wkvh, KVp, 2048);
  gemm_bt<<<dim3(4096 / 128, 1024 / 128, 2), 256, 0, stream>>>(Aq2, Wqh, Part, 1024);
  norm_rope_k<<<4096 * 16 / 4, 256, 0, stream>>>(Part, 1024, 64, 2, PSTRIDE, qnw, pos_q, Qb, 1024);
  norm_rope_k<<<8192 * 16 / 4, 256, 0, stream>>>(KVp, 2048, 128, 1, 0, knw, pos_k, Kb, 2048);
  vtrans_k<<<64 * 32, 256, 0, stream>>>(KVp, Vt);
  flash_k<<<64 * 16, 256, 0, stream>>>(Qb, Kb, Vt, Y2);
  gemm_bt<<<dim3(4096 / 128, 1024 / 128, 2), 256, 0, stream>>>(Y2, Woh, Part, 1024);
  reduce2_k<<<4096, 256, 0, stream>>>(Part, out, 4096 * 1024);
}

// Round 9
// 304.984 us; speedup vs baseline: 1.7385x; 1.0208x over previous
//
#include <hip/hip_runtime.h>
#include <stdint.h>

typedef unsigned short u16;
typedef u16 u16x8 __attribute__((ext_vector_type(8)));
typedef u16 u16x4 __attribute__((ext_vector_type(4)));
typedef short s16x8 __attribute__((ext_vector_type(8)));
typedef float f32x4 __attribute__((ext_vector_type(4)));

#define B_ 4
#define LQ_ 1024
#define LK_ 2048
#define D_ 1024
#define H_ 16
#define DH_ 64
// Q prescale: 1/sqrt(DH) * log2(e)  -> softmax in exp2 domain
#define QSCL 0.1803368801111204f
#define L2_10000 13.287712379549449f

__device__ __forceinline__ u16 f2bf(float x) {
  uint32_t u = __float_as_uint(x);
  u += 0x7FFFu + ((u >> 16) & 1u);   // round-to-nearest-even
  return (u16)(u >> 16);
}
__device__ __forceinline__ float bf2f(u16 h) {
  return __uint_as_float(((uint32_t)h) << 16);
}
__device__ __forceinline__ uint32_t cvtpk(float lo, float hi) {
  uint32_t r;
  asm("v_cvt_pk_bf16_f32 %0, %1, %2" : "=v"(r) : "v"(lo), "v"(hi));
  return r;
}
__device__ __forceinline__ float exp2fast(float x) {
  float r;
  asm("v_exp_f32 %0, %1" : "=v"(r) : "v"(x));
  return r;
}

// ---------- activation split: rows x 1024 fp32 -> rows x 2048 bf16 [hi | lo] ----------
__global__ __launch_bounds__(256) void split2a_k(const float* __restrict__ src,
                                                 u16* __restrict__ dst, int n) {
  int i = blockIdx.x * 256 + threadIdx.x;
  if (i >= n) return;
  int k = i & 1023;
  int r = i >> 10;
  float x = src[i];
  u16 hi = f2bf(x);
  u16 lo = f2bf(x - bf2f(hi));
  u16* d = dst + (size_t)r * 2048;
  d[k] = hi;
  d[1024 + k] = lo;
}

// ---------- weight cast: fp32 -> bf16 (hi only), vectorized x4 ----------
__global__ __launch_bounds__(256) void castw_k(const float* __restrict__ src,
                                               u16* __restrict__ dst, int n) {
  int i = (blockIdx.x * 256 + threadIdx.x) * 4;
  if (i >= n) return;
  float4 v = *(const float4*)(src + i);
  ushort4 o;
  o.x = f2bf(v.x); o.y = f2bf(v.y); o.z = f2bf(v.z); o.w = f2bf(v.w);
  *(ushort4*)(dst + i) = o;
}

// ---------- 128x128 GEMM, split-K (Q/O): A[M,2048] ([hi|lo]) x W[N,1024]^T ----------
__global__ __launch_bounds__(256) void gemm_bt(const u16* __restrict__ A,
                                               const u16* __restrict__ Bm,
                                               float* __restrict__ C,
                                               int N) {
  __shared__ __align__(16) u16 As[128 * 32];
  __shared__ __align__(16) u16 Bs[128 * 32];
  const int tid = threadIdx.x;
  const int lane = tid & 63;
  const int wid = tid >> 6;
  const int m0 = blockIdx.x * 128;
  const int n0 = blockIdx.y * 128;
  const int slice = 2048 / gridDim.z;
  const int kStart = blockIdx.z * slice;
  const int kEnd = kStart + slice;
  C += (size_t)blockIdx.z * (size_t)gridDim.x * 128 * N;
  const int wr = (wid >> 1) * 64;
  const int wc = (wid & 1) * 64;
  const int fr = lane & 15;
  const int fq = lane >> 4;
  const int srow = lane >> 2;
  const int schunk = lane & 3;

  f32x4 zero = {0.f, 0.f, 0.f, 0.f};
  f32x4 acc[4][4];
  for (int i = 0; i < 4; i++)
    for (int j = 0; j < 4; j++) acc[i][j] = zero;

  const int r0 = wid * 32;
  const u16* gA = A + (size_t)(m0 + r0 + srow) * 2048 + schunk * 8;
  const u16* gB = Bm + (size_t)(n0 + r0 + srow) * 1024 + schunk * 8;
  u16* lA = &As[r0 * 32];
  u16* lB = &Bs[r0 * 32];

  for (int k0 = kStart; k0 < kEnd; k0 += 32) {
    int kw = k0 & 1023;
    __syncthreads();
    __builtin_amdgcn_global_load_lds(
        (const __attribute__((address_space(1))) void*)(gA + k0),
        (__attribute__((address_space(3))) void*)(lA), 16, 0, 0);
    __builtin_amdgcn_global_load_lds(
        (const __attribute__((address_space(1))) void*)(gA + k0 + (size_t)16 * 2048),
        (__attribute__((address_space(3))) void*)(lA + 16 * 32), 16, 0, 0);
    __builtin_amdgcn_global_load_lds(
        (const __attribute__((address_space(1))) void*)(gB + kw),
        (__attribute__((address_space(3))) void*)(lB), 16, 0, 0);
    __builtin_amdgcn_global_load_lds(
        (const __attribute__((address_space(1))) void*)(gB + kw + (size_t)16 * 1024),
        (__attribute__((address_space(3))) void*)(lB + 16 * 32), 16, 0, 0);
    asm volatile("s_waitcnt vmcnt(0)" ::: "memory");
    __syncthreads();

    s16x8 af[4], bf[4];
#pragma unroll
    for (int mi = 0; mi < 4; mi++)
      af[mi] = *(const s16x8*)&As[(wr + mi * 16 + fr) * 32 + fq * 8];
#pragma unroll
    for (int ni = 0; ni < 4; ni++)
      bf[ni] = *(const s16x8*)&Bs[(wc + ni * 16 + fr) * 32 + fq * 8];
#pragma unroll
    for (int mi = 0; mi < 4; mi++)
#pragma unroll
      for (int ni = 0; ni < 4; ni++)
        acc[mi][ni] = __builtin_amdgcn_mfma_f32_16x16x32_bf16(af[mi], bf[ni],
                                                              acc[mi][ni], 0, 0, 0);
  }
#pragma unroll
  for (int mi = 0; mi < 4; mi++) {
#pragma unroll
    for (int ni = 0; ni < 4; ni++) {
      int row = m0 + wr + mi * 16 + fq * 4;
      int col = n0 + wc + ni * 16 + fr;
#pragma unroll
      for (int r = 0; r < 4; r++) C[(size_t)(row + r) * N + col] = acc[mi][ni][r];
    }
  }
}

// ---------- 256x256 KV GEMM, 6-barrier pipeline + FUSED RMSNorm/RoPE epilogue ----------
// A = kv [hi|lo] (8192 x 2048), W = wkv bf16 (2048 x 1024). Output: per-head
// K (RMSNorm+RoPE, bf16 -> Kb[bh][l][64]) and V (bf16 -> Vb[bh][l][64]).
// Each wave's 64 output cols are exactly one head-half (k or v): RMS = sum over
// ni + shfl_xor(fr bits); RoPE pairs (j, j+32) are lane-local (ni, ni+2).
#define BAR8 asm volatile("s_barrier" ::: "memory")
__global__ __launch_bounds__(512, 2) void gemm_kv256(const u16* __restrict__ A,
                                                     const u16* __restrict__ Bm,
                                                     const float* __restrict__ knw,
                                                     const int* __restrict__ posk,
                                                     u16* __restrict__ Kb,
                                                     u16* __restrict__ Vb) {
  __shared__ __align__(16) u16 lds[65536];
  const int N = 2048;
  const int tid = threadIdx.x;
  const int lane = tid & 63;
  const int w = tid >> 6;
  const int wr = w >> 2;
  const int wc = w & 3;
  const int fr = lane & 15;
  const int fq = lane >> 4;
  const int nwg = gridDim.x;
  const int cpx = nwg >> 3;
  const int bid = blockIdx.x;
  const int swz = (bid & 7) * cpx + (bid >> 3);
  const int nbn = N >> 8;
  const int bm = swz / nbn, bn = swz % nbn;
  const int gm0 = bm * 256, gn0 = bn * 256;
  const int NT = 32;  // 2048 / 64

  f32x4 zero = {0.f, 0.f, 0.f, 0.f};
  f32x4 acc[8][4];
#pragma unroll
  for (int i = 0; i < 8; i++)
#pragma unroll
    for (int j = 0; j < 4; j++) acc[i][j] = zero;

  auto stage = [&](int buf, int t, int s) {
    int q = (s & 3) * 512 + tid;
    int row = q >> 3, p = q & 7;
    int l = p ^ (row & 7);
    const u16* src = (s < 4)
        ? A + (size_t)(gm0 + row) * 2048 + (t << 6) + l * 8
        : Bm + (size_t)(gn0 + row) * 1024 + ((t << 6) & 1023) + l * 8;
    u16* dst = &lds[buf * 32768 + ((s < 4) ? 0 : 16384) + ((s & 3) * 512 + w * 64) * 8];
    __builtin_amdgcn_global_load_lds(
        (const __attribute__((address_space(1))) void*)src,
        (__attribute__((address_space(3))) void*)dst, 16, 0, 0);
  };
  auto rdA = [&](int buf, int mi, int kk) -> s16x8 {
    int row = wr * 128 + mi * 16 + fr;
    int l = (kk * 4 + fq) ^ (fr & 7);
    return *(const s16x8*)&lds[buf * 32768 + row * 64 + l * 8];
  };
  auto rdB = [&](int buf, int ni, int kk) -> s16x8 {
    int row = wc * 64 + ni * 16 + fr;
    int l = (kk * 4 + fq) ^ (fr & 7);
    return *(const s16x8*)&lds[buf * 32768 + 16384 + row * 64 + l * 8];
  };

  s16x8 af[4][2], bf[4][2];

#pragma unroll
  for (int s = 0; s < 8; s++) stage(0, 0, s);
  asm volatile("s_waitcnt vmcnt(0)" ::: "memory");
  BAR8;

  for (int t = 0; t < NT; t++) {
    const int cur = t & 1;
    const bool st = (t + 1 < NT);
#pragma unroll
    for (int mi = 0; mi < 4; mi++)
#pragma unroll
      for (int kk = 0; kk < 2; kk++) af[mi][kk] = rdA(cur, mi, kk);
#pragma unroll
    for (int ni = 0; ni < 2; ni++)
#pragma unroll
      for (int kk = 0; kk < 2; kk++) bf[ni][kk] = rdB(cur, ni, kk);
    if (st) {
#pragma unroll
      for (int s = 0; s < 4; s++) stage(cur ^ 1, t + 1, s);
    }
    BAR8;
    __builtin_amdgcn_s_setprio(1);
#pragma unroll
    for (int mi = 0; mi < 4; mi++)
#pragma unroll
      for (int ni = 0; ni < 2; ni++)
#pragma unroll
        for (int kk = 0; kk < 2; kk++)
          acc[mi][ni] = __builtin_amdgcn_mfma_f32_16x16x32_bf16(af[mi][kk], bf[ni][kk],
                                                                acc[mi][ni], 0, 0, 0);
    __builtin_amdgcn_s_setprio(0);
    BAR8;
#pragma unroll
    for (int ni = 2; ni < 4; ni++)
#pragma unroll
      for (int kk = 0; kk < 2; kk++) bf[ni][kk] = rdB(cur, ni, kk);
    if (st) {
#pragma unroll
      for (int s = 4; s < 8; s++) stage(cur ^ 1, t + 1, s);
    }
    BAR8;
    __builtin_amdgcn_s_setprio(1);
#pragma unroll
    for (int mi = 0; mi < 4; mi++)
#pragma unroll
      for (int ni = 2; ni < 4; ni++)
#pragma unroll
        for (int kk = 0; kk < 2; kk++)
          acc[mi][ni] = __builtin_amdgcn_mfma_f32_16x16x32_bf16(af[mi][kk], bf[ni][kk],
                                                                acc[mi][ni], 0, 0, 0);
    __builtin_amdgcn_s_setprio(0);
    BAR8;
#pragma unroll
    for (int mi = 0; mi < 4; mi++)
#pragma unroll
      for (int kk = 0; kk < 2; kk++) af[mi][kk] = rdA(cur, mi + 4, kk);
    BAR8;
    __builtin_amdgcn_s_setprio(1);
#pragma unroll
    for (int mi = 0; mi < 4; mi++)
#pragma unroll
      for (int ni = 2; ni < 4; ni++)
#pragma unroll
        for (int kk = 0; kk < 2; kk++)
          acc[mi + 4][ni] = __builtin_amdgcn_mfma_f32_16x16x32_bf16(
              af[mi][kk], bf[ni][kk], acc[mi + 4][ni], 0, 0, 0);
    __builtin_amdgcn_s_setprio(0);
    asm volatile("s_waitcnt vmcnt(0)" ::: "memory");
    BAR8;
    __builtin_amdgcn_s_setprio(1);
#pragma unroll
    for (int mi = 0; mi < 4; mi++)
#pragma unroll
      for (int ni = 0; ni < 2; ni++)
#pragma unroll
        for (int kk = 0; kk < 2; kk++)
          acc[mi + 4][ni] = __builtin_amdgcn_mfma_f32_16x16x32_bf16(
              af[mi][kk], bf[ni][kk], acc[mi + 4][ni], 0, 0, 0);
    __builtin_amdgcn_s_setprio(0);
  }
  // ---- fused epilogue ----
  const int col0 = gn0 + wc * 64;      // 64-aligned -> one head-half per wave
  const int head = col0 >> 7;
  const bool isV = (col0 & 127) >= 64;
  u16* outb = (isV ? Vb : Kb) + (size_t)head * (2048 * 64);
  float wn0 = 0, wn1 = 0, wn2 = 0, wn3 = 0, f0 = 0, f1 = 0;
  if (!isV) {
    wn0 = knw[fr]; wn1 = knw[16 + fr]; wn2 = knw[32 + fr]; wn3 = knw[48 + fr];
    f0 = exp2fast(-(float)fr * (L2_10000 / 32.f));
    f1 = exp2fast(-(float)(16 + fr) * (L2_10000 / 32.f));
  }
#pragma unroll
  for (int mi = 0; mi < 8; mi++) {
#pragma unroll
    for (int r = 0; r < 4; r++) {
      int row = gm0 + wr * 128 + mi * 16 + fq * 4 + r;
      int b = row >> 11, l = row & 2047;
      u16* dst = outb + (size_t)b * (16 * 2048 * 64) + (size_t)l * 64;
      float v0 = acc[mi][0][r], v1 = acc[mi][1][r];
      float v2 = acc[mi][2][r], v3 = acc[mi][3][r];
      if (isV) {
        dst[fr] = f2bf(v0);
        dst[16 + fr] = f2bf(v1);
        dst[32 + fr] = f2bf(v2);
        dst[48 + fr] = f2bf(v3);
      } else {
        float ss = v0 * v0 + v1 * v1 + v2 * v2 + v3 * v3;
#pragma unroll
        for (int m = 1; m < 16; m <<= 1) ss += __shfl_xor(ss, m, 64);
        float rms = rsqrtf(ss * (1.0f / 64.0f) + 1e-6f);
        float x0 = v0 * rms * wn0, x1 = v1 * rms * wn1;
        float x2 = v2 * rms * wn2, x3 = v3 * rms * wn3;
        float pos = (float)posk[l];
        float a0 = pos * f0, a1 = pos * f1;
        float c0 = cosf(a0), s0 = sinf(a0);
        float c1 = cosf(a1), s1 = sinf(a1);
        dst[fr] = f2bf(x0 * c0 - x2 * s0);
        dst[16 + fr] = f2bf(x1 * c1 - x3 * s1);
        dst[32 + fr] = f2bf(x0 * s0 + x2 * c0);
        dst[48 + fr] = f2bf(x1 * s1 + x3 * c1);
      }
    }
  }
}

// ---------- per-head RMSNorm + RoPE for Q (sums 2 split-K partials), fp32 -> bf16 ----------
// outScale folds 1/sqrt(DH)*log2(e) into Q so flash softmax runs in exp2 domain.
__global__ __launch_bounds__(256) void norm_rope_q(const float* __restrict__ src,
                                                   size_t partStride,
                                                   const float* __restrict__ w,
                                                   const int* __restrict__ pos,
                                                   u16* __restrict__ dst) {
  int wid = threadIdx.x >> 6;
  int lane = threadIdx.x & 63;
  int g = blockIdx.x * 4 + wid;  // (b*L + l)*H + h
  int h = g & 15;
  int bl = g >> 4;
  int b = bl >> 10;
  int l = bl & 1023;
  size_t idx = (size_t)bl * 1024 + h * 64 + lane;
  float x = src[idx] + src[partStride + idx];
  float ss = x * x;
#pragma unroll
  for (int m = 1; m < 64; m <<= 1) ss += __shfl_xor(ss, m, 64);
  float xn = x * rsqrtf(ss * (1.0f / 64.0f) + 1e-6f) * w[lane];
  float p = __shfl_xor(xn, 32, 64);
  int j = lane & 31;
  float freq = exp2fast(-(float)j * (L2_10000 / 32.f));
  float ang = (float)pos[l] * freq;
  float c = cosf(ang), s = sinf(ang);
  float o = (lane < 32) ? (xn * c - p * s) : (p * s + xn * c);
  dst[((size_t)(b * 16 + h) * 1024 + l) * 64 + lane] = f2bf(o * QSCL);
}

// ---------- sum of 2 split-K partials -> out ----------
__global__ __launch_bounds__(256) void reduce2_k(const float* __restrict__ p,
                                                 float* __restrict__ out, int n) {
  int i = (blockIdx.x * 256 + threadIdx.x) * 4;
  if (i >= n) return;
  float4 a = *(const float4*)(p + i);
  float4 b = *(const float4*)(p + (size_t)n + i);
  float4 r = make_float4(a.x + b.x, a.y + b.y, a.z + b.z, a.w + b.w);
  *(float4*)(out + i) = r;
}

// ---------- V transpose: Vb[bh][lk][dh] bf16 -> Vt[bh][dh][lk] bf16 ----------
__global__ __launch_bounds__(256) void vtrans_k(const u16* __restrict__ vbm,
                                                u16* __restrict__ vt) {
  __shared__ u16 tile[64][72];
  int kt = blockIdx.x & 31;  // LK/64
  int bh = blockIdx.x >> 5;
  const u16* src = vbm + ((size_t)bh * LK_ + kt * 64) * 64;
  int lrow = threadIdx.x >> 3;    // 0..31
  int lch = threadIdx.x & 7;      // 0..7
#pragma unroll
  for (int p = 0; p < 2; p++) {
    int row = lrow + p * 32;
    *(u16x8*)&tile[row][lch * 8] = *(const u16x8*)(src + (size_t)row * 64 + lch * 8);
  }
  __syncthreads();
  u16* dst = vt + (size_t)bh * 64 * LK_ + kt * 64;
  int c = threadIdx.x & 63;
  int r4 = threadIdx.x >> 6;
#pragma unroll
  for (int p = 0; p < 16; p++) {
    int dh = p * 4 + r4;
    dst[(size_t)dh * LK_ + c] = tile[c][dh];
  }
}

// ---------- flash attention v3: exp2-domain softmax + defer-max ----------
__global__ __launch_bounds__(256) void flash_k(const u16* __restrict__ qb,
                                               const u16* __restrict__ kb,
                                               const u16* __restrict__ vb,
                                               u16* __restrict__ y2) {
  __shared__ __align__(16) u16 Ks[2][64][64];
  __shared__ __align__(16) u16 Vs[2][64][64];
  const int tid = threadIdx.x;
  const int lane = tid & 63;
  const int wid = tid >> 6;
  const int fr = lane & 15;
  const int fq = lane >> 4;
  int bid = blockIdx.x;
  int vbid = (bid & 7) * 128 + (bid >> 3);
  int qt = vbid & 15;
  int bh = vbid >> 4;
  const u16* qbase = qb + ((size_t)bh * LQ_ + qt * 64 + wid * 16) * 64;
  const u16* kbase = kb + (size_t)bh * LK_ * 64;
  const u16* vbase = vb + (size_t)bh * 64 * LK_;
  s16x8 qf0 = *(const s16x8*)(qbase + (size_t)fr * 64 + fq * 8);
  s16x8 qf1 = *(const s16x8*)(qbase + (size_t)fr * 64 + 32 + fq * 8);
  float mrun = -1e30f, lrun = 0.f;
  f32x4 zero = {0.f, 0.f, 0.f, 0.f};
  f32x4 yacc[4];
#pragma unroll
  for (int ni = 0; ni < 4; ni++) yacc[ni] = zero;
  const int srow = tid >> 3;
  const int schunk = tid & 7;
  const int c2 = schunk >> 2, c1 = (schunk >> 1) & 1, c0 = schunk & 1;
  const int vg1 = 4 * c2 + 2 * c0;
  const int voff = 4 * c1;

  auto kaddr = [&](int bufi, int row) -> u16* {
    return &Ks[bufi][row][(schunk ^ (row & 7)) << 3];
  };
  auto stageV = [&](int bufi, int row, u16x8 v) {
    u16x4 lo4 = __builtin_shufflevector(v, v, 0, 1, 2, 3);
    u16x4 hi4 = __builtin_shufflevector(v, v, 4, 5, 6, 7);
    *(u16x4*)&Vs[bufi][row][((vg1 ^ (row & 7)) << 3) + voff] = lo4;
    *(u16x4*)&Vs[bufi][row][(((vg1 + 1) ^ (row & 7)) << 3) + voff] = hi4;
  };

  {
    u16x8 k0 = *(const u16x8*)(kbase + (size_t)srow * 64 + schunk * 8);
    u16x8 k1 = *(const u16x8*)(kbase + (size_t)(srow + 32) * 64 + schunk * 8);
    u16x8 v0 = *(const u16x8*)(vbase + (size_t)srow * LK_ + schunk * 8);
    u16x8 v1 = *(const u16x8*)(vbase + (size_t)(srow + 32) * LK_ + schunk * 8);
    *(u16x8*)kaddr(0, srow) = k0;
    *(u16x8*)kaddr(0, srow + 32) = k1;
    stageV(0, srow, v0);
    stageV(0, srow + 32, v1);
    __syncthreads();
  }

  const int NT = LK_ / 64;
  for (int t = 0; t < NT; t++) {
    const int cur = t & 1;
    const bool st = (t + 1 < NT);
    u16x8 kr0, kr1, vr0, vr1;
    if (st) {
      int kt = (t + 1) * 64;
      kr0 = *(const u16x8*)(kbase + (size_t)(kt + srow) * 64 + schunk * 8);
      kr1 = *(const u16x8*)(kbase + (size_t)(kt + srow + 32) * 64 + schunk * 8);
      vr0 = *(const u16x8*)(vbase + (size_t)srow * LK_ + kt + schunk * 8);
      vr1 = *(const u16x8*)(vbase + (size_t)(srow + 32) * LK_ + kt + schunk * 8);
    }
    f32x4 sacc[4];
#pragma unroll
    for (int ni = 0; ni < 4; ni++) sacc[ni] = zero;
#pragma unroll
    for (int ni = 0; ni < 4; ni++) {
      int row = ni * 16 + fr;
      s16x8 kf0 = *(const s16x8*)&Ks[cur][row][(fq ^ (fr & 7)) << 3];
      s16x8 kf1 = *(const s16x8*)&Ks[cur][row][((4 + fq) ^ (fr & 7)) << 3];
      sacc[ni] = __builtin_amdgcn_mfma_f32_16x16x32_bf16(kf0, qf0, sacc[ni], 0, 0, 0);
      sacc[ni] = __builtin_amdgcn_mfma_f32_16x16x32_bf16(kf1, qf1, sacc[ni], 0, 0, 0);
    }
    // online softmax, exp2 domain, defer-max (T13)
    float mx = -1e30f;
#pragma unroll
    for (int ni = 0; ni < 4; ni++)
#pragma unroll
      for (int r = 0; r < 4; r++) mx = fmaxf(mx, sacc[ni][r]);
    mx = fmaxf(mx, __shfl_xor(mx, 16, 64));
    mx = fmaxf(mx, __shfl_xor(mx, 32, 64));
    float alpha = 1.0f;
    bool skip = __all(mx <= mrun + 10.0f);
    if (!skip) {
      float mn = fmaxf(mrun, mx);
      alpha = exp2fast(mrun - mn);
      mrun = mn;
      float va[4];
#pragma unroll
      for (int r = 0; r < 4; r++) va[r] = __shfl(alpha, fq * 4 + r, 64);
#pragma unroll
      for (int ni = 0; ni < 4; ni++)
#pragma unroll
        for (int r = 0; r < 4; r++) yacc[ni][r] *= va[r];
    }
    float ts = 0.f;
#pragma unroll
    for (int ni = 0; ni < 4; ni++)
#pragma unroll
      for (int r = 0; r < 4; r++) {
        float pv = exp2fast(sacc[ni][r] - mrun);
        sacc[ni][r] = pv;
        ts += pv;
      }
    ts += __shfl_xor(ts, 16, 64);
    ts += __shfl_xor(ts, 32, 64);
    lrun = skip ? (lrun + ts) : (lrun * alpha + ts);
#pragma unroll
    for (int s2 = 0; s2 < 2; s2++) {
      union { uint32_t u[4]; s16x8 v8; } pu;
      pu.u[0] = cvtpk(sacc[2 * s2][0], sacc[2 * s2][1]);
      pu.u[1] = cvtpk(sacc[2 * s2][2], sacc[2 * s2][3]);
      pu.u[2] = cvtpk(sacc[2 * s2 + 1][0], sacc[2 * s2 + 1][1]);
      pu.u[3] = cvtpk(sacc[2 * s2 + 1][2], sacc[2 * s2 + 1][3]);
#pragma unroll
      for (int ni = 0; ni < 4; ni++) {
        int row = ni * 16 + fr;
        s16x8 vf = *(const s16x8*)&Vs[cur][row][(((4 * s2 + fq) ^ (fr & 7)) << 3)];
        yacc[ni] = __builtin_amdgcn_mfma_f32_16x16x32_bf16(pu.v8, vf, yacc[ni], 0, 0, 0);
      }
    }
    if (st) {
      *(u16x8*)kaddr(cur ^ 1, srow) = kr0;
      *(u16x8*)kaddr(cur ^ 1, srow + 32) = kr1;
      stageV(cur ^ 1, srow, vr0);
      stageV(cur ^ 1, srow + 32, vr1);
    }
    __syncthreads();
  }
  int b = bh >> 4, h = bh & 15;
  float lr[4];
#pragma unroll
  for (int r = 0; r < 4; r++) lr[r] = __shfl(lrun, fq * 4 + r, 64);
  u16* yo = y2 + ((size_t)(b * LQ_ + qt * 64 + wid * 16 + fq * 4)) * 2048 + h * 64;
#pragma unroll
  for (int ni = 0; ni < 4; ni++) {
#pragma unroll
    for (int r = 0; r < 4; r++) {
      float v = yacc[ni][r] / lr[r];
      u16 hi = f2bf(v);
      u16 lo = f2bf(v - bf2f(hi));
      yo[(size_t)r * 2048 + ni * 16 + fr] = hi;
      yo[(size_t)r * 2048 + 1024 + ni * 16 + fr] = lo;
    }
  }
}

extern "C" void kernel_launch(void* const* d_in, const int* in_sizes, int n_in,
                              void* d_out, int out_size, void* d_ws, size_t ws_size,
                              hipStream_t stream) {
  (void)in_sizes; (void)n_in; (void)out_size;
  const float* queries = (const float*)d_in[0];
  const float* kv = (const float*)d_in[1];
  const float* wq = (const float*)d_in[2];
  const float* wkv = (const float*)d_in[3];
  const float* wo = (const float*)d_in[4];
  const float* qnw = (const float*)d_in[5];
  const float* knw = (const float*)d_in[6];
  const int* pos_q = (const int*)d_in[7];
  const int* pos_k = (const int*)d_in[8];
  float* out = (float*)d_out;

  char* ws = (char*)d_ws;
  size_t off = 0;
  auto alloc = [&](size_t sz) { void* p = ws + off; off += sz; return p; };
  u16* Aq2 = (u16*)alloc((size_t)4096 * 2048 * 2);
  u16* Wqh = (u16*)alloc((size_t)1024 * 1024 * 2);
  u16* Akv2 = (u16*)alloc((size_t)8192 * 2048 * 2);  // reused as Part after KV gemm
  u16* Wkvh = (u16*)alloc((size_t)2048 * 1024 * 2);
  u16* Woh = (u16*)alloc((size_t)1024 * 1024 * 2);
  u16* Qb = (u16*)alloc((size_t)64 * 1024 * 64 * 2);
  u16* Kb = (u16*)alloc((size_t)64 * 2048 * 64 * 2);
  u16* Vb = (u16*)alloc((size_t)64 * 2048 * 64 * 2);
  u16* Vt = (u16*)alloc((size_t)64 * 2048 * 64 * 2);
  u16* Y2 = (u16*)alloc((size_t)4096 * 2048 * 2);
  if (off > ws_size) return;

  float* Part = (float*)Akv2;
  const size_t PSTRIDE = (size_t)4096 * 1024;

  split2a_k<<<4096 * 1024 / 256, 256, 0, stream>>>(queries, Aq2, 4096 * 1024);
  castw_k<<<1024 * 1024 / 1024, 256, 0, stream>>>(wq, Wqh, 1024 * 1024);
  split2a_k<<<8192 * 1024 / 256, 256, 0, stream>>>(kv, Akv2, 8192 * 1024);
  castw_k<<<2048 * 1024 / 1024, 256, 0, stream>>>(wkv, Wkvh, 2048 * 1024);
  castw_k<<<1024 * 1024 / 1024, 256, 0, stream>>>(wo, Woh, 1024 * 1024);
  // KV projection with fused RMSNorm/RoPE epilogue -> Kb, Vb
  gemm_kv256<<<(8192 / 256) * (2048 / 256), 512, 0, stream>>>(Akv2, Wkvh, knw, pos_k, Kb, Vb);
  // Q projection split-K=2 -> Part (overlays Akv2, now dead)
  gemm_bt<<<dim3(4096 / 128, 1024 / 128, 2), 256, 0, stream>>>(Aq2, Wqh, Part, 1024);
  norm_rope_q<<<4096 * 16 / 4, 256, 0, stream>>>(Part, PSTRIDE, qnw, pos_q, Qb);
  vtrans_k<<<64 * 32, 256, 0, stream>>>(Vb, Vt);
  flash_k<<<64 * 16, 256, 0, stream>>>(Qb, Kb, Vt, Y2);
  gemm_bt<<<dim3(4096 / 128, 1024 / 128, 2), 256, 0, stream>>>(Y2, Woh, Part, 1024);
  reduce2_k<<<4096, 256, 0, stream>>>(Part, out, 4096 * 1024);
}

// Round 10
// 298.019 us; speedup vs baseline: 1.7791x; 1.0234x over previous
//
#include <hip/hip_runtime.h>
#include <stdint.h>

typedef unsigned short u16;
typedef u16 u16x8 __attribute__((ext_vector_type(8)));
typedef u16 u16x4 __attribute__((ext_vector_type(4)));
typedef short s16x8 __attribute__((ext_vector_type(8)));
typedef float f32x4 __attribute__((ext_vector_type(4)));

#define B_ 4
#define LQ_ 1024
#define LK_ 2048
#define D_ 1024
#define H_ 16
#define DH_ 64
// Q prescale: 1/sqrt(DH) * log2(e)  -> softmax in exp2 domain
#define QSCL 0.1803368801111204f
#define L2_10000 13.287712379549449f

__device__ __forceinline__ u16 f2bf(float x) {
  uint32_t u = __float_as_uint(x);
  u += 0x7FFFu + ((u >> 16) & 1u);   // round-to-nearest-even
  return (u16)(u >> 16);
}
__device__ __forceinline__ float bf2f(u16 h) {
  return __uint_as_float(((uint32_t)h) << 16);
}
__device__ __forceinline__ uint32_t cvtpk(float lo, float hi) {
  uint32_t r;
  asm("v_cvt_pk_bf16_f32 %0, %1, %2" : "=v"(r) : "v"(lo), "v"(hi));
  return r;
}
__device__ __forceinline__ float exp2fast(float x) {
  float r;
  asm("v_exp_f32 %0, %1" : "=v"(r) : "v"(x));
  return r;
}

// ---------- activation split: rows x 1024 fp32 -> rows x 2048 bf16 [hi | lo] ----------
__global__ __launch_bounds__(256) void split2a_k(const float* __restrict__ src,
                                                 u16* __restrict__ dst, int n) {
  int i = blockIdx.x * 256 + threadIdx.x;
  if (i >= n) return;
  int k = i & 1023;
  int r = i >> 10;
  float x = src[i];
  u16 hi = f2bf(x);
  u16 lo = f2bf(x - bf2f(hi));
  u16* d = dst + (size_t)r * 2048;
  d[k] = hi;
  d[1024 + k] = lo;
}

// ---------- weight cast: fp32 -> bf16 (hi only), vectorized x4 ----------
__global__ __launch_bounds__(256) void castw_k(const float* __restrict__ src,
                                               u16* __restrict__ dst, int n) {
  int i = (blockIdx.x * 256 + threadIdx.x) * 4;
  if (i >= n) return;
  float4 v = *(const float4*)(src + i);
  ushort4 o;
  o.x = f2bf(v.x); o.y = f2bf(v.y); o.z = f2bf(v.z); o.w = f2bf(v.w);
  *(ushort4*)(dst + i) = o;
}

// ---------- 128x128 GEMM, split-K (Q/O): A[M,2048] ([hi|lo]) x W[N,1024]^T ----------
__global__ __launch_bounds__(256) void gemm_bt(const u16* __restrict__ A,
                                               const u16* __restrict__ Bm,
                                               float* __restrict__ C,
                                               int N) {
  __shared__ __align__(16) u16 As[128 * 32];
  __shared__ __align__(16) u16 Bs[128 * 32];
  const int tid = threadIdx.x;
  const int lane = tid & 63;
  const int wid = tid >> 6;
  const int m0 = blockIdx.x * 128;
  const int n0 = blockIdx.y * 128;
  const int slice = 2048 / gridDim.z;
  const int kStart = blockIdx.z * slice;
  const int kEnd = kStart + slice;
  C += (size_t)blockIdx.z * (size_t)gridDim.x * 128 * N;
  const int wr = (wid >> 1) * 64;
  const int wc = (wid & 1) * 64;
  const int fr = lane & 15;
  const int fq = lane >> 4;
  const int srow = lane >> 2;
  const int schunk = lane & 3;

  f32x4 zero = {0.f, 0.f, 0.f, 0.f};
  f32x4 acc[4][4];
  for (int i = 0; i < 4; i++)
    for (int j = 0; j < 4; j++) acc[i][j] = zero;

  const int r0 = wid * 32;
  const u16* gA = A + (size_t)(m0 + r0 + srow) * 2048 + schunk * 8;
  const u16* gB = Bm + (size_t)(n0 + r0 + srow) * 1024 + schunk * 8;
  u16* lA = &As[r0 * 32];
  u16* lB = &Bs[r0 * 32];

  for (int k0 = kStart; k0 < kEnd; k0 += 32) {
    int kw = k0 & 1023;
    __syncthreads();
    __builtin_amdgcn_global_load_lds(
        (const __attribute__((address_space(1))) void*)(gA + k0),
        (__attribute__((address_space(3))) void*)(lA), 16, 0, 0);
    __builtin_amdgcn_global_load_lds(
        (const __attribute__((address_space(1))) void*)(gA + k0 + (size_t)16 * 2048),
        (__attribute__((address_space(3))) void*)(lA + 16 * 32), 16, 0, 0);
    __builtin_amdgcn_global_load_lds(
        (const __attribute__((address_space(1))) void*)(gB + kw),
        (__attribute__((address_space(3))) void*)(lB), 16, 0, 0);
    __builtin_amdgcn_global_load_lds(
        (const __attribute__((address_space(1))) void*)(gB + kw + (size_t)16 * 1024),
        (__attribute__((address_space(3))) void*)(lB + 16 * 32), 16, 0, 0);
    asm volatile("s_waitcnt vmcnt(0)" ::: "memory");
    __syncthreads();

    s16x8 af[4], bf[4];
#pragma unroll
    for (int mi = 0; mi < 4; mi++)
      af[mi] = *(const s16x8*)&As[(wr + mi * 16 + fr) * 32 + fq * 8];
#pragma unroll
    for (int ni = 0; ni < 4; ni++)
      bf[ni] = *(const s16x8*)&Bs[(wc + ni * 16 + fr) * 32 + fq * 8];
#pragma unroll
    for (int mi = 0; mi < 4; mi++)
#pragma unroll
      for (int ni = 0; ni < 4; ni++)
        acc[mi][ni] = __builtin_amdgcn_mfma_f32_16x16x32_bf16(af[mi], bf[ni],
                                                              acc[mi][ni], 0, 0, 0);
  }
#pragma unroll
  for (int mi = 0; mi < 4; mi++) {
#pragma unroll
    for (int ni = 0; ni < 4; ni++) {
      int row = m0 + wr + mi * 16 + fq * 4;
      int col = n0 + wc + ni * 16 + fr;
#pragma unroll
      for (int r = 0; r < 4; r++) C[(size_t)(row + r) * N + col] = acc[mi][ni][r];
    }
  }
}

// ---------- 256x256 KV GEMM + fused RMSNorm/RoPE epilogue (LDS-staged stores) ----------
// A = kv [hi|lo] (8192 x 2048), W = wkv bf16 (2048 x 1024).
// K-waves: RMSNorm+RoPE -> Kb[bh][l][64]. V-waves: transpose in LDS -> Vt[bh][dh][lk].
// Epilogue reuses the (dead) staging LDS per-wave; all global stores are 16B coalesced.
#define BAR8 asm volatile("s_barrier" ::: "memory")
__global__ __launch_bounds__(512, 2) void gemm_kv256(const u16* __restrict__ A,
                                                     const u16* __restrict__ Bm,
                                                     const float* __restrict__ knw,
                                                     const int* __restrict__ posk,
                                                     u16* __restrict__ Kb,
                                                     u16* __restrict__ Vt) {
  __shared__ __align__(16) u16 lds[65536];
  const int N = 2048;
  const int tid = threadIdx.x;
  const int lane = tid & 63;
  const int w = tid >> 6;
  const int wr = w >> 2;
  const int wc = w & 3;
  const int fr = lane & 15;
  const int fq = lane >> 4;
  const int nwg = gridDim.x;
  const int cpx = nwg >> 3;
  const int bid = blockIdx.x;
  const int swz = (bid & 7) * cpx + (bid >> 3);
  const int nbn = N >> 8;
  const int bm = swz / nbn, bn = swz % nbn;
  const int gm0 = bm * 256, gn0 = bn * 256;
  const int NT = 32;  // 2048 / 64

  f32x4 zero = {0.f, 0.f, 0.f, 0.f};
  f32x4 acc[8][4];
#pragma unroll
  for (int i = 0; i < 8; i++)
#pragma unroll
    for (int j = 0; j < 4; j++) acc[i][j] = zero;

  auto stage = [&](int buf, int t, int s) {
    int q = (s & 3) * 512 + tid;
    int row = q >> 3, p = q & 7;
    int l = p ^ (row & 7);
    const u16* src = (s < 4)
        ? A + (size_t)(gm0 + row) * 2048 + (t << 6) + l * 8
        : Bm + (size_t)(gn0 + row) * 1024 + ((t << 6) & 1023) + l * 8;
    u16* dst = &lds[buf * 32768 + ((s < 4) ? 0 : 16384) + ((s & 3) * 512 + w * 64) * 8];
    __builtin_amdgcn_global_load_lds(
        (const __attribute__((address_space(1))) void*)src,
        (__attribute__((address_space(3))) void*)dst, 16, 0, 0);
  };
  auto rdA = [&](int buf, int mi, int kk) -> s16x8 {
    int row = wr * 128 + mi * 16 + fr;
    int l = (kk * 4 + fq) ^ (fr & 7);
    return *(const s16x8*)&lds[buf * 32768 + row * 64 + l * 8];
  };
  auto rdB = [&](int buf, int ni, int kk) -> s16x8 {
    int row = wc * 64 + ni * 16 + fr;
    int l = (kk * 4 + fq) ^ (fr & 7);
    return *(const s16x8*)&lds[buf * 32768 + 16384 + row * 64 + l * 8];
  };

  s16x8 af[4][2], bf[4][2];

#pragma unroll
  for (int s = 0; s < 8; s++) stage(0, 0, s);
  asm volatile("s_waitcnt vmcnt(0)" ::: "memory");
  BAR8;

  for (int t = 0; t < NT; t++) {
    const int cur = t & 1;
    const bool st = (t + 1 < NT);
#pragma unroll
    for (int mi = 0; mi < 4; mi++)
#pragma unroll
      for (int kk = 0; kk < 2; kk++) af[mi][kk] = rdA(cur, mi, kk);
#pragma unroll
    for (int ni = 0; ni < 2; ni++)
#pragma unroll
      for (int kk = 0; kk < 2; kk++) bf[ni][kk] = rdB(cur, ni, kk);
    if (st) {
#pragma unroll
      for (int s = 0; s < 4; s++) stage(cur ^ 1, t + 1, s);
    }
    BAR8;
    __builtin_amdgcn_s_setprio(1);
#pragma unroll
    for (int mi = 0; mi < 4; mi++)
#pragma unroll
      for (int ni = 0; ni < 2; ni++)
#pragma unroll
        for (int kk = 0; kk < 2; kk++)
          acc[mi][ni] = __builtin_amdgcn_mfma_f32_16x16x32_bf16(af[mi][kk], bf[ni][kk],
                                                                acc[mi][ni], 0, 0, 0);
    __builtin_amdgcn_s_setprio(0);
    BAR8;
#pragma unroll
    for (int ni = 2; ni < 4; ni++)
#pragma unroll
      for (int kk = 0; kk < 2; kk++) bf[ni][kk] = rdB(cur, ni, kk);
    if (st) {
#pragma unroll
      for (int s = 4; s < 8; s++) stage(cur ^ 1, t + 1, s);
    }
    BAR8;
    __builtin_amdgcn_s_setprio(1);
#pragma unroll
    for (int mi = 0; mi < 4; mi++)
#pragma unroll
      for (int ni = 2; ni < 4; ni++)
#pragma unroll
        for (int kk = 0; kk < 2; kk++)
          acc[mi][ni] = __builtin_amdgcn_mfma_f32_16x16x32_bf16(af[mi][kk], bf[ni][kk],
                                                                acc[mi][ni], 0, 0, 0);
    __builtin_amdgcn_s_setprio(0);
    BAR8;
#pragma unroll
    for (int mi = 0; mi < 4; mi++)
#pragma unroll
      for (int kk = 0; kk < 2; kk++) af[mi][kk] = rdA(cur, mi + 4, kk);
    BAR8;
    __builtin_amdgcn_s_setprio(1);
#pragma unroll
    for (int mi = 0; mi < 4; mi++)
#pragma unroll
      for (int ni = 2; ni < 4; ni++)
#pragma unroll
        for (int kk = 0; kk < 2; kk++)
          acc[mi + 4][ni] = __builtin_amdgcn_mfma_f32_16x16x32_bf16(
              af[mi][kk], bf[ni][kk], acc[mi + 4][ni], 0, 0, 0);
    __builtin_amdgcn_s_setprio(0);
    asm volatile("s_waitcnt vmcnt(0)" ::: "memory");
    BAR8;
    __builtin_amdgcn_s_setprio(1);
#pragma unroll
    for (int mi = 0; mi < 4; mi++)
#pragma unroll
      for (int ni = 0; ni < 2; ni++)
#pragma unroll
        for (int kk = 0; kk < 2; kk++)
          acc[mi + 4][ni] = __builtin_amdgcn_mfma_f32_16x16x32_bf16(
              af[mi][kk], bf[ni][kk], acc[mi + 4][ni], 0, 0, 0);
    __builtin_amdgcn_s_setprio(0);
  }
  // ---- fused epilogue: per-wave LDS scratch (64 x 72 u16), 2 passes of 64 rows ----
  const int col0 = gn0 + wc * 64;      // 64-aligned -> one head-half per wave
  const int head = col0 >> 7;
  const bool isV = (col0 & 127) >= 64;
  u16* scratch = &lds[w * 4608];
  float wn0 = 0, wn1 = 0, wn2 = 0, wn3 = 0, f0 = 0, f1 = 0;
  if (!isV) {
    wn0 = knw[fr]; wn1 = knw[16 + fr]; wn2 = knw[32 + fr]; wn3 = knw[48 + fr];
    f0 = exp2fast(-(float)fr * (L2_10000 / 32.f));
    f1 = exp2fast(-(float)(16 + fr) * (L2_10000 / 32.f));
  }
  const int rq8 = lane >> 3, c8 = lane & 7;
  BAR8;  // all waves done reading staging LDS (final ds_reads precede P3's barrier)
#pragma unroll
  for (int pass = 0; pass < 2; pass++) {
#pragma unroll
    for (int ml = 0; ml < 4; ml++) {
      int mi = pass * 4 + ml;
#pragma unroll
      for (int r = 0; r < 4; r++) {
        int rl = ml * 16 + fq * 4 + r;
        float v0 = acc[mi][0][r], v1 = acc[mi][1][r];
        float v2 = acc[mi][2][r], v3 = acc[mi][3][r];
        if (isV) {
          // transposed deposit: scratch[dh][rl]
          scratch[fr * 72 + rl] = f2bf(v0);
          scratch[(16 + fr) * 72 + rl] = f2bf(v1);
          scratch[(32 + fr) * 72 + rl] = f2bf(v2);
          scratch[(48 + fr) * 72 + rl] = f2bf(v3);
        } else {
          int row = gm0 + wr * 128 + pass * 64 + rl;
          int l = row & 2047;
          float ss = v0 * v0 + v1 * v1 + v2 * v2 + v3 * v3;
#pragma unroll
          for (int m = 1; m < 16; m <<= 1) ss += __shfl_xor(ss, m, 64);
          float rms = rsqrtf(ss * (1.0f / 64.0f) + 1e-6f);
          float x0 = v0 * rms * wn0, x1 = v1 * rms * wn1;
          float x2 = v2 * rms * wn2, x3 = v3 * rms * wn3;
          float pos = (float)posk[l];
          float a0 = pos * f0, a1 = pos * f1;
          float c0 = cosf(a0), s0 = sinf(a0);
          float c1 = cosf(a1), s1 = sinf(a1);
          scratch[rl * 72 + fr] = f2bf(x0 * c0 - x2 * s0);
          scratch[rl * 72 + 16 + fr] = f2bf(x1 * c1 - x3 * s1);
          scratch[rl * 72 + 32 + fr] = f2bf(x0 * s0 + x2 * c0);
          scratch[rl * 72 + 48 + fr] = f2bf(x1 * s1 + x3 * c1);
        }
      }
    }
    int base = gm0 + wr * 128 + pass * 64;
    int b = base >> 11;
    int l0 = base & 2047;
    if (isV) {
      u16* vdst = Vt + (size_t)(b * 16 + head) * (64 * 2048);
#pragma unroll
      for (int it = 0; it < 8; it++) {
        int dh = it * 8 + rq8;
        *(u16x8*)(vdst + (size_t)dh * 2048 + l0 + c8 * 8) =
            *(const u16x8*)&scratch[dh * 72 + c8 * 8];
      }
    } else {
      u16* kdst = Kb + ((size_t)(b * 16 + head) * 2048 + l0) * 64;
#pragma unroll
      for (int it = 0; it < 8; it++) {
        int rl = it * 8 + rq8;
        *(u16x8*)(kdst + (size_t)rl * 64 + c8 * 8) =
            *(const u16x8*)&scratch[rl * 72 + c8 * 8];
      }
    }
  }
}

// ---------- per-head RMSNorm + RoPE for Q (sums 2 split-K partials), fp32 -> bf16 ----------
__global__ __launch_bounds__(256) void norm_rope_q(const float* __restrict__ src,
                                                   size_t partStride,
                                                   const float* __restrict__ w,
                                                   const int* __restrict__ pos,
                                                   u16* __restrict__ dst) {
  int wid = threadIdx.x >> 6;
  int lane = threadIdx.x & 63;
  int g = blockIdx.x * 4 + wid;  // (b*L + l)*H + h
  int h = g & 15;
  int bl = g >> 4;
  int b = bl >> 10;
  int l = bl & 1023;
  size_t idx = (size_t)bl * 1024 + h * 64 + lane;
  float x = src[idx] + src[partStride + idx];
  float ss = x * x;
#pragma unroll
  for (int m = 1; m < 64; m <<= 1) ss += __shfl_xor(ss, m, 64);
  float xn = x * rsqrtf(ss * (1.0f / 64.0f) + 1e-6f) * w[lane];
  float p = __shfl_xor(xn, 32, 64);
  int j = lane & 31;
  float freq = exp2fast(-(float)j * (L2_10000 / 32.f));
  float ang = (float)pos[l] * freq;
  float c = cosf(ang), s = sinf(ang);
  float o = (lane < 32) ? (xn * c - p * s) : (p * s + xn * c);
  dst[((size_t)(b * 16 + h) * 1024 + l) * 64 + lane] = f2bf(o * QSCL);
}

// ---------- sum of 2 split-K partials -> out ----------
__global__ __launch_bounds__(256) void reduce2_k(const float* __restrict__ p,
                                                 float* __restrict__ out, int n) {
  int i = (blockIdx.x * 256 + threadIdx.x) * 4;
  if (i >= n) return;
  float4 a = *(const float4*)(p + i);
  float4 b = *(const float4*)(p + (size_t)n + i);
  float4 r = make_float4(a.x + b.x, a.y + b.y, a.z + b.z, a.w + b.w);
  *(float4*)(out + i) = r;
}

// ---------- flash attention v3: exp2-domain softmax + defer-max ----------
__global__ __launch_bounds__(256) void flash_k(const u16* __restrict__ qb,
                                               const u16* __restrict__ kb,
                                               const u16* __restrict__ vb,
                                               u16* __restrict__ y2) {
  __shared__ __align__(16) u16 Ks[2][64][64];
  __shared__ __align__(16) u16 Vs[2][64][64];
  const int tid = threadIdx.x;
  const int lane = tid & 63;
  const int wid = tid >> 6;
  const int fr = lane & 15;
  const int fq = lane >> 4;
  int bid = blockIdx.x;
  int vbid = (bid & 7) * 128 + (bid >> 3);
  int qt = vbid & 15;
  int bh = vbid >> 4;
  const u16* qbase = qb + ((size_t)bh * LQ_ + qt * 64 + wid * 16) * 64;
  const u16* kbase = kb + (size_t)bh * LK_ * 64;
  const u16* vbase = vb + (size_t)bh * 64 * LK_;
  s16x8 qf0 = *(const s16x8*)(qbase + (size_t)fr * 64 + fq * 8);
  s16x8 qf1 = *(const s16x8*)(qbase + (size_t)fr * 64 + 32 + fq * 8);
  float mrun = -1e30f, lrun = 0.f;
  f32x4 zero = {0.f, 0.f, 0.f, 0.f};
  f32x4 yacc[4];
#pragma unroll
  for (int ni = 0; ni < 4; ni++) yacc[ni] = zero;
  const int srow = tid >> 3;
  const int schunk = tid & 7;
  const int c2 = schunk >> 2, c1 = (schunk >> 1) & 1, c0 = schunk & 1;
  const int vg1 = 4 * c2 + 2 * c0;
  const int voff = 4 * c1;

  auto kaddr = [&](int bufi, int row) -> u16* {
    return &Ks[bufi][row][(schunk ^ (row & 7)) << 3];
  };
  auto stageV = [&](int bufi, int row, u16x8 v) {
    u16x4 lo4 = __builtin_shufflevector(v, v, 0, 1, 2, 3);
    u16x4 hi4 = __builtin_shufflevector(v, v, 4, 5, 6, 7);
    *(u16x4*)&Vs[bufi][row][((vg1 ^ (row & 7)) << 3) + voff] = lo4;
    *(u16x4*)&Vs[bufi][row][(((vg1 + 1) ^ (row & 7)) << 3) + voff] = hi4;
  };

  {
    u16x8 k0 = *(const u16x8*)(kbase + (size_t)srow * 64 + schunk * 8);
    u16x8 k1 = *(const u16x8*)(kbase + (size_t)(srow + 32) * 64 + schunk * 8);
    u16x8 v0 = *(const u16x8*)(vbase + (size_t)srow * LK_ + schunk * 8);
    u16x8 v1 = *(const u16x8*)(vbase + (size_t)(srow + 32) * LK_ + schunk * 8);
    *(u16x8*)kaddr(0, srow) = k0;
    *(u16x8*)kaddr(0, srow + 32) = k1;
    stageV(0, srow, v0);
    stageV(0, srow + 32, v1);
    __syncthreads();
  }

  const int NT = LK_ / 64;
  for (int t = 0; t < NT; t++) {
    const int cur = t & 1;
    const bool st = (t + 1 < NT);
    u16x8 kr0, kr1, vr0, vr1;
    if (st) {
      int kt = (t + 1) * 64;
      kr0 = *(const u16x8*)(kbase + (size_t)(kt + srow) * 64 + schunk * 8);
      kr1 = *(const u16x8*)(kbase + (size_t)(kt + srow + 32) * 64 + schunk * 8);
      vr0 = *(const u16x8*)(vbase + (size_t)srow * LK_ + kt + schunk * 8);
      vr1 = *(const u16x8*)(vbase + (size_t)(srow + 32) * LK_ + kt + schunk * 8);
    }
    f32x4 sacc[4];
#pragma unroll
    for (int ni = 0; ni < 4; ni++) sacc[ni] = zero;
#pragma unroll
    for (int ni = 0; ni < 4; ni++) {
      int row = ni * 16 + fr;
      s16x8 kf0 = *(const s16x8*)&Ks[cur][row][(fq ^ (fr & 7)) << 3];
      s16x8 kf1 = *(const s16x8*)&Ks[cur][row][((4 + fq) ^ (fr & 7)) << 3];
      sacc[ni] = __builtin_amdgcn_mfma_f32_16x16x32_bf16(kf0, qf0, sacc[ni], 0, 0, 0);
      sacc[ni] = __builtin_amdgcn_mfma_f32_16x16x32_bf16(kf1, qf1, sacc[ni], 0, 0, 0);
    }
    // online softmax, exp2 domain, defer-max (T13)
    float mx = -1e30f;
#pragma unroll
    for (int ni = 0; ni < 4; ni++)
#pragma unroll
      for (int r = 0; r < 4; r++) mx = fmaxf(mx, sacc[ni][r]);
    mx = fmaxf(mx, __shfl_xor(mx, 16, 64));
    mx = fmaxf(mx, __shfl_xor(mx, 32, 64));
    float alpha = 1.0f;
    bool skip = __all(mx <= mrun + 10.0f);
    if (!skip) {
      float mn = fmaxf(mrun, mx);
      alpha = exp2fast(mrun - mn);
      mrun = mn;
      float va[4];
#pragma unroll
      for (int r = 0; r < 4; r++) va[r] = __shfl(alpha, fq * 4 + r, 64);
#pragma unroll
      for (int ni = 0; ni < 4; ni++)
#pragma unroll
        for (int r = 0; r < 4; r++) yacc[ni][r] *= va[r];
    }
    float ts = 0.f;
#pragma unroll
    for (int ni = 0; ni < 4; ni++)
#pragma unroll
      for (int r = 0; r < 4; r++) {
        float pv = exp2fast(sacc[ni][r] - mrun);
        sacc[ni][r] = pv;
        ts += pv;
      }
    ts += __shfl_xor(ts, 16, 64);
    ts += __shfl_xor(ts, 32, 64);
    lrun = skip ? (lrun + ts) : (lrun * alpha + ts);
#pragma unroll
    for (int s2 = 0; s2 < 2; s2++) {
      union { uint32_t u[4]; s16x8 v8; } pu;
      pu.u[0] = cvtpk(sacc[2 * s2][0], sacc[2 * s2][1]);
      pu.u[1] = cvtpk(sacc[2 * s2][2], sacc[2 * s2][3]);
      pu.u[2] = cvtpk(sacc[2 * s2 + 1][0], sacc[2 * s2 + 1][1]);
      pu.u[3] = cvtpk(sacc[2 * s2 + 1][2], sacc[2 * s2 + 1][3]);
#pragma unroll
      for (int ni = 0; ni < 4; ni++) {
        int row = ni * 16 + fr;
        s16x8 vf = *(const s16x8*)&Vs[cur][row][(((4 * s2 + fq) ^ (fr & 7)) << 3)];
        yacc[ni] = __builtin_amdgcn_mfma_f32_16x16x32_bf16(pu.v8, vf, yacc[ni], 0, 0, 0);
      }
    }
    if (st) {
      *(u16x8*)kaddr(cur ^ 1, srow) = kr0;
      *(u16x8*)kaddr(cur ^ 1, srow + 32) = kr1;
      stageV(cur ^ 1, srow, vr0);
      stageV(cur ^ 1, srow + 32, vr1);
    }
    __syncthreads();
  }
  int b = bh >> 4, h = bh & 15;
  float lr[4];
#pragma unroll
  for (int r = 0; r < 4; r++) lr[r] = __shfl(lrun, fq * 4 + r, 64);
  u16* yo = y2 + ((size_t)(b * LQ_ + qt * 64 + wid * 16 + fq * 4)) * 2048 + h * 64;
#pragma unroll
  for (int ni = 0; ni < 4; ni++) {
#pragma unroll
    for (int r = 0; r < 4; r++) {
      float v = yacc[ni][r] / lr[r];
      u16 hi = f2bf(v);
      u16 lo = f2bf(v - bf2f(hi));
      yo[(size_t)r * 2048 + ni * 16 + fr] = hi;
      yo[(size_t)r * 2048 + 1024 + ni * 16 + fr] = lo;
    }
  }
}

extern "C" void kernel_launch(void* const* d_in, const int* in_sizes, int n_in,
                              void* d_out, int out_size, void* d_ws, size_t ws_size,
                              hipStream_t stream) {
  (void)in_sizes; (void)n_in; (void)out_size;
  const float* queries = (const float*)d_in[0];
  const float* kv = (const float*)d_in[1];
  const float* wq = (const float*)d_in[2];
  const float* wkv = (const float*)d_in[3];
  const float* wo = (const float*)d_in[4];
  const float* qnw = (const float*)d_in[5];
  const float* knw = (const float*)d_in[6];
  const int* pos_q = (const int*)d_in[7];
  const int* pos_k = (const int*)d_in[8];
  float* out = (float*)d_out;

  char* ws = (char*)d_ws;
  size_t off = 0;
  auto alloc = [&](size_t sz) { void* p = ws + off; off += sz; return p; };
  u16* Aq2 = (u16*)alloc((size_t)4096 * 2048 * 2);
  u16* Wqh = (u16*)alloc((size_t)1024 * 1024 * 2);
  u16* Akv2 = (u16*)alloc((size_t)8192 * 2048 * 2);  // reused as Part after KV gemm
  u16* Wkvh = (u16*)alloc((size_t)2048 * 1024 * 2);
  u16* Woh = (u16*)alloc((size_t)1024 * 1024 * 2);
  u16* Qb = (u16*)alloc((size_t)64 * 1024 * 64 * 2);
  u16* Kb = (u16*)alloc((size_t)64 * 2048 * 64 * 2);
  u16* Vt = (u16*)alloc((size_t)64 * 2048 * 64 * 2);
  u16* Y2 = (u16*)alloc((size_t)4096 * 2048 * 2);
  if (off > ws_size) return;

  float* Part = (float*)Akv2;
  const size_t PSTRIDE = (size_t)4096 * 1024;

  split2a_k<<<4096 * 1024 / 256, 256, 0, stream>>>(queries, Aq2, 4096 * 1024);
  castw_k<<<1024 * 1024 / 1024, 256, 0, stream>>>(wq, Wqh, 1024 * 1024);
  split2a_k<<<8192 * 1024 / 256, 256, 0, stream>>>(kv, Akv2, 8192 * 1024);
  castw_k<<<2048 * 1024 / 1024, 256, 0, stream>>>(wkv, Wkvh, 2048 * 1024);
  castw_k<<<1024 * 1024 / 1024, 256, 0, stream>>>(wo, Woh, 1024 * 1024);
  // KV projection with fused RMSNorm/RoPE epilogue -> Kb, Vt (V written transposed)
  gemm_kv256<<<(8192 / 256) * (2048 / 256), 512, 0, stream>>>(Akv2, Wkvh, knw, pos_k, Kb, Vt);
  // Q projection split-K=2 -> Part (overlays Akv2, now dead)
  gemm_bt<<<dim3(4096 / 128, 1024 / 128, 2), 256, 0, stream>>>(Aq2, Wqh, Part, 1024);
  norm_rope_q<<<4096 * 16 / 4, 256, 0, stream>>>(Part, PSTRIDE, qnw, pos_q, Qb);
  flash_k<<<64 * 16, 256, 0, stream>>>(Qb, Kb, Vt, Y2);
  gemm_bt<<<dim3(4096 / 128, 1024 / 128, 2), 256, 0, stream>>>(Y2, Woh, Part, 1024);
  reduce2_k<<<4096, 256, 0, stream>>>(Part, out, 4096 * 1024);
}

// Round 11
// 278.463 us; speedup vs baseline: 1.9040x; 1.0702x over previous
//
#include <hip/hip_runtime.h>
#include <stdint.h>

typedef unsigned short u16;
typedef u16 u16x8 __attribute__((ext_vector_type(8)));
typedef u16 u16x4 __attribute__((ext_vector_type(4)));
typedef short s16x8 __attribute__((ext_vector_type(8)));
typedef float f32x4 __attribute__((ext_vector_type(4)));

#define B_ 4
#define LQ_ 1024
#define LK_ 2048
#define D_ 1024
#define H_ 16
#define DH_ 64
// Q prescale: 1/sqrt(DH) * log2(e)  -> softmax in exp2 domain
#define QSCL 0.1803368801111204f
#define L2_10000 13.287712379549449f

__device__ __forceinline__ u16 f2bf(float x) {
  uint32_t u = __float_as_uint(x);
  u += 0x7FFFu + ((u >> 16) & 1u);   // round-to-nearest-even
  return (u16)(u >> 16);
}
__device__ __forceinline__ float bf2f(u16 h) {
  return __uint_as_float(((uint32_t)h) << 16);
}
__device__ __forceinline__ uint32_t cvtpk(float lo, float hi) {
  uint32_t r;
  asm("v_cvt_pk_bf16_f32 %0, %1, %2" : "=v"(r) : "v"(lo), "v"(hi));
  return r;
}
__device__ __forceinline__ float exp2fast(float x) {
  float r;
  asm("v_exp_f32 %0, %1" : "=v"(r) : "v"(x));
  return r;
}

// ---------- activation split: rows x 1024 fp32 -> rows x 2048 bf16 [hi | lo] ----------
__global__ __launch_bounds__(256) void split2a_k(const float* __restrict__ src,
                                                 u16* __restrict__ dst, int n) {
  int i = blockIdx.x * 256 + threadIdx.x;
  if (i >= n) return;
  int k = i & 1023;
  int r = i >> 10;
  float x = src[i];
  u16 hi = f2bf(x);
  u16 lo = f2bf(x - bf2f(hi));
  u16* d = dst + (size_t)r * 2048;
  d[k] = hi;
  d[1024 + k] = lo;
}

// ---------- weight cast: fp32 -> bf16 (hi only), vectorized x4 ----------
__global__ __launch_bounds__(256) void castw_k(const float* __restrict__ src,
                                               u16* __restrict__ dst, int n) {
  int i = (blockIdx.x * 256 + threadIdx.x) * 4;
  if (i >= n) return;
  float4 v = *(const float4*)(src + i);
  ushort4 o;
  o.x = f2bf(v.x); o.y = f2bf(v.y); o.z = f2bf(v.z); o.w = f2bf(v.w);
  *(ushort4*)(dst + i) = o;
}

// ---------- 128x128 GEMM, split-K (Q/O): A[M,2048] ([hi|lo]) x W[N,1024]^T ----------
__global__ __launch_bounds__(256) void gemm_bt(const u16* __restrict__ A,
                                               const u16* __restrict__ Bm,
                                               float* __restrict__ C,
                                               int N) {
  __shared__ __align__(16) u16 As[128 * 32];
  __shared__ __align__(16) u16 Bs[128 * 32];
  const int tid = threadIdx.x;
  const int lane = tid & 63;
  const int wid = tid >> 6;
  const int m0 = blockIdx.x * 128;
  const int n0 = blockIdx.y * 128;
  const int slice = 2048 / gridDim.z;
  const int kStart = blockIdx.z * slice;
  const int kEnd = kStart + slice;
  C += (size_t)blockIdx.z * (size_t)gridDim.x * 128 * N;
  const int wr = (wid >> 1) * 64;
  const int wc = (wid & 1) * 64;
  const int fr = lane & 15;
  const int fq = lane >> 4;
  const int srow = lane >> 2;
  const int schunk = lane & 3;

  f32x4 zero = {0.f, 0.f, 0.f, 0.f};
  f32x4 acc[4][4];
  for (int i = 0; i < 4; i++)
    for (int j = 0; j < 4; j++) acc[i][j] = zero;

  const int r0 = wid * 32;
  const u16* gA = A + (size_t)(m0 + r0 + srow) * 2048 + schunk * 8;
  const u16* gB = Bm + (size_t)(n0 + r0 + srow) * 1024 + schunk * 8;
  u16* lA = &As[r0 * 32];
  u16* lB = &Bs[r0 * 32];

  for (int k0 = kStart; k0 < kEnd; k0 += 32) {
    int kw = k0 & 1023;
    __syncthreads();
    __builtin_amdgcn_global_load_lds(
        (const __attribute__((address_space(1))) void*)(gA + k0),
        (__attribute__((address_space(3))) void*)(lA), 16, 0, 0);
    __builtin_amdgcn_global_load_lds(
        (const __attribute__((address_space(1))) void*)(gA + k0 + (size_t)16 * 2048),
        (__attribute__((address_space(3))) void*)(lA + 16 * 32), 16, 0, 0);
    __builtin_amdgcn_global_load_lds(
        (const __attribute__((address_space(1))) void*)(gB + kw),
        (__attribute__((address_space(3))) void*)(lB), 16, 0, 0);
    __builtin_amdgcn_global_load_lds(
        (const __attribute__((address_space(1))) void*)(gB + kw + (size_t)16 * 1024),
        (__attribute__((address_space(3))) void*)(lB + 16 * 32), 16, 0, 0);
    asm volatile("s_waitcnt vmcnt(0)" ::: "memory");
    __syncthreads();

    s16x8 af[4], bf[4];
#pragma unroll
    for (int mi = 0; mi < 4; mi++)
      af[mi] = *(const s16x8*)&As[(wr + mi * 16 + fr) * 32 + fq * 8];
#pragma unroll
    for (int ni = 0; ni < 4; ni++)
      bf[ni] = *(const s16x8*)&Bs[(wc + ni * 16 + fr) * 32 + fq * 8];
#pragma unroll
    for (int mi = 0; mi < 4; mi++)
#pragma unroll
      for (int ni = 0; ni < 4; ni++)
        acc[mi][ni] = __builtin_amdgcn_mfma_f32_16x16x32_bf16(af[mi], bf[ni],
                                                              acc[mi][ni], 0, 0, 0);
  }
#pragma unroll
  for (int mi = 0; mi < 4; mi++) {
#pragma unroll
    for (int ni = 0; ni < 4; ni++) {
      int row = m0 + wr + mi * 16 + fq * 4;
      int col = n0 + wc + ni * 16 + fr;
#pragma unroll
      for (int r = 0; r < 4; r++) C[(size_t)(row + r) * N + col] = acc[mi][ni][r];
    }
  }
}

// ---------- 256x256 KV GEMM, counted-vmcnt pipeline (T4) ----------
// A[8192,2048] ([hi|lo]) x W[2048,1024]^T -> C fp32 [8192,2048].
// 2-buffer LDS; tile t+2 staged into the CURRENT buffer: B-halves at P3 (B last
// read P2), A-halves at P4 (A last read P3) -> WAR barrier-protected. P4 waits
// vmcnt(8): outstanding = (t+1)'s 8 + (t+2)'s 8 -> waits exactly tile t+1.
// Loads get ~6 phases of cover; steady state never drains (m218 T4).
#define BAR8 asm volatile("s_barrier" ::: "memory")
__global__ __launch_bounds__(512, 2) void gemm_bt256(const u16* __restrict__ A,
                                                     const u16* __restrict__ Bm,
                                                     float* __restrict__ C) {
  __shared__ __align__(16) u16 lds[65536];
  const int N = 2048;
  const int tid = threadIdx.x;
  const int lane = tid & 63;
  const int w = tid >> 6;
  const int wr = w >> 2;
  const int wc = w & 3;
  const int fr = lane & 15;
  const int fq = lane >> 4;
  const int nwg = gridDim.x;
  const int cpx = nwg >> 3;
  const int bid = blockIdx.x;
  const int swz = (bid & 7) * cpx + (bid >> 3);
  const int nbn = N >> 8;
  const int bm = swz / nbn, bn = swz % nbn;
  const int gm0 = bm * 256, gn0 = bn * 256;
  const int NT = 32;  // 2048 / 64

  f32x4 zero = {0.f, 0.f, 0.f, 0.f};
  f32x4 acc[8][4];
#pragma unroll
  for (int i = 0; i < 8; i++)
#pragma unroll
    for (int j = 0; j < 4; j++) acc[i][j] = zero;

  // s = 0..3 A half-tiles (rows 0-127, 128-255), 4..7 B half-tiles
  auto stage = [&](int buf, int t, int s) {
    int q = (s & 3) * 512 + tid;
    int row = q >> 3, p = q & 7;
    int l = p ^ (row & 7);
    const u16* src = (s < 4)
        ? A + (size_t)(gm0 + row) * 2048 + (t << 6) + l * 8
        : Bm + (size_t)(gn0 + row) * 1024 + ((t << 6) & 1023) + l * 8;
    u16* dst = &lds[buf * 32768 + ((s < 4) ? 0 : 16384) + ((s & 3) * 512 + w * 64) * 8];
    __builtin_amdgcn_global_load_lds(
        (const __attribute__((address_space(1))) void*)src,
        (__attribute__((address_space(3))) void*)dst, 16, 0, 0);
  };
  auto rdA = [&](int buf, int mi, int kk) -> s16x8 {
    int row = wr * 128 + mi * 16 + fr;
    int l = (kk * 4 + fq) ^ (fr & 7);
    return *(const s16x8*)&lds[buf * 32768 + row * 64 + l * 8];
  };
  auto rdB = [&](int buf, int ni, int kk) -> s16x8 {
    int row = wc * 64 + ni * 16 + fr;
    int l = (kk * 4 + fq) ^ (fr & 7);
    return *(const s16x8*)&lds[buf * 32768 + 16384 + row * 64 + l * 8];
  };

  s16x8 af[4][2], bf[4][2];

  // prologue: stage tiles 0 and 1 (B-halves then A-halves, matching loop order)
#pragma unroll
  for (int s = 4; s < 8; s++) stage(0, 0, s);
#pragma unroll
  for (int s = 0; s < 4; s++) stage(0, 0, s);
#pragma unroll
  for (int s = 4; s < 8; s++) stage(1, 1, s);
#pragma unroll
  for (int s = 0; s < 4; s++) stage(1, 1, s);
  asm volatile("s_waitcnt vmcnt(8)" ::: "memory");  // tile 0 landed; tile 1 in flight
  BAR8;

  for (int t = 0; t < NT; t++) {
    const int cur = t & 1;
    const bool st2 = (t + 2 < NT);
    // ---- P1: read A mi0-3 + B ni0-1; MFMA (mi0-3 x ni0-1)
#pragma unroll
    for (int mi = 0; mi < 4; mi++)
#pragma unroll
      for (int kk = 0; kk < 2; kk++) af[mi][kk] = rdA(cur, mi, kk);
#pragma unroll
    for (int ni = 0; ni < 2; ni++)
#pragma unroll
      for (int kk = 0; kk < 2; kk++) bf[ni][kk] = rdB(cur, ni, kk);
    BAR8;
    __builtin_amdgcn_s_setprio(1);
#pragma unroll
    for (int mi = 0; mi < 4; mi++)
#pragma unroll
      for (int ni = 0; ni < 2; ni++)
#pragma unroll
        for (int kk = 0; kk < 2; kk++)
          acc[mi][ni] = __builtin_amdgcn_mfma_f32_16x16x32_bf16(af[mi][kk], bf[ni][kk],
                                                                acc[mi][ni], 0, 0, 0);
    __builtin_amdgcn_s_setprio(0);
    BAR8;
    // ---- P2: read B ni2-3; MFMA (mi0-3 x ni2-3)   [last B-region ds_read]
#pragma unroll
    for (int ni = 2; ni < 4; ni++)
#pragma unroll
      for (int kk = 0; kk < 2; kk++) bf[ni][kk] = rdB(cur, ni, kk);
    BAR8;
    __builtin_amdgcn_s_setprio(1);
#pragma unroll
    for (int mi = 0; mi < 4; mi++)
#pragma unroll
      for (int ni = 2; ni < 4; ni++)
#pragma unroll
        for (int kk = 0; kk < 2; kk++)
          acc[mi][ni] = __builtin_amdgcn_mfma_f32_16x16x32_bf16(af[mi][kk], bf[ni][kk],
                                                                acc[mi][ni], 0, 0, 0);
    __builtin_amdgcn_s_setprio(0);
    BAR8;
    // ---- P3: read A mi4-7 (last A-region ds_read); stage (t+2) B into cur buf
#pragma unroll
    for (int mi = 0; mi < 4; mi++)
#pragma unroll
      for (int kk = 0; kk < 2; kk++) af[mi][kk] = rdA(cur, mi + 4, kk);
    if (st2) {
#pragma unroll
      for (int s = 4; s < 8; s++) stage(cur, t + 2, s);
    }
    BAR8;
    __builtin_amdgcn_s_setprio(1);
#pragma unroll
    for (int mi = 0; mi < 4; mi++)
#pragma unroll
      for (int ni = 2; ni < 4; ni++)
#pragma unroll
        for (int kk = 0; kk < 2; kk++)
          acc[mi + 4][ni] = __builtin_amdgcn_mfma_f32_16x16x32_bf16(
              af[mi][kk], bf[ni][kk], acc[mi + 4][ni], 0, 0, 0);
    __builtin_amdgcn_s_setprio(0);
    BAR8;
    // ---- P4: stage (t+2) A into cur buf; counted wait (tile t+1 landed); MFMA
    if (st2) {
#pragma unroll
      for (int s = 0; s < 4; s++) stage(cur, t + 2, s);
      asm volatile("s_waitcnt vmcnt(8)" ::: "memory");
    } else {
      asm volatile("s_waitcnt vmcnt(0)" ::: "memory");
    }
    BAR8;
    __builtin_amdgcn_s_setprio(1);
#pragma unroll
    for (int mi = 0; mi < 4; mi++)
#pragma unroll
      for (int ni = 0; ni < 2; ni++)
#pragma unroll
        for (int kk = 0; kk < 2; kk++)
          acc[mi + 4][ni] = __builtin_amdgcn_mfma_f32_16x16x32_bf16(
              af[mi][kk], bf[ni][kk], acc[mi + 4][ni], 0, 0, 0);
    __builtin_amdgcn_s_setprio(0);
    BAR8;
  }
  // plain fp32 epilogue (r8-verified clean write pattern)
#pragma unroll
  for (int mi = 0; mi < 8; mi++) {
#pragma unroll
    for (int ni = 0; ni < 4; ni++) {
      int row = gm0 + wr * 128 + mi * 16 + fq * 4;
      int col = gn0 + wc * 64 + ni * 16 + fr;
#pragma unroll
      for (int r = 0; r < 4; r++) C[(size_t)(row + r) * N + col] = acc[mi][ni][r];
    }
  }
}

// ---------- per-head RMSNorm + RoPE (sums nparts split-K partials), fp32 -> bf16 ----------
__global__ __launch_bounds__(256) void norm_rope_k(const float* __restrict__ src,
                                                   int srcStride, int hs,
                                                   int nparts, size_t partStride,
                                                   const float* __restrict__ w,
                                                   const int* __restrict__ pos,
                                                   u16* __restrict__ dst, int L,
                                                   float outScale) {
  int wid = threadIdx.x >> 6;
  int lane = threadIdx.x & 63;
  int g = blockIdx.x * 4 + wid;  // (b*L + l)*H + h
  int h = g & 15;
  int bl = g >> 4;
  int b = bl / L;
  int l = bl - b * L;
  size_t idx = (size_t)bl * srcStride + h * hs + lane;
  float x = src[idx];
  for (int pp = 1; pp < nparts; pp++) x += src[pp * partStride + idx];
  float ss = x * x;
#pragma unroll
  for (int m = 1; m < 64; m <<= 1) ss += __shfl_xor(ss, m, 64);
  float xn = x * rsqrtf(ss * (1.0f / 64.0f) + 1e-6f) * w[lane];
  float p = __shfl_xor(xn, 32, 64);
  int j = lane & 31;
  float freq = exp2fast(-(float)j * (L2_10000 / 32.f));
  float ang = (float)pos[l] * freq;
  float c = cosf(ang), s = sinf(ang);
  float o = (lane < 32) ? (xn * c - p * s) : (p * s + xn * c);
  dst[((size_t)(b * 16 + h) * L + l) * 64 + lane] = f2bf(o * outScale);
}

// ---------- sum of 2 split-K partials -> out ----------
__global__ __launch_bounds__(256) void reduce2_k(const float* __restrict__ p,
                                                 float* __restrict__ out, int n) {
  int i = (blockIdx.x * 256 + threadIdx.x) * 4;
  if (i >= n) return;
  float4 a = *(const float4*)(p + i);
  float4 b = *(const float4*)(p + (size_t)n + i);
  float4 r = make_float4(a.x + b.x, a.y + b.y, a.z + b.z, a.w + b.w);
  *(float4*)(out + i) = r;
}

// ---------- V transpose: KVp v-part (fp32) -> vt[b][h][dh][lk] bf16 ----------
__global__ __launch_bounds__(256) void vtrans_k(const float* __restrict__ kvp,
                                                u16* __restrict__ vt) {
  __shared__ float tile[64][65];
  int kt = blockIdx.x & 31;  // LK/64
  int bh = blockIdx.x >> 5;
  int h = bh & 15;
  int b = bh >> 4;
  int c = threadIdx.x & 63;
  int r4 = threadIdx.x >> 6;
  const float* src = kvp + ((size_t)(b * LK_ + kt * 64)) * 2048 + h * 128 + 64;
#pragma unroll
  for (int p = 0; p < 16; p++) {
    int lk = p * 4 + r4;
    tile[lk][c] = src[(size_t)lk * 2048 + c];
  }
  __syncthreads();
  u16* dst = vt + (size_t)bh * 64 * LK_ + kt * 64;
#pragma unroll
  for (int p = 0; p < 16; p++) {
    int dh = p * 4 + r4;
    dst[(size_t)dh * LK_ + c] = f2bf(tile[c][dh]);
  }
}

// ---------- flash attention v3: exp2-domain softmax + defer-max ----------
__global__ __launch_bounds__(256) void flash_k(const u16* __restrict__ qb,
                                               const u16* __restrict__ kb,
                                               const u16* __restrict__ vb,
                                               u16* __restrict__ y2) {
  __shared__ __align__(16) u16 Ks[2][64][64];
  __shared__ __align__(16) u16 Vs[2][64][64];
  const int tid = threadIdx.x;
  const int lane = tid & 63;
  const int wid = tid >> 6;
  const int fr = lane & 15;
  const int fq = lane >> 4;
  int bid = blockIdx.x;
  int vbid = (bid & 7) * 128 + (bid >> 3);
  int qt = vbid & 15;
  int bh = vbid >> 4;
  const u16* qbase = qb + ((size_t)bh * LQ_ + qt * 64 + wid * 16) * 64;
  const u16* kbase = kb + (size_t)bh * LK_ * 64;
  const u16* vbase = vb + (size_t)bh * 64 * LK_;
  s16x8 qf0 = *(const s16x8*)(qbase + (size_t)fr * 64 + fq * 8);
  s16x8 qf1 = *(const s16x8*)(qbase + (size_t)fr * 64 + 32 + fq * 8);
  float mrun = -1e30f, lrun = 0.f;
  f32x4 zero = {0.f, 0.f, 0.f, 0.f};
  f32x4 yacc[4];
#pragma unroll
  for (int ni = 0; ni < 4; ni++) yacc[ni] = zero;
  const int srow = tid >> 3;
  const int schunk = tid & 7;
  const int c2 = schunk >> 2, c1 = (schunk >> 1) & 1, c0 = schunk & 1;
  const int vg1 = 4 * c2 + 2 * c0;
  const int voff = 4 * c1;

  auto kaddr = [&](int bufi, int row) -> u16* {
    return &Ks[bufi][row][(schunk ^ (row & 7)) << 3];
  };
  auto stageV = [&](int bufi, int row, u16x8 v) {
    u16x4 lo4 = __builtin_shufflevector(v, v, 0, 1, 2, 3);
    u16x4 hi4 = __builtin_shufflevector(v, v, 4, 5, 6, 7);
    *(u16x4*)&Vs[bufi][row][((vg1 ^ (row & 7)) << 3) + voff] = lo4;
    *(u16x4*)&Vs[bufi][row][(((vg1 + 1) ^ (row & 7)) << 3) + voff] = hi4;
  };

  {
    u16x8 k0 = *(const u16x8*)(kbase + (size_t)srow * 64 + schunk * 8);
    u16x8 k1 = *(const u16x8*)(kbase + (size_t)(srow + 32) * 64 + schunk * 8);
    u16x8 v0 = *(const u16x8*)(vbase + (size_t)srow * LK_ + schunk * 8);
    u16x8 v1 = *(const u16x8*)(vbase + (size_t)(srow + 32) * LK_ + schunk * 8);
    *(u16x8*)kaddr(0, srow) = k0;
    *(u16x8*)kaddr(0, srow + 32) = k1;
    stageV(0, srow, v0);
    stageV(0, srow + 32, v1);
    __syncthreads();
  }

  const int NT = LK_ / 64;
  for (int t = 0; t < NT; t++) {
    const int cur = t & 1;
    const bool st = (t + 1 < NT);
    u16x8 kr0, kr1, vr0, vr1;
    if (st) {
      int kt = (t + 1) * 64;
      kr0 = *(const u16x8*)(kbase + (size_t)(kt + srow) * 64 + schunk * 8);
      kr1 = *(const u16x8*)(kbase + (size_t)(kt + srow + 32) * 64 + schunk * 8);
      vr0 = *(const u16x8*)(vbase + (size_t)srow * LK_ + kt + schunk * 8);
      vr1 = *(const u16x8*)(vbase + (size_t)(srow + 32) * LK_ + kt + schunk * 8);
    }
    f32x4 sacc[4];
#pragma unroll
    for (int ni = 0; ni < 4; ni++) sacc[ni] = zero;
#pragma unroll
    for (int ni = 0; ni < 4; ni++) {
      int row = ni * 16 + fr;
      s16x8 kf0 = *(const s16x8*)&Ks[cur][row][(fq ^ (fr & 7)) << 3];
      s16x8 kf1 = *(const s16x8*)&Ks[cur][row][((4 + fq) ^ (fr & 7)) << 3];
      sacc[ni] = __builtin_amdgcn_mfma_f32_16x16x32_bf16(kf0, qf0, sacc[ni], 0, 0, 0);
      sacc[ni] = __builtin_amdgcn_mfma_f32_16x16x32_bf16(kf1, qf1, sacc[ni], 0, 0, 0);
    }
    float mx = -1e30f;
#pragma unroll
    for (int ni = 0; ni < 4; ni++)
#pragma unroll
      for (int r = 0; r < 4; r++) mx = fmaxf(mx, sacc[ni][r]);
    mx = fmaxf(mx, __shfl_xor(mx, 16, 64));
    mx = fmaxf(mx, __shfl_xor(mx, 32, 64));
    float alpha = 1.0f;
    bool skip = __all(mx <= mrun + 10.0f);
    if (!skip) {
      float mn = fmaxf(mrun, mx);
      alpha = exp2fast(mrun - mn);
      mrun = mn;
      float va[4];
#pragma unroll
      for (int r = 0; r < 4; r++) va[r] = __shfl(alpha, fq * 4 + r, 64);
#pragma unroll
      for (int ni = 0; ni < 4; ni++)
#pragma unroll
        for (int r = 0; r < 4; r++) yacc[ni][r] *= va[r];
    }
    float ts = 0.f;
#pragma unroll
    for (int ni = 0; ni < 4; ni++)
#pragma unroll
      for (int r = 0; r < 4; r++) {
        float pv = exp2fast(sacc[ni][r] - mrun);
        sacc[ni][r] = pv;
        ts += pv;
      }
    ts += __shfl_xor(ts, 16, 64);
    ts += __shfl_xor(ts, 32, 64);
    lrun = skip ? (lrun + ts) : (lrun * alpha + ts);
#pragma unroll
    for (int s2 = 0; s2 < 2; s2++) {
      union { uint32_t u[4]; s16x8 v8; } pu;
      pu.u[0] = cvtpk(sacc[2 * s2][0], sacc[2 * s2][1]);
      pu.u[1] = cvtpk(sacc[2 * s2][2], sacc[2 * s2][3]);
      pu.u[2] = cvtpk(sacc[2 * s2 + 1][0], sacc[2 * s2 + 1][1]);
      pu.u[3] = cvtpk(sacc[2 * s2 + 1][2], sacc[2 * s2 + 1][3]);
#pragma unroll
      for (int ni = 0; ni < 4; ni++) {
        int row = ni * 16 + fr;
        s16x8 vf = *(const s16x8*)&Vs[cur][row][(((4 * s2 + fq) ^ (fr & 7)) << 3)];
        yacc[ni] = __builtin_amdgcn_mfma_f32_16x16x32_bf16(pu.v8, vf, yacc[ni], 0, 0, 0);
      }
    }
    if (st) {
      *(u16x8*)kaddr(cur ^ 1, srow) = kr0;
      *(u16x8*)kaddr(cur ^ 1, srow + 32) = kr1;
      stageV(cur ^ 1, srow, vr0);
      stageV(cur ^ 1, srow + 32, vr1);
    }
    __syncthreads();
  }
  int b = bh >> 4, h = bh & 15;
  float lr[4];
#pragma unroll
  for (int r = 0; r < 4; r++) lr[r] = __shfl(lrun, fq * 4 + r, 64);
  u16* yo = y2 + ((size_t)(b * LQ_ + qt * 64 + wid * 16 + fq * 4)) * 2048 + h * 64;
#pragma unroll
  for (int ni = 0; ni < 4; ni++) {
#pragma unroll
    for (int r = 0; r < 4; r++) {
      float v = yacc[ni][r] / lr[r];
      u16 hi = f2bf(v);
      u16 lo = f2bf(v - bf2f(hi));
      yo[(size_t)r * 2048 + ni * 16 + fr] = hi;
      yo[(size_t)r * 2048 + 1024 + ni * 16 + fr] = lo;
    }
  }
}

extern "C" void kernel_launch(void* const* d_in, const int* in_sizes, int n_in,
                              void* d_out, int out_size, void* d_ws, size_t ws_size,
                              hipStream_t stream) {
  (void)in_sizes; (void)n_in; (void)out_size;
  const float* queries = (const float*)d_in[0];
  const float* kv = (const float*)d_in[1];
  const float* wq = (const float*)d_in[2];
  const float* wkv = (const float*)d_in[3];
  const float* wo = (const float*)d_in[4];
  const float* qnw = (const float*)d_in[5];
  const float* knw = (const float*)d_in[6];
  const int* pos_q = (const int*)d_in[7];
  const int* pos_k = (const int*)d_in[8];
  float* out = (float*)d_out;

  char* ws = (char*)d_ws;
  size_t off = 0;
  auto alloc = [&](size_t sz) { void* p = ws + off; off += sz; return p; };
  u16* Aq2 = (u16*)alloc((size_t)4096 * 2048 * 2);
  u16* Wqh = (u16*)alloc((size_t)1024 * 1024 * 2);
  u16* Akv2 = (u16*)alloc((size_t)8192 * 2048 * 2);  // reused as Part after KV gemm
  u16* Wkvh = (u16*)alloc((size_t)2048 * 1024 * 2);
  u16* Woh = (u16*)alloc((size_t)1024 * 1024 * 2);
  float* KVp = (float*)alloc((size_t)8192 * 2048 * 4);
  u16* Qb = (u16*)alloc((size_t)64 * 1024 * 64 * 2);
  u16* Kb = (u16*)alloc((size_t)64 * 2048 * 64 * 2);
  u16* Vt = (u16*)alloc((size_t)64 * 2048 * 64 * 2);
  u16* Y2 = (u16*)alloc((size_t)4096 * 2048 * 2);
  if (off > ws_size) return;

  float* Part = (float*)Akv2;
  const size_t PSTRIDE = (size_t)4096 * 1024;

  split2a_k<<<4096 * 1024 / 256, 256, 0, stream>>>(queries, Aq2, 4096 * 1024);
  castw_k<<<1024 * 1024 / 1024, 256, 0, stream>>>(wq, Wqh, 1024 * 1024);
  split2a_k<<<8192 * 1024 / 256, 256, 0, stream>>>(kv, Akv2, 8192 * 1024);
  castw_k<<<2048 * 1024 / 1024, 256, 0, stream>>>(wkv, Wkvh, 2048 * 1024);
  castw_k<<<1024 * 1024 / 1024, 256, 0, stream>>>(wo, Woh, 1024 * 1024);
  // KV projection (counted-vmcnt pipeline) -> KVp fp32
  gemm_bt256<<<(8192 / 256) * (2048 / 256), 512, 0, stream>>>(Akv2, Wkvh, KVp);
  // Q projection split-K=2 -> Part (overlays Akv2, now dead)
  gemm_bt<<<dim3(4096 / 128, 1024 / 128, 2), 256, 0, stream>>>(Aq2, Wqh, Part, 1024);
  norm_rope_k<<<4096 * 16 / 4, 256, 0, stream>>>(Part, 1024, 64, 2, PSTRIDE, qnw,
                                                 pos_q, Qb, 1024, QSCL);
  norm_rope_k<<<8192 * 16 / 4, 256, 0, stream>>>(KVp, 2048, 128, 1, 0, knw,
                                                 pos_k, Kb, 2048, 1.0f);
  vtrans_k<<<64 * 32, 256, 0, stream>>>(KVp, Vt);
  flash_k<<<64 * 16, 256, 0, stream>>>(Qb, Kb, Vt, Y2);
  gemm_bt<<<dim3(4096 / 128, 1024 / 128, 2), 256, 0, stream>>>(Y2, Woh, Part, 1024);
  reduce2_k<<<4096, 256, 0, stream>>>(Part, out, 4096 * 1024);
}